// Round 4
// baseline (25943.112 us; speedup 1.0000x reference)
//
#include <hip/hip_runtime.h>
#include <hip/hip_bf16.h>
#include <math.h>

#define NS 2048
#define NB 512
#define DIMX 256
#define NFEAT 8

// ---------------- small prep kernels ----------------

__global__ __launch_bounds__(256) void prep_k(const float* __restrict__ Wf,
                                              const float* __restrict__ bf,
                                              const float* __restrict__ Ws,
                                              const float* __restrict__ Wt,
                                              float* __restrict__ wcomb,
                                              float* __restrict__ consts) {
    int d = threadIdx.x;
    float w0 = 0.f, w1 = 0.f, w2 = 0.f, w3 = 0.f;
#pragma unroll
    for (int k = 0; k < NFEAT; ++k) {
        float wf = Wf[k * DIMX + d];
        w0 += Ws[k] * wf;
        w1 += Ws[NFEAT + k] * wf;
        w2 += Wt[k] * wf;
        w3 += Wt[NFEAT + k] * wf;
    }
    wcomb[0 * DIMX + d] = w0;
    wcomb[1 * DIMX + d] = w1;
    wcomb[2 * DIMX + d] = w2;
    wcomb[3 * DIMX + d] = w3;
    if (d == 0) {
        float c0 = 0.f, c1 = 0.f, c2 = 0.f, c3 = 0.f;
#pragma unroll
        for (int k = 0; k < NFEAT; ++k) {
            c0 += Ws[k] * bf[k];
            c1 += Ws[NFEAT + k] * bf[k];
            c2 += Wt[k] * bf[k];
            c3 += Wt[NFEAT + k] * bf[k];
        }
        consts[0] = c0; consts[1] = c1; consts[2] = c2; consts[3] = c3;
    }
}

__global__ __launch_bounds__(256) void matvec_k(const float* __restrict__ X, int nrows,
                                                const float* __restrict__ wc,
                                                const float* __restrict__ consts, int cidx,
                                                float* __restrict__ out) {
    int wave = threadIdx.x >> 6, lane = threadIdx.x & 63;
    int row = blockIdx.x * 4 + wave;
    if (row >= nrows) return;
    const float* xr = X + (size_t)row * DIMX;
    float s = 0.f;
#pragma unroll
    for (int t = 0; t < 4; ++t) s += xr[lane + 64 * t] * wc[lane + 64 * t];
#pragma unroll
    for (int off = 32; off; off >>= 1) s += __shfl_down(s, off);
    if (lane == 0) out[row] = s + consts[cidx];
}

__global__ __launch_bounds__(256) void weights_k(const float* __restrict__ a,
                                                 const float* __restrict__ b,
                                                 const float* __restrict__ bw,
                                                 float* __restrict__ w) {
    __shared__ float red[256];
    int i = blockIdx.x, tid = threadIdx.x;
    float ai = a[i] + bw[0];
    float r1 = ai + b[tid];
    float r2 = ai + b[tid + 256];
    float e1 = r1 > 0.f ? r1 : expm1f(r1);
    float e2 = r2 > 0.f ? r2 : expm1f(r2);
    red[tid] = e1 + e2;
    __syncthreads();
    for (int s = 128; s; s >>= 1) {
        if (tid < s) red[tid] += red[tid + s];
        __syncthreads();
    }
    float scale = 512.f / red[0];
    w[(size_t)i * NB + tid] = e1 * scale;
    w[(size_t)i * NB + tid + 256] = e2 * scale;
}

// ---------------- 128-tile f32 GEMM (M,N mult of 128; K mult of 16) ----------------
// mode 0: C=acc | 1: C=kmat*acc+diag(noise) | 2: C=kmat*acc | 3: C=C-acc | 4: C=-acc
// flags bit0 = lower_only (skip tiles strictly above diagonal; relative coords)
// flags bit1 = ktrim   (K limited to rowBase+128; lower-triangular A)
// flags bit2 = kstart  (K starts at colBase;       lower-triangular B)
template <int TA, int TB>
__global__ __launch_bounds__(256) void gemm128_k(int M, int N, int K,
                                                 const float* __restrict__ A, int lda, size_t zoffA,
                                                 const float* __restrict__ B, int ldb, size_t zoffB,
                                                 float* __restrict__ C, int ldc, size_t zoffC,
                                                 const float* __restrict__ kmat, int ldk,
                                                 const float* __restrict__ noisep,
                                                 int mode, int row0, int col0, int flags) {
    __shared__ float As[16][132];
    __shared__ float Bs[16][132];
    int bz = blockIdx.z;
    A += zoffA * bz; B += zoffB * bz; C += zoffC * bz;
    int bm = blockIdx.y, bn = blockIdx.x;
    int rowBase = bm * 128, colBase = bn * 128;
    if ((flags & 1) && (rowBase + 127) < colBase) return;
    int Kend = (flags & 2) ? ((rowBase + 128 < K) ? rowBase + 128 : K) : K;
    int Kstart = (flags & 4) ? colBase : 0;
    int tid = threadIdx.x;
    int tx = tid & 15, ty = tid >> 4;
    float acc[8][8];
#pragma unroll
    for (int i = 0; i < 8; ++i)
#pragma unroll
        for (int j = 0; j < 8; ++j) acc[i][j] = 0.f;

    for (int kk = Kstart; kk < Kend; kk += 16) {
        if (TA == 0) {
            int row = tid >> 1, koff = (tid & 1) * 8;
            const float* src = A + (size_t)(rowBase + row) * lda + kk + koff;
            float4 v0 = *(const float4*)(src);
            float4 v1 = *(const float4*)(src + 4);
            As[koff + 0][row] = v0.x; As[koff + 1][row] = v0.y;
            As[koff + 2][row] = v0.z; As[koff + 3][row] = v0.w;
            As[koff + 4][row] = v1.x; As[koff + 5][row] = v1.y;
            As[koff + 6][row] = v1.z; As[koff + 7][row] = v1.w;
        } else {
            int k = tid >> 4, ib = (tid & 15) * 4;
            const float* src = A + (size_t)(kk + k) * lda + rowBase + ib;
            *(float4*)&As[k][ib] = *(const float4*)src;
            *(float4*)&As[k][ib + 64] = *(const float4*)(src + 64);
        }
        if (TB == 0) {
            int k = tid >> 4, jb = (tid & 15) * 4;
            const float* src = B + (size_t)(kk + k) * ldb + colBase + jb;
            *(float4*)&Bs[k][jb] = *(const float4*)src;
            *(float4*)&Bs[k][jb + 64] = *(const float4*)(src + 64);
        } else {
            int col = tid >> 1, koff = (tid & 1) * 8;
            const float* src = B + (size_t)(colBase + col) * ldb + kk + koff;
            float4 v0 = *(const float4*)(src);
            float4 v1 = *(const float4*)(src + 4);
            Bs[koff + 0][col] = v0.x; Bs[koff + 1][col] = v0.y;
            Bs[koff + 2][col] = v0.z; Bs[koff + 3][col] = v0.w;
            Bs[koff + 4][col] = v1.x; Bs[koff + 5][col] = v1.y;
            Bs[koff + 6][col] = v1.z; Bs[koff + 7][col] = v1.w;
        }
        __syncthreads();
#pragma unroll
        for (int k = 0; k < 16; ++k) {
            float a[8], b[8];
            float4 t0 = *(const float4*)&As[k][ty * 4];
            float4 t1 = *(const float4*)&As[k][64 + ty * 4];
            float4 u0 = *(const float4*)&Bs[k][tx * 4];
            float4 u1 = *(const float4*)&Bs[k][64 + tx * 4];
            a[0] = t0.x; a[1] = t0.y; a[2] = t0.z; a[3] = t0.w;
            a[4] = t1.x; a[5] = t1.y; a[6] = t1.z; a[7] = t1.w;
            b[0] = u0.x; b[1] = u0.y; b[2] = u0.z; b[3] = u0.w;
            b[4] = u1.x; b[5] = u1.y; b[6] = u1.z; b[7] = u1.w;
#pragma unroll
            for (int i = 0; i < 8; ++i)
#pragma unroll
                for (int j = 0; j < 8; ++j) acc[i][j] += a[i] * b[j];
        }
        __syncthreads();
    }
#pragma unroll
    for (int i = 0; i < 8; ++i) {
        int gi = rowBase + ((i >> 2) << 6) + ty * 4 + (i & 3);
#pragma unroll
        for (int j = 0; j < 8; ++j) {
            int gj = colBase + ((j >> 2) << 6) + tx * 4 + (j & 3);
            float v = acc[i][j];
            if (mode == 1 || mode == 2) {
                v *= kmat[(size_t)gi * ldk + gj];
                if (mode == 1 && (row0 + gi) == (col0 + gj)) {
                    float ns = noisep[0];
                    ns = fminf(fmaxf(ns, 1e-5f), 1.0f);
                    v += ns;
                }
            } else if (mode == 3) {
                v = C[(size_t)gi * ldc + gj] - v;
            } else if (mode == 4) {
                v = -v;
            }
            C[(size_t)gi * ldc + gj] = v;
        }
    }
}

// ------- fused 128x128 diag Cholesky + in-place triangular inverse (256 thr) -------
// Reads lower triangle of the 128x128 diag block; writes back Dinv = L^{-1}
// (full 128x128, zeros in strict upper).
__global__ __launch_bounds__(256) void chol_diag_inv128_k(float* __restrict__ A, int lda) {
    __shared__ float sp[8256];   // packed lower triangle: (r,c) -> r*(r+1)/2 + c
    __shared__ float rowbuf[128];
    int tid = threadIdx.x;

    // load lower triangle (packed)
    for (int idx = tid; idx < 8256; idx += 256) {
        int r = (int)((sqrtf(8.0f * (float)idx + 1.0f) - 1.0f) * 0.5f);
        while ((r + 1) * (r + 2) / 2 <= idx) ++r;
        while (r * (r + 1) / 2 > idx) --r;
        int c = idx - r * (r + 1) / 2;
        sp[idx] = A[(size_t)r * lda + c];
    }
    __syncthreads();

    // right-looking Cholesky on packed storage
    int a = tid & 31, b = tid >> 5;   // 32 x 8 thread layout for updates
    for (int k = 0; k < 128; ++k) {
        int krow = k * (k + 1) / 2;
        float dk = sqrtf(sp[krow + k]);
        float inv = 1.0f / dk;
        // scale column k
        {
            int i = k + 1 + tid;
            if (i < 128) sp[i * (i + 1) / 2 + k] *= inv;
            if (tid == 0) sp[krow + k] = dk;
        }
        __syncthreads();
        // trailing update: sp[i][j] -= L[i][k]*L[j][k], k<j<=i<128
        for (int i = k + 1 + b; i < 128; i += 8) {
            int ri = i * (i + 1) / 2;
            float lik = sp[ri + k];
            for (int j = k + 1 + a; j <= i; j += 32) {
                sp[ri + j] -= lik * sp[(j * (j + 1) >> 1) + k];
            }
        }
        __syncthreads();
    }

    // in-place triangular inversion, row-synchronized:
    // X[r][c] = -(1/L[r][r]) * sum_{t=c}^{r-1} L[r][t] * X[t][c];  X[r][r] = 1/L[r][r]
    for (int r = 0; r < 128; ++r) {
        int rowr = r * (r + 1) / 2;
        for (int c = tid; c <= r; c += 256) rowbuf[c] = sp[rowr + c];
        __syncthreads();
        float dinv = 1.0f / rowbuf[r];
        if (tid < r) {
            int c = tid;
            float acc = 0.f;
            for (int t = c; t < r; ++t) acc += rowbuf[t] * sp[(t * (t + 1) >> 1) + c];
            sp[rowr + c] = -acc * dinv;
        }
        if (tid == r) sp[rowr + r] = dinv;
        __syncthreads();
    }

    // write back full 128x128 (zeros in strict upper)
    for (int idx = tid; idx < 128 * 128; idx += 256) {
        int r = idx >> 7, c = idx & 127;
        A[(size_t)r * lda + c] = (c <= r) ? sp[r * (r + 1) / 2 + c] : 0.f;
    }
}

__global__ __launch_bounds__(256) void zero_upper_k(float* __restrict__ A, int n, int lda) {
    int i = blockIdx.x;
    for (int j = i + 1 + threadIdx.x; j < n; j += 256) A[(size_t)i * lda + j] = 0.f;
}

// z[row] = sum_{j<=row} L[row][j] * y[j]
__global__ __launch_bounds__(256) void gemv_lower_k(const float* __restrict__ L, int ld,
                                                    const float* __restrict__ y,
                                                    float* __restrict__ z, int n) {
    int wave = threadIdx.x >> 6, lane = threadIdx.x & 63;
    int row = blockIdx.x * 4 + wave;
    if (row >= n) return;
    const float* Lr = L + (size_t)row * ld;
    float s = 0.f;
    for (int j = lane; j <= row; j += 64) s += Lr[j] * y[j];
#pragma unroll
    for (int off = 32; off; off >>= 1) s += __shfl_down(s, off);
    if (lane == 0) z[row] = s;
}

// partials: part[by][j] = sum_{i in block-y range} Z[i][j]*zv[i]
__global__ __launch_bounds__(256) void resid_part_k(const float* __restrict__ Z,
                                                    const float* __restrict__ zv,
                                                    float* __restrict__ part) {
    int j = blockIdx.x * 256 + threadIdx.x;
    int i0 = blockIdx.y * 64;
    float acc = 0.f;
    for (int i = i0; i < i0 + 64; ++i) acc += Z[(size_t)i * NS + j] * zv[i];
    part[(size_t)blockIdx.y * NS + j] = acc;
}

__global__ __launch_bounds__(256) void resid_fin_k(const float* __restrict__ part,
                                                   const float* __restrict__ ty,
                                                   float* __restrict__ r) {
    int j = blockIdx.x * 256 + threadIdx.x;
    float acc = 0.f;
    for (int q = 0; q < 32; ++q) acc += part[(size_t)q * NS + j];
    r[j] = ty[j] - acc;
}

// loss = 0.5*sign*sum(log(diag)) + 0.5*||v||^2 + 0.5*n*log(2*pi)
__global__ __launch_bounds__(256) void loss_k(const float* __restrict__ Lc, int n, int ldl,
                                              float sign,
                                              const float* __restrict__ v,
                                              float* __restrict__ out) {
    __shared__ float red1[256];
    __shared__ float red2[256];
    int tid = threadIdx.x;
    float s1 = 0.f, s2 = 0.f;
    for (int i = tid; i < n; i += 256) {
        s1 += logf(Lc[(size_t)i * ldl + i]);
        float vi = v[i];
        s2 += vi * vi;
    }
    red1[tid] = s1;
    red2[tid] = s2;
    __syncthreads();
    for (int s = 128; s; s >>= 1) {
        if (tid < s) { red1[tid] += red1[tid + s]; red2[tid] += red2[tid + s]; }
        __syncthreads();
    }
    if (tid == 0) {
        out[0] = 0.5f * sign * red1[0] + 0.5f * red2[0] + 0.5f * (float)n * 1.8378770664093453f;
    }
}

// ---------------- host orchestration ----------------

// Blocked right-looking Cholesky, BS=128. On exit: off-diag lower blocks hold L,
// diag blocks hold Dinv (inverse of the 128x128 diagonal Cholesky factors,
// zeros in strict upper).
static void run_chol(float* A, hipStream_t stream) {
    for (int kb = 0; kb < 16; ++kb) {
        float* Ad = A + (size_t)kb * 128 * (NS + 1);
        chol_diag_inv128_k<<<1, 256, 0, stream>>>(Ad, NS);
        int rem = NS - (kb + 1) * 128;
        if (rem > 0) {
            float* P = A + (size_t)(kb + 1) * 128 * NS + kb * 128;
            // panel: P = P @ Dinv^T (in place)
            gemm128_k<0, 1><<<dim3(1, rem / 128), 256, 0, stream>>>(
                rem, 128, 128, P, NS, 0, Ad, NS, 0, P, NS, 0,
                nullptr, 0, nullptr, 0, 0, 0, 0);
            // trailing: C -= P P^T (lower tiles only)
            float* Ct = A + (size_t)(kb + 1) * 128 * (NS + 1);
            gemm128_k<0, 1><<<dim3(rem / 128, rem / 128), 256, 0, stream>>>(
                rem, rem, 128, P, NS, 0, P, NS, 0, Ct, NS, 0,
                nullptr, 0, nullptr, 3, 0, 0, 1);
        }
    }
}

// In-place recursive inversion of the lower-triangular factor in A
// (128-diag blocks already hold Dinv). T = scratch >= 1024^2 floats.
static void run_inv(float* A, float* T, hipStream_t stream) {
    zero_upper_k<<<NS, 256, 0, stream>>>(A, NS, NS);
    for (int s = 128; s <= 1024; s <<= 1) {
        int np = NS / (2 * s);
        size_t zz = (size_t)2 * s * (NS + 1);
        size_t zt = (size_t)s * s;
        dim3 g(s / 128, s / 128, np);
        // T = L21 @ X11   (X11 lower-tri -> kstart trim)
        gemm128_k<0, 0><<<g, 256, 0, stream>>>(s, s, s, A + (size_t)s * NS, NS, zz,
                                               A, NS, zz, T, s, zt,
                                               nullptr, 0, nullptr, 0, 0, 0, 4);
        // X21 = -X22 @ T  (X22 lower-tri -> ktrim)
        gemm128_k<0, 0><<<g, 256, 0, stream>>>(s, s, s, A + (size_t)s * (NS + 1), NS, zz,
                                               T, s, zt, A + (size_t)s * NS, NS, zz,
                                               nullptr, 0, nullptr, 4, 0, 0, 2);
    }
}

extern "C" void kernel_launch(void* const* d_in, const int* in_sizes, int n_in,
                              void* d_out, int out_size, void* d_ws, size_t ws_size,
                              hipStream_t stream) {
    const float* source_x = (const float*)d_in[0];
    const float* source_y = (const float*)d_in[1];
    const float* target_x = (const float*)d_in[2];
    const float* target_y = (const float*)d_in[3];
    const float* k_ss = (const float*)d_in[4];
    const float* k_tt = (const float*)d_in[5];
    const float* k_st = (const float*)d_in[6];
    const float* noise_s = (const float*)d_in[7];
    const float* noise_t = (const float*)d_in[8];
    const float* Wf = (const float*)d_in[9];
    const float* bf = (const float*)d_in[10];
    const float* Ws = (const float*)d_in[11];
    const float* bs = (const float*)d_in[12];
    const float* Wt = (const float*)d_in[13];
    const float* bt = (const float*)d_in[14];
    const float* Kb = (const float*)d_in[15];
    const float* base_s = (const float*)d_in[16];
    const float* base_t = (const float*)d_in[17];
    float* out = (float*)d_out;

    float* w = (float*)d_ws;
    const size_t M2 = (size_t)NS * NS;
    float* Ksrc = w;                 // K_src -> chol -> Linv (in place)
    float* Kcos = w + M2;
    float* Ktgt = w + 2 * M2;        // K_tgt -> cov -> Lc -> Lcinv (in place)
    float* stag = w + 3 * M2;        // wsb|wtb|wsK|wtK, later overlaid by Z
    float* wsb = stag;
    float* wtb = stag + (size_t)NS * NB;
    float* wsK = stag + 2 * (size_t)NS * NB;
    float* wtK = stag + 3 * (size_t)NS * NB;
    float* Z = stag;                 // 2048x2048, overlays staging
    float* T = w + 4 * M2;           // recursion temp / resid partials
    float* sm = T + (size_t)1024 * 1024;
    float* wcomb = sm;               // 1024
    float* consts = sm + 1024;       // 4
    float* a_s = sm + 1032;          // 2048
    float* b_s = a_s + NS;           // 512
    float* a_t = b_s + NB;           // 2048
    float* b_t = a_t + NS;           // 512
    float* rvec = b_t + NB;          // 2048
    float* vvec = rvec + NS;         // 2048
    float* z2 = vvec + NS;           // 2048

    // 1) feature maps + kernel weights
    prep_k<<<1, 256, 0, stream>>>(Wf, bf, Ws, Wt, wcomb, consts);
    matvec_k<<<NS / 4, 256, 0, stream>>>(source_x, NS, wcomb + 0 * DIMX, consts, 0, a_s);
    matvec_k<<<NB / 4, 256, 0, stream>>>(base_s, NB, wcomb + 1 * DIMX, consts, 1, b_s);
    matvec_k<<<NS / 4, 256, 0, stream>>>(target_x, NS, wcomb + 2 * DIMX, consts, 2, a_t);
    matvec_k<<<NB / 4, 256, 0, stream>>>(base_t, NB, wcomb + 3 * DIMX, consts, 3, b_t);
    weights_k<<<NS, 256, 0, stream>>>(a_s, b_s, bs, wsb);
    weights_k<<<NS, 256, 0, stream>>>(a_t, b_t, bt, wtb);

    // 2) wsK = ws@Kb, wtK = wt@Kb
    {
        dim3 g(NB / 128, NS / 128);
        gemm128_k<0, 0><<<g, 256, 0, stream>>>(NS, NB, NB, wsb, NB, 0, Kb, NB, 0, wsK, NB, 0,
                                               nullptr, 0, nullptr, 0, 0, 0, 0);
        gemm128_k<0, 0><<<g, 256, 0, stream>>>(NS, NB, NB, wtb, NB, 0, Kb, NB, 0, wtK, NB, 0,
                                               nullptr, 0, nullptr, 0, 0, 0, 0);
    }
    // 3) K_src, K_tgt, K_cos (Hadamard epilogues)
    {
        dim3 g(NS / 128, NS / 128);
        gemm128_k<0, 1><<<g, 256, 0, stream>>>(NS, NS, NB, wsK, NB, 0, wsb, NB, 0, Ksrc, NS, 0,
                                               k_ss, NS, noise_s, 1, 0, 0, 0);
        gemm128_k<0, 1><<<g, 256, 0, stream>>>(NS, NS, NB, wtK, NB, 0, wtb, NB, 0, Ktgt, NS, 0,
                                               k_tt, NS, noise_t, 1, 0, 0, 0);
        gemm128_k<0, 1><<<g, 256, 0, stream>>>(NS, NS, NB, wsK, NB, 0, wtb, NB, 0, Kcos, NS, 0,
                                               k_st, NS, nullptr, 2, 0, 0, 0);
    }

    // 4) Cholesky of K_src + full triangular inversion -> Linv in Ksrc
    run_chol(Ksrc, stream);
    run_inv(Ksrc, T, stream);

    // 5) Z = Linv @ Kcos (K trimmed to the lower band)
    {
        dim3 g(NS / 128, NS / 128);
        gemm128_k<0, 0><<<g, 256, 0, stream>>>(NS, NS, NS, Ksrc, NS, 0, Kcos, NS, 0, Z, NS, 0,
                                               nullptr, 0, nullptr, 0, 0, 0, 2);
    }

    // 6) z2 = Linv @ source_y ; r = target_y - Z^T z2
    gemv_lower_k<<<NS / 4, 256, 0, stream>>>(Ksrc, NS, source_y, z2, NS);
    resid_part_k<<<dim3(NS / 256, 32), 256, 0, stream>>>(Z, z2, T);
    resid_fin_k<<<NS / 256, 256, 0, stream>>>(T, target_y, rvec);

    // 7) cov = K_tgt - Z^T Z (lower tiles only)
    {
        dim3 g(NS / 128, NS / 128);
        gemm128_k<1, 0><<<g, 256, 0, stream>>>(NS, NS, NS, Z, NS, 0, Z, NS, 0, Ktgt, NS, 0,
                                               nullptr, 0, nullptr, 3, 0, 0, 1);
    }

    // 8) Cholesky of cov + full triangular inversion -> Lcinv in Ktgt
    run_chol(Ktgt, stream);
    run_inv(Ktgt, T, stream);

    // 9) v = Lcinv @ r ; loss (log diag(Lc) = -log diag(Lcinv))
    gemv_lower_k<<<NS / 4, 256, 0, stream>>>(Ktgt, NS, rvec, vvec, NS);
    loss_k<<<1, 256, 0, stream>>>(Ktgt, NS, NS, -1.0f, vvec, out);
}

// Round 5
// 14485.649 us; speedup vs baseline: 1.7910x; 1.7910x over previous
//
#include <hip/hip_runtime.h>
#include <hip/hip_bf16.h>
#include <math.h>

#define NS 2048
#define NB 512
#define DIMX 256
#define NFEAT 8
#define DPAD 129

// ---------------- small prep kernels ----------------

__global__ __launch_bounds__(256) void prep_k(const float* __restrict__ Wf,
                                              const float* __restrict__ bf,
                                              const float* __restrict__ Ws,
                                              const float* __restrict__ Wt,
                                              float* __restrict__ wcomb,
                                              float* __restrict__ consts) {
    int d = threadIdx.x;
    float w0 = 0.f, w1 = 0.f, w2 = 0.f, w3 = 0.f;
#pragma unroll
    for (int k = 0; k < NFEAT; ++k) {
        float wf = Wf[k * DIMX + d];
        w0 += Ws[k] * wf;
        w1 += Ws[NFEAT + k] * wf;
        w2 += Wt[k] * wf;
        w3 += Wt[NFEAT + k] * wf;
    }
    wcomb[0 * DIMX + d] = w0;
    wcomb[1 * DIMX + d] = w1;
    wcomb[2 * DIMX + d] = w2;
    wcomb[3 * DIMX + d] = w3;
    if (d == 0) {
        float c0 = 0.f, c1 = 0.f, c2 = 0.f, c3 = 0.f;
#pragma unroll
        for (int k = 0; k < NFEAT; ++k) {
            c0 += Ws[k] * bf[k];
            c1 += Ws[NFEAT + k] * bf[k];
            c2 += Wt[k] * bf[k];
            c3 += Wt[NFEAT + k] * bf[k];
        }
        consts[0] = c0; consts[1] = c1; consts[2] = c2; consts[3] = c3;
    }
}

__global__ __launch_bounds__(256) void matvec_k(const float* __restrict__ X, int nrows,
                                                const float* __restrict__ wc,
                                                const float* __restrict__ consts, int cidx,
                                                float* __restrict__ out) {
    int wave = threadIdx.x >> 6, lane = threadIdx.x & 63;
    int row = blockIdx.x * 4 + wave;
    if (row >= nrows) return;
    const float* xr = X + (size_t)row * DIMX;
    float s = 0.f;
#pragma unroll
    for (int t = 0; t < 4; ++t) s += xr[lane + 64 * t] * wc[lane + 64 * t];
#pragma unroll
    for (int off = 32; off; off >>= 1) s += __shfl_down(s, off);
    if (lane == 0) out[row] = s + consts[cidx];
}

__global__ __launch_bounds__(256) void weights_k(const float* __restrict__ a,
                                                 const float* __restrict__ b,
                                                 const float* __restrict__ bw,
                                                 float* __restrict__ w) {
    __shared__ float red[256];
    int i = blockIdx.x, tid = threadIdx.x;
    float ai = a[i] + bw[0];
    float r1 = ai + b[tid];
    float r2 = ai + b[tid + 256];
    float e1 = r1 > 0.f ? r1 : expm1f(r1);
    float e2 = r2 > 0.f ? r2 : expm1f(r2);
    red[tid] = e1 + e2;
    __syncthreads();
    for (int s = 128; s; s >>= 1) {
        if (tid < s) red[tid] += red[tid + s];
        __syncthreads();
    }
    float scale = 512.f / red[0];
    w[(size_t)i * NB + tid] = e1 * scale;
    w[(size_t)i * NB + tid + 256] = e2 * scale;
}

// ---------------- 128-tile f32 GEMM (M,N mult of 128; K mult of 16) ----------------
// mode 0: C=acc | 1: C=kmat*acc+diag(noise) | 2: C=kmat*acc | 3: C=C-acc | 4: C=-acc
// flags bit0 = lower_only (skip tiles strictly above diagonal; relative coords)
// flags bit1 = ktrim   (K limited to rowBase+128; lower-triangular A)
// flags bit2 = kstart  (K starts at colBase;       lower-triangular B)
template <int TA, int TB>
__global__ __launch_bounds__(256) void gemm128_k(int M, int N, int K,
                                                 const float* __restrict__ A, int lda, size_t zoffA,
                                                 const float* __restrict__ B, int ldb, size_t zoffB,
                                                 float* __restrict__ C, int ldc, size_t zoffC,
                                                 const float* __restrict__ kmat, int ldk,
                                                 const float* __restrict__ noisep,
                                                 int mode, int row0, int col0, int flags) {
    __shared__ float As[16][132];
    __shared__ float Bs[16][132];
    int bz = blockIdx.z;
    A += zoffA * bz; B += zoffB * bz; C += zoffC * bz;
    int bm = blockIdx.y, bn = blockIdx.x;
    int rowBase = bm * 128, colBase = bn * 128;
    if ((flags & 1) && (rowBase + 127) < colBase) return;
    int Kend = (flags & 2) ? ((rowBase + 128 < K) ? rowBase + 128 : K) : K;
    int Kstart = (flags & 4) ? colBase : 0;
    int tid = threadIdx.x;
    int tx = tid & 15, ty = tid >> 4;
    float acc[8][8];
#pragma unroll
    for (int i = 0; i < 8; ++i)
#pragma unroll
        for (int j = 0; j < 8; ++j) acc[i][j] = 0.f;

    for (int kk = Kstart; kk < Kend; kk += 16) {
        if (TA == 0) {
            int row = tid >> 1, koff = (tid & 1) * 8;
            const float* src = A + (size_t)(rowBase + row) * lda + kk + koff;
            float4 v0 = *(const float4*)(src);
            float4 v1 = *(const float4*)(src + 4);
            As[koff + 0][row] = v0.x; As[koff + 1][row] = v0.y;
            As[koff + 2][row] = v0.z; As[koff + 3][row] = v0.w;
            As[koff + 4][row] = v1.x; As[koff + 5][row] = v1.y;
            As[koff + 6][row] = v1.z; As[koff + 7][row] = v1.w;
        } else {
            int k = tid >> 4, ib = (tid & 15) * 4;
            const float* src = A + (size_t)(kk + k) * lda + rowBase + ib;
            *(float4*)&As[k][ib] = *(const float4*)src;
            *(float4*)&As[k][ib + 64] = *(const float4*)(src + 64);
        }
        if (TB == 0) {
            int k = tid >> 4, jb = (tid & 15) * 4;
            const float* src = B + (size_t)(kk + k) * ldb + colBase + jb;
            *(float4*)&Bs[k][jb] = *(const float4*)src;
            *(float4*)&Bs[k][jb + 64] = *(const float4*)(src + 64);
        } else {
            int col = tid >> 1, koff = (tid & 1) * 8;
            const float* src = B + (size_t)(colBase + col) * ldb + kk + koff;
            float4 v0 = *(const float4*)(src);
            float4 v1 = *(const float4*)(src + 4);
            Bs[koff + 0][col] = v0.x; Bs[koff + 1][col] = v0.y;
            Bs[koff + 2][col] = v0.z; Bs[koff + 3][col] = v0.w;
            Bs[koff + 4][col] = v1.x; Bs[koff + 5][col] = v1.y;
            Bs[koff + 6][col] = v1.z; Bs[koff + 7][col] = v1.w;
        }
        __syncthreads();
#pragma unroll
        for (int k = 0; k < 16; ++k) {
            float a[8], b[8];
            float4 t0 = *(const float4*)&As[k][ty * 4];
            float4 t1 = *(const float4*)&As[k][64 + ty * 4];
            float4 u0 = *(const float4*)&Bs[k][tx * 4];
            float4 u1 = *(const float4*)&Bs[k][64 + tx * 4];
            a[0] = t0.x; a[1] = t0.y; a[2] = t0.z; a[3] = t0.w;
            a[4] = t1.x; a[5] = t1.y; a[6] = t1.z; a[7] = t1.w;
            b[0] = u0.x; b[1] = u0.y; b[2] = u0.z; b[3] = u0.w;
            b[4] = u1.x; b[5] = u1.y; b[6] = u1.z; b[7] = u1.w;
#pragma unroll
            for (int i = 0; i < 8; ++i)
#pragma unroll
                for (int j = 0; j < 8; ++j) acc[i][j] += a[i] * b[j];
        }
        __syncthreads();
    }
#pragma unroll
    for (int i = 0; i < 8; ++i) {
        int gi = rowBase + ((i >> 2) << 6) + ty * 4 + (i & 3);
#pragma unroll
        for (int j = 0; j < 8; ++j) {
            int gj = colBase + ((j >> 2) << 6) + tx * 4 + (j & 3);
            float v = acc[i][j];
            if (mode == 1 || mode == 2) {
                v *= kmat[(size_t)gi * ldk + gj];
                if (mode == 1 && (row0 + gi) == (col0 + gj)) {
                    float ns = noisep[0];
                    ns = fminf(fmaxf(ns, 1e-5f), 1.0f);
                    v += ns;
                }
            } else if (mode == 3) {
                v = C[(size_t)gi * ldc + gj] - v;
            } else if (mode == 4) {
                v = -v;
            }
            C[(size_t)gi * ldc + gj] = v;
        }
    }
}

// ------- fused 128x128 diag Cholesky + triangular inverse (256 thr, dyn LDS) -------
// Reads lower triangle of the 128x128 diag block; writes back Dinv = L^{-1}
// (full 128x128, zeros in strict upper).
// Layout: s[r*DPAD + c] holds L (lower). X = L^{-1} is written TRANSPOSED into the
// strict upper area: X[r][c] (r>c) lives at s[c*DPAD + r]; diagonal in xdiag[].
// The inversion phase is sync-free: thread c only reads the lower triangle
// (never written during inversion), xdiag, and its own row c.
__global__ __launch_bounds__(256) void chol_diag_inv128_k(float* __restrict__ A, int lda) {
    extern __shared__ float s[];          // 128 * DPAD floats
    __shared__ float colbuf[128];
    __shared__ float xdiag[128];
    int tid = threadIdx.x;

    for (int idx = tid; idx < 128 * 128; idx += 256) {
        int r = idx >> 7, c = idx & 127;
        s[r * DPAD + c] = A[(size_t)r * lda + c];
    }
    __syncthreads();

    // right-looking Cholesky
    int b = tid >> 5, a = tid & 31;
    for (int k = 0; k < 128; ++k) {
        float inv = 1.0f / sqrtf(s[k * DPAD + k]);
        if (tid > k && tid < 128) {
            float v = s[tid * DPAD + k] * inv;
            s[tid * DPAD + k] = v;
            colbuf[tid] = v;
        }
        __syncthreads();
        for (int i = k + 1 + b; i < 128; i += 8) {
            float lik = colbuf[i];
            float* row = s + (size_t)i * DPAD;
            for (int j = k + 1 + a; j <= i; j += 32) {
                row[j] -= lik * colbuf[j];
            }
        }
        if (tid == k) s[k * DPAD + k] = 1.0f / (inv * inv * sqrtf(s[k * DPAD + k]));
        __syncthreads();
    }
    // note: diag write above sets s[k][k]=sqrt(orig) robustly: orig/(sqrt(orig)) = sqrt
    if (tid < 128) xdiag[tid] = 1.0f / s[tid * DPAD + tid];
    __syncthreads();

    // sync-free column-parallel inversion
    if (tid < 128) {
        int c = tid;
        float* xc = s + (size_t)c * DPAD;   // xc[r] (r>c) = X[r][c]
        float xdc = xdiag[c];
        for (int r = c + 1; r < 128; ++r) {
            const float* Lr = s + (size_t)r * DPAD;
            float accv = Lr[c] * xdc;                    // t = c
            for (int t = c + 1; t < r; ++t) accv += Lr[t] * xc[t];
            xc[r] = -accv * xdiag[r];
        }
    }
    __syncthreads();

    for (int idx = tid; idx < 128 * 128; idx += 256) {
        int r = idx >> 7, c = idx & 127;
        float v = (r == c) ? xdiag[r] : (r > c ? s[c * DPAD + r] : 0.f);
        A[(size_t)r * lda + c] = v;
    }
}

__global__ __launch_bounds__(256) void zero_upper_k(float* __restrict__ A, int n, int lda) {
    int i = blockIdx.x;
    for (int j = i + 1 + threadIdx.x; j < n; j += 256) A[(size_t)i * lda + j] = 0.f;
}

// z[row] = sum_{j<=row} L[row][j] * y[j]
__global__ __launch_bounds__(256) void gemv_lower_k(const float* __restrict__ L, int ld,
                                                    const float* __restrict__ y,
                                                    float* __restrict__ z, int n) {
    int wave = threadIdx.x >> 6, lane = threadIdx.x & 63;
    int row = blockIdx.x * 4 + wave;
    if (row >= n) return;
    const float* Lr = L + (size_t)row * ld;
    float s = 0.f;
    for (int j = lane; j <= row; j += 64) s += Lr[j] * y[j];
#pragma unroll
    for (int off = 32; off; off >>= 1) s += __shfl_down(s, off);
    if (lane == 0) z[row] = s;
}

// partials: part[by][j] = sum_{i in block-y range} Z[i][j]*zv[i]
__global__ __launch_bounds__(256) void resid_part_k(const float* __restrict__ Z,
                                                    const float* __restrict__ zv,
                                                    float* __restrict__ part) {
    int j = blockIdx.x * 256 + threadIdx.x;
    int i0 = blockIdx.y * 64;
    float acc = 0.f;
    for (int i = i0; i < i0 + 64; ++i) acc += Z[(size_t)i * NS + j] * zv[i];
    part[(size_t)blockIdx.y * NS + j] = acc;
}

__global__ __launch_bounds__(256) void resid_fin_k(const float* __restrict__ part,
                                                   const float* __restrict__ ty,
                                                   float* __restrict__ r) {
    int j = blockIdx.x * 256 + threadIdx.x;
    float acc = 0.f;
    for (int q = 0; q < 32; ++q) acc += part[(size_t)q * NS + j];
    r[j] = ty[j] - acc;
}

// loss = 0.5*sign*sum(log(diag)) + 0.5*||v||^2 + 0.5*n*log(2*pi)
__global__ __launch_bounds__(256) void loss_k(const float* __restrict__ Lc, int n, int ldl,
                                              float sign,
                                              const float* __restrict__ v,
                                              float* __restrict__ out) {
    __shared__ float red1[256];
    __shared__ float red2[256];
    int tid = threadIdx.x;
    float s1 = 0.f, s2 = 0.f;
    for (int i = tid; i < n; i += 256) {
        s1 += logf(Lc[(size_t)i * ldl + i]);
        float vi = v[i];
        s2 += vi * vi;
    }
    red1[tid] = s1;
    red2[tid] = s2;
    __syncthreads();
    for (int s = 128; s; s >>= 1) {
        if (tid < s) { red1[tid] += red1[tid + s]; red2[tid] += red2[tid + s]; }
        __syncthreads();
    }
    if (tid == 0) {
        out[0] = 0.5f * sign * red1[0] + 0.5f * red2[0] + 0.5f * (float)n * 1.8378770664093453f;
    }
}

// ---------------- host orchestration ----------------

static const size_t CHOL_LDS = (size_t)128 * DPAD * sizeof(float);  // 66 KB dynamic

// Blocked right-looking Cholesky, BS=128. On exit: off-diag lower blocks hold L,
// diag blocks hold Dinv (inverse of the 128x128 diagonal Cholesky factors,
// zeros in strict upper).
static void run_chol(float* A, hipStream_t stream) {
    for (int kb = 0; kb < 16; ++kb) {
        float* Ad = A + (size_t)kb * 128 * (NS + 1);
        chol_diag_inv128_k<<<1, 256, CHOL_LDS, stream>>>(Ad, NS);
        int rem = NS - (kb + 1) * 128;
        if (rem > 0) {
            float* P = A + (size_t)(kb + 1) * 128 * NS + kb * 128;
            // panel: P = P @ Dinv^T (in place)
            gemm128_k<0, 1><<<dim3(1, rem / 128), 256, 0, stream>>>(
                rem, 128, 128, P, NS, 0, Ad, NS, 0, P, NS, 0,
                nullptr, 0, nullptr, 0, 0, 0, 0);
            // trailing: C -= P P^T (lower tiles only)
            float* Ct = A + (size_t)(kb + 1) * 128 * (NS + 1);
            gemm128_k<0, 1><<<dim3(rem / 128, rem / 128), 256, 0, stream>>>(
                rem, rem, 128, P, NS, 0, P, NS, 0, Ct, NS, 0,
                nullptr, 0, nullptr, 3, 0, 0, 1);
        }
    }
}

// In-place recursive inversion of the lower-triangular factor in A
// (128-diag blocks already hold Dinv). T = scratch >= 1024^2 floats.
static void run_inv(float* A, float* T, hipStream_t stream) {
    zero_upper_k<<<NS, 256, 0, stream>>>(A, NS, NS);
    for (int s = 128; s <= 1024; s <<= 1) {
        int np = NS / (2 * s);
        size_t zz = (size_t)2 * s * (NS + 1);
        size_t zt = (size_t)s * s;
        dim3 g(s / 128, s / 128, np);
        // T = L21 @ X11   (X11 lower-tri -> kstart trim)
        gemm128_k<0, 0><<<g, 256, 0, stream>>>(s, s, s, A + (size_t)s * NS, NS, zz,
                                               A, NS, zz, T, s, zt,
                                               nullptr, 0, nullptr, 0, 0, 0, 4);
        // X21 = -X22 @ T  (X22 lower-tri -> ktrim)
        gemm128_k<0, 0><<<g, 256, 0, stream>>>(s, s, s, A + (size_t)s * (NS + 1), NS, zz,
                                               T, s, zt, A + (size_t)s * NS, NS, zz,
                                               nullptr, 0, nullptr, 4, 0, 0, 2);
    }
}

extern "C" void kernel_launch(void* const* d_in, const int* in_sizes, int n_in,
                              void* d_out, int out_size, void* d_ws, size_t ws_size,
                              hipStream_t stream) {
    const float* source_x = (const float*)d_in[0];
    const float* source_y = (const float*)d_in[1];
    const float* target_x = (const float*)d_in[2];
    const float* target_y = (const float*)d_in[3];
    const float* k_ss = (const float*)d_in[4];
    const float* k_tt = (const float*)d_in[5];
    const float* k_st = (const float*)d_in[6];
    const float* noise_s = (const float*)d_in[7];
    const float* noise_t = (const float*)d_in[8];
    const float* Wf = (const float*)d_in[9];
    const float* bf = (const float*)d_in[10];
    const float* Ws = (const float*)d_in[11];
    const float* bs = (const float*)d_in[12];
    const float* Wt = (const float*)d_in[13];
    const float* bt = (const float*)d_in[14];
    const float* Kb = (const float*)d_in[15];
    const float* base_s = (const float*)d_in[16];
    const float* base_t = (const float*)d_in[17];
    float* out = (float*)d_out;

    float* w = (float*)d_ws;
    const size_t M2 = (size_t)NS * NS;
    float* Ksrc = w;                 // K_src -> chol -> Linv (in place)
    float* Kcos = w + M2;
    float* Ktgt = w + 2 * M2;        // K_tgt -> cov -> Lc -> Lcinv (in place)
    float* stag = w + 3 * M2;        // wsb|wtb|wsK|wtK, later overlaid by Z
    float* wsb = stag;
    float* wtb = stag + (size_t)NS * NB;
    float* wsK = stag + 2 * (size_t)NS * NB;
    float* wtK = stag + 3 * (size_t)NS * NB;
    float* Z = stag;                 // 2048x2048, overlays staging
    float* T = w + 4 * M2;           // recursion temp / resid partials
    float* sm = T + (size_t)1024 * 1024;
    float* wcomb = sm;               // 1024
    float* consts = sm + 1024;       // 4
    float* a_s = sm + 1032;          // 2048
    float* b_s = a_s + NS;           // 512
    float* a_t = b_s + NB;           // 2048
    float* b_t = a_t + NS;           // 512
    float* rvec = b_t + NB;          // 2048
    float* vvec = rvec + NS;         // 2048
    float* z2 = vvec + NS;           // 2048

    // 1) feature maps + kernel weights
    prep_k<<<1, 256, 0, stream>>>(Wf, bf, Ws, Wt, wcomb, consts);
    matvec_k<<<NS / 4, 256, 0, stream>>>(source_x, NS, wcomb + 0 * DIMX, consts, 0, a_s);
    matvec_k<<<NB / 4, 256, 0, stream>>>(base_s, NB, wcomb + 1 * DIMX, consts, 1, b_s);
    matvec_k<<<NS / 4, 256, 0, stream>>>(target_x, NS, wcomb + 2 * DIMX, consts, 2, a_t);
    matvec_k<<<NB / 4, 256, 0, stream>>>(base_t, NB, wcomb + 3 * DIMX, consts, 3, b_t);
    weights_k<<<NS, 256, 0, stream>>>(a_s, b_s, bs, wsb);
    weights_k<<<NS, 256, 0, stream>>>(a_t, b_t, bt, wtb);

    // 2) wsK = ws@Kb, wtK = wt@Kb
    {
        dim3 g(NB / 128, NS / 128);
        gemm128_k<0, 0><<<g, 256, 0, stream>>>(NS, NB, NB, wsb, NB, 0, Kb, NB, 0, wsK, NB, 0,
                                               nullptr, 0, nullptr, 0, 0, 0, 0);
        gemm128_k<0, 0><<<g, 256, 0, stream>>>(NS, NB, NB, wtb, NB, 0, Kb, NB, 0, wtK, NB, 0,
                                               nullptr, 0, nullptr, 0, 0, 0, 0);
    }
    // 3) K_src, K_tgt, K_cos (Hadamard epilogues)
    {
        dim3 g(NS / 128, NS / 128);
        gemm128_k<0, 1><<<g, 256, 0, stream>>>(NS, NS, NB, wsK, NB, 0, wsb, NB, 0, Ksrc, NS, 0,
                                               k_ss, NS, noise_s, 1, 0, 0, 0);
        gemm128_k<0, 1><<<g, 256, 0, stream>>>(NS, NS, NB, wtK, NB, 0, wtb, NB, 0, Ktgt, NS, 0,
                                               k_tt, NS, noise_t, 1, 0, 0, 0);
        gemm128_k<0, 1><<<g, 256, 0, stream>>>(NS, NS, NB, wsK, NB, 0, wtb, NB, 0, Kcos, NS, 0,
                                               k_st, NS, nullptr, 2, 0, 0, 0);
    }

    // 4) Cholesky of K_src + full triangular inversion -> Linv in Ksrc
    run_chol(Ksrc, stream);
    run_inv(Ksrc, T, stream);

    // 5) Z = Linv @ Kcos (K trimmed to the lower band)
    {
        dim3 g(NS / 128, NS / 128);
        gemm128_k<0, 0><<<g, 256, 0, stream>>>(NS, NS, NS, Ksrc, NS, 0, Kcos, NS, 0, Z, NS, 0,
                                               nullptr, 0, nullptr, 0, 0, 0, 2);
    }

    // 6) z2 = Linv @ source_y ; r = target_y - Z^T z2
    gemv_lower_k<<<NS / 4, 256, 0, stream>>>(Ksrc, NS, source_y, z2, NS);
    resid_part_k<<<dim3(NS / 256, 32), 256, 0, stream>>>(Z, z2, T);
    resid_fin_k<<<NS / 256, 256, 0, stream>>>(T, target_y, rvec);

    // 7) cov = K_tgt - Z^T Z (lower tiles only)
    {
        dim3 g(NS / 128, NS / 128);
        gemm128_k<1, 0><<<g, 256, 0, stream>>>(NS, NS, NS, Z, NS, 0, Z, NS, 0, Ktgt, NS, 0,
                                               nullptr, 0, nullptr, 3, 0, 0, 1);
    }

    // 8) Cholesky of cov + full triangular inversion -> Lcinv in Ktgt
    run_chol(Ktgt, stream);
    run_inv(Ktgt, T, stream);

    // 9) v = Lcinv @ r ; loss (log diag(Lc) = -log diag(Lcinv))
    gemv_lower_k<<<NS / 4, 256, 0, stream>>>(Ktgt, NS, rvec, vvec, NS);
    loss_k<<<1, 256, 0, stream>>>(Ktgt, NS, NS, -1.0f, vvec, out);
}

// Round 6
// 11532.335 us; speedup vs baseline: 2.2496x; 1.2561x over previous
//
#include <hip/hip_runtime.h>
#include <hip/hip_bf16.h>
#include <math.h>

#define NS 2048
#define NB 512
#define DIMX 256
#define NFEAT 8
#define DPAD 129
#define BI 16
#define NBK 8

// ---------------- small prep kernels ----------------

__global__ __launch_bounds__(256) void prep_k(const float* __restrict__ Wf,
                                              const float* __restrict__ bf,
                                              const float* __restrict__ Ws,
                                              const float* __restrict__ Wt,
                                              float* __restrict__ wcomb,
                                              float* __restrict__ consts) {
    int d = threadIdx.x;
    float w0 = 0.f, w1 = 0.f, w2 = 0.f, w3 = 0.f;
#pragma unroll
    for (int k = 0; k < NFEAT; ++k) {
        float wf = Wf[k * DIMX + d];
        w0 += Ws[k] * wf;
        w1 += Ws[NFEAT + k] * wf;
        w2 += Wt[k] * wf;
        w3 += Wt[NFEAT + k] * wf;
    }
    wcomb[0 * DIMX + d] = w0;
    wcomb[1 * DIMX + d] = w1;
    wcomb[2 * DIMX + d] = w2;
    wcomb[3 * DIMX + d] = w3;
    if (d == 0) {
        float c0 = 0.f, c1 = 0.f, c2 = 0.f, c3 = 0.f;
#pragma unroll
        for (int k = 0; k < NFEAT; ++k) {
            c0 += Ws[k] * bf[k];
            c1 += Ws[NFEAT + k] * bf[k];
            c2 += Wt[k] * bf[k];
            c3 += Wt[NFEAT + k] * bf[k];
        }
        consts[0] = c0; consts[1] = c1; consts[2] = c2; consts[3] = c3;
    }
}

__global__ __launch_bounds__(256) void matvec_k(const float* __restrict__ X, int nrows,
                                                const float* __restrict__ wc,
                                                const float* __restrict__ consts, int cidx,
                                                float* __restrict__ out) {
    int wave = threadIdx.x >> 6, lane = threadIdx.x & 63;
    int row = blockIdx.x * 4 + wave;
    if (row >= nrows) return;
    const float* xr = X + (size_t)row * DIMX;
    float s = 0.f;
#pragma unroll
    for (int t = 0; t < 4; ++t) s += xr[lane + 64 * t] * wc[lane + 64 * t];
#pragma unroll
    for (int off = 32; off; off >>= 1) s += __shfl_down(s, off);
    if (lane == 0) out[row] = s + consts[cidx];
}

__global__ __launch_bounds__(256) void weights_k(const float* __restrict__ a,
                                                 const float* __restrict__ b,
                                                 const float* __restrict__ bw,
                                                 float* __restrict__ w) {
    __shared__ float red[256];
    int i = blockIdx.x, tid = threadIdx.x;
    float ai = a[i] + bw[0];
    float r1 = ai + b[tid];
    float r2 = ai + b[tid + 256];
    float e1 = r1 > 0.f ? r1 : expm1f(r1);
    float e2 = r2 > 0.f ? r2 : expm1f(r2);
    red[tid] = e1 + e2;
    __syncthreads();
    for (int s = 128; s; s >>= 1) {
        if (tid < s) red[tid] += red[tid + s];
        __syncthreads();
    }
    float scale = 512.f / red[0];
    w[(size_t)i * NB + tid] = e1 * scale;
    w[(size_t)i * NB + tid + 256] = e2 * scale;
}

// ---------------- 128-tile f32 GEMM (M,N mult of 128; K mult of 16) ----------------
// mode 0: C=acc | 1: C=kmat*acc+diag(noise) | 2: C=kmat*acc | 3: C=C-acc | 4: C=-acc
// flags bit0 = lower_only (skip tiles strictly above diagonal; relative coords)
// flags bit1 = ktrim   (K limited to rowBase+128; lower-triangular A)
// flags bit2 = kstart  (K starts at colBase;       lower-triangular B)
template <int TA, int TB>
__global__ __launch_bounds__(256) void gemm128_k(int M, int N, int K,
                                                 const float* __restrict__ A, int lda, size_t zoffA,
                                                 const float* __restrict__ B, int ldb, size_t zoffB,
                                                 float* __restrict__ C, int ldc, size_t zoffC,
                                                 const float* __restrict__ kmat, int ldk,
                                                 const float* __restrict__ noisep,
                                                 int mode, int row0, int col0, int flags) {
    __shared__ float As[16][132];
    __shared__ float Bs[16][132];
    int bz = blockIdx.z;
    A += zoffA * bz; B += zoffB * bz; C += zoffC * bz;
    int bm = blockIdx.y, bn = blockIdx.x;
    int rowBase = bm * 128, colBase = bn * 128;
    if ((flags & 1) && (rowBase + 127) < colBase) return;
    int Kend = (flags & 2) ? ((rowBase + 128 < K) ? rowBase + 128 : K) : K;
    int Kstart = (flags & 4) ? colBase : 0;
    int tid = threadIdx.x;
    int tx = tid & 15, ty = tid >> 4;
    float acc[8][8];
#pragma unroll
    for (int i = 0; i < 8; ++i)
#pragma unroll
        for (int j = 0; j < 8; ++j) acc[i][j] = 0.f;

    for (int kk = Kstart; kk < Kend; kk += 16) {
        if (TA == 0) {
            int row = tid >> 1, koff = (tid & 1) * 8;
            const float* src = A + (size_t)(rowBase + row) * lda + kk + koff;
            float4 v0 = *(const float4*)(src);
            float4 v1 = *(const float4*)(src + 4);
            As[koff + 0][row] = v0.x; As[koff + 1][row] = v0.y;
            As[koff + 2][row] = v0.z; As[koff + 3][row] = v0.w;
            As[koff + 4][row] = v1.x; As[koff + 5][row] = v1.y;
            As[koff + 6][row] = v1.z; As[koff + 7][row] = v1.w;
        } else {
            int k = tid >> 4, ib = (tid & 15) * 4;
            const float* src = A + (size_t)(kk + k) * lda + rowBase + ib;
            *(float4*)&As[k][ib] = *(const float4*)src;
            *(float4*)&As[k][ib + 64] = *(const float4*)(src + 64);
        }
        if (TB == 0) {
            int k = tid >> 4, jb = (tid & 15) * 4;
            const float* src = B + (size_t)(kk + k) * ldb + colBase + jb;
            *(float4*)&Bs[k][jb] = *(const float4*)src;
            *(float4*)&Bs[k][jb + 64] = *(const float4*)(src + 64);
        } else {
            int col = tid >> 1, koff = (tid & 1) * 8;
            const float* src = B + (size_t)(colBase + col) * ldb + kk + koff;
            float4 v0 = *(const float4*)(src);
            float4 v1 = *(const float4*)(src + 4);
            Bs[koff + 0][col] = v0.x; Bs[koff + 1][col] = v0.y;
            Bs[koff + 2][col] = v0.z; Bs[koff + 3][col] = v0.w;
            Bs[koff + 4][col] = v1.x; Bs[koff + 5][col] = v1.y;
            Bs[koff + 6][col] = v1.z; Bs[koff + 7][col] = v1.w;
        }
        __syncthreads();
#pragma unroll
        for (int k = 0; k < 16; ++k) {
            float a[8], b[8];
            float4 t0 = *(const float4*)&As[k][ty * 4];
            float4 t1 = *(const float4*)&As[k][64 + ty * 4];
            float4 u0 = *(const float4*)&Bs[k][tx * 4];
            float4 u1 = *(const float4*)&Bs[k][64 + tx * 4];
            a[0] = t0.x; a[1] = t0.y; a[2] = t0.z; a[3] = t0.w;
            a[4] = t1.x; a[5] = t1.y; a[6] = t1.z; a[7] = t1.w;
            b[0] = u0.x; b[1] = u0.y; b[2] = u0.z; b[3] = u0.w;
            b[4] = u1.x; b[5] = u1.y; b[6] = u1.z; b[7] = u1.w;
#pragma unroll
            for (int i = 0; i < 8; ++i)
#pragma unroll
                for (int j = 0; j < 8; ++j) acc[i][j] += a[i] * b[j];
        }
        __syncthreads();
    }
#pragma unroll
    for (int i = 0; i < 8; ++i) {
        int gi = rowBase + ((i >> 2) << 6) + ty * 4 + (i & 3);
#pragma unroll
        for (int j = 0; j < 8; ++j) {
            int gj = colBase + ((j >> 2) << 6) + tx * 4 + (j & 3);
            float v = acc[i][j];
            if (mode == 1 || mode == 2) {
                v *= kmat[(size_t)gi * ldk + gj];
                if (mode == 1 && (row0 + gi) == (col0 + gj)) {
                    float ns = noisep[0];
                    ns = fminf(fmaxf(ns, 1e-5f), 1.0f);
                    v += ns;
                }
            } else if (mode == 3) {
                v = C[(size_t)gi * ldc + gj] - v;
            } else if (mode == 4) {
                v = -v;
            }
            C[(size_t)gi * ldc + gj] = v;
        }
    }
}

// ------- fused 128x128 diag Cholesky + blocked triangular inverse (256 thr) -------
// Reads lower triangle of the 128x128 diag block; writes back Dinv = L^{-1}
// (full 128x128, zeros in strict upper).
// Layout: s[r*DPAD+c] holds L (lower triangle, off-diag blocks never overwritten).
// X = L^{-1}: off-diag blocks stored TRANSPOSED in the strict upper area
// (X[r][c], r>c, different 16-blocks -> s[c*DPAD+r]); 16x16 diag-block inverses
// live in xd[]. Inversion is blocked by block-diagonal offset d=1..7:
//   X_IJ = -Xd_I * ( L_IJ*Xd_J + sum_{K=J+1}^{I-1} L_IK * X_KJ )
// all (8-d) blocks of a diagonal computed in parallel, 2 barriers per d.
__global__ __launch_bounds__(256) void chol_diag_inv128_k(float* __restrict__ A, int lda) {
    extern __shared__ float s[];              // 128 * DPAD floats
    __shared__ float colbuf[128];
    __shared__ float xd[NBK][BI][BI + 1];     // diag-block inverses
    __shared__ float wbuf[NBK - 1][BI][BI + 1];
    int tid = threadIdx.x;

    for (int idx = tid; idx < 128 * 128; idx += 256) {
        int r = idx >> 7, c = idx & 127;
        s[r * DPAD + c] = A[(size_t)r * lda + c];
    }
    __syncthreads();

    // ---- right-looking Cholesky ----
    int b = tid >> 5, a = tid & 31;
    for (int k = 0; k < 128; ++k) {
        float dk = sqrtf(s[k * DPAD + k]);
        float inv = 1.0f / dk;
        if (tid > k && tid < 128) {
            float v = s[tid * DPAD + k] * inv;
            s[tid * DPAD + k] = v;
            colbuf[tid] = v;
        }
        __syncthreads();
        for (int i = k + 1 + b; i < 128; i += 8) {
            float lik = colbuf[i];
            float* row = s + (size_t)i * DPAD;
            for (int j = k + 1 + a; j <= i; j += 32) {
                row[j] -= lik * colbuf[j];
            }
        }
        if (tid == k) s[k * DPAD + k] = dk;
        __syncthreads();
    }

    // ---- phase A: invert the 8 diagonal 16x16 blocks (column-parallel) ----
    {
        int g = tid >> 4, l = tid & 15;
        if (g < NBK) {
            const float* Lb = s + (size_t)(g * BI) * DPAD + g * BI;  // row stride DPAD
            for (int r = 0; r < BI; ++r) {
                float acc = (r == l) ? 1.f : 0.f;
                for (int t = l; t < r; ++t) acc -= Lb[r * DPAD + t] * xd[g][t][l];
                xd[g][r][l] = (r >= l) ? acc / Lb[r * DPAD + r] : 0.f;
            }
        }
    }
    __syncthreads();

    // ---- phase B: off-diagonal blocks by diagonal offset ----
    for (int d = 1; d < NBK; ++d) {
        int npairs = NBK - d;
        for (int e = tid; e < npairs * 256; e += 256) {
            int p = e >> 8, ab = e & 255;
            int a2 = ab >> 4, b2 = ab & 15;
            int J = p, I = p + d;
            int Ibase = I * BI, Jbase = J * BI;
            float acc = 0.f;
            // K = J term: L_IJ * Xd_J
            {
                const float* Lr = s + (size_t)(Ibase + a2) * DPAD + Jbase;
                for (int t = 0; t < BI; ++t) acc += Lr[t] * xd[J][t][b2];
            }
            // K = J+1 .. I-1: L_IK * X_KJ  (X_KJ[t][b2] = s[(Jbase+b2)*DPAD + Kbase+t])
            for (int K = J + 1; K < I; ++K) {
                int Kbase = K * BI;
                const float* Lr = s + (size_t)(Ibase + a2) * DPAD + Kbase;
                const float* Xc = s + (size_t)(Jbase + b2) * DPAD + Kbase;
                for (int t = 0; t < BI; ++t) acc += Lr[t] * Xc[t];
            }
            wbuf[p][a2][b2] = acc;
        }
        __syncthreads();
        for (int e = tid; e < npairs * 256; e += 256) {
            int p = e >> 8, ab = e & 255;
            int a2 = ab >> 4, b2 = ab & 15;
            int J = p, I = p + d;
            float acc = 0.f;
            for (int t = 0; t < BI; ++t) acc += xd[I][a2][t] * wbuf[p][t][b2];
            s[(size_t)(J * BI + b2) * DPAD + I * BI + a2] = -acc;  // X_IJ[a2][b2], transposed store
        }
        __syncthreads();
    }

    // ---- write back full 128x128 Dinv (zeros in strict upper) ----
    for (int idx = tid; idx < 128 * 128; idx += 256) {
        int r = idx >> 7, c = idx & 127;
        float v;
        if (c > r) {
            v = 0.f;
        } else {
            int gr = r >> 4, gc = c >> 4;
            v = (gr == gc) ? xd[gr][r & 15][c & 15] : s[(size_t)c * DPAD + r];
        }
        A[(size_t)r * lda + c] = v;
    }
}

__global__ __launch_bounds__(256) void zero_upper_k(float* __restrict__ A, int n, int lda) {
    int i = blockIdx.x;
    for (int j = i + 1 + threadIdx.x; j < n; j += 256) A[(size_t)i * lda + j] = 0.f;
}

// z[row] = sum_{j<=row} L[row][j] * y[j]
__global__ __launch_bounds__(256) void gemv_lower_k(const float* __restrict__ L, int ld,
                                                    const float* __restrict__ y,
                                                    float* __restrict__ z, int n) {
    int wave = threadIdx.x >> 6, lane = threadIdx.x & 63;
    int row = blockIdx.x * 4 + wave;
    if (row >= n) return;
    const float* Lr = L + (size_t)row * ld;
    float s = 0.f;
    for (int j = lane; j <= row; j += 64) s += Lr[j] * y[j];
#pragma unroll
    for (int off = 32; off; off >>= 1) s += __shfl_down(s, off);
    if (lane == 0) z[row] = s;
}

// partials: part[by][j] = sum_{i in block-y range} Z[i][j]*zv[i]
__global__ __launch_bounds__(256) void resid_part_k(const float* __restrict__ Z,
                                                    const float* __restrict__ zv,
                                                    float* __restrict__ part) {
    int j = blockIdx.x * 256 + threadIdx.x;
    int i0 = blockIdx.y * 64;
    float acc = 0.f;
    for (int i = i0; i < i0 + 64; ++i) acc += Z[(size_t)i * NS + j] * zv[i];
    part[(size_t)blockIdx.y * NS + j] = acc;
}

__global__ __launch_bounds__(256) void resid_fin_k(const float* __restrict__ part,
                                                   const float* __restrict__ ty,
                                                   float* __restrict__ r) {
    int j = blockIdx.x * 256 + threadIdx.x;
    float acc = 0.f;
    for (int q = 0; q < 32; ++q) acc += part[(size_t)q * NS + j];
    r[j] = ty[j] - acc;
}

// loss = 0.5*sign*sum(log(diag)) + 0.5*||v||^2 + 0.5*n*log(2*pi)
__global__ __launch_bounds__(256) void loss_k(const float* __restrict__ Lc, int n, int ldl,
                                              float sign,
                                              const float* __restrict__ v,
                                              float* __restrict__ out) {
    __shared__ float red1[256];
    __shared__ float red2[256];
    int tid = threadIdx.x;
    float s1 = 0.f, s2 = 0.f;
    for (int i = tid; i < n; i += 256) {
        s1 += logf(Lc[(size_t)i * ldl + i]);
        float vi = v[i];
        s2 += vi * vi;
    }
    red1[tid] = s1;
    red2[tid] = s2;
    __syncthreads();
    for (int s = 128; s; s >>= 1) {
        if (tid < s) { red1[tid] += red1[tid + s]; red2[tid] += red2[tid + s]; }
        __syncthreads();
    }
    if (tid == 0) {
        out[0] = 0.5f * sign * red1[0] + 0.5f * red2[0] + 0.5f * (float)n * 1.8378770664093453f;
    }
}

// ---------------- host orchestration ----------------

static const size_t CHOL_LDS = (size_t)128 * DPAD * sizeof(float);  // 66 KB dynamic

// Blocked right-looking Cholesky, BS=128. On exit: off-diag lower blocks hold L,
// diag blocks hold Dinv (inverse of the 128x128 diagonal Cholesky factors,
// zeros in strict upper).
static void run_chol(float* A, hipStream_t stream) {
    for (int kb = 0; kb < 16; ++kb) {
        float* Ad = A + (size_t)kb * 128 * (NS + 1);
        chol_diag_inv128_k<<<1, 256, CHOL_LDS, stream>>>(Ad, NS);
        int rem = NS - (kb + 1) * 128;
        if (rem > 0) {
            float* P = A + (size_t)(kb + 1) * 128 * NS + kb * 128;
            // panel: P = P @ Dinv^T (in place)
            gemm128_k<0, 1><<<dim3(1, rem / 128), 256, 0, stream>>>(
                rem, 128, 128, P, NS, 0, Ad, NS, 0, P, NS, 0,
                nullptr, 0, nullptr, 0, 0, 0, 0);
            // trailing: C -= P P^T (lower tiles only)
            float* Ct = A + (size_t)(kb + 1) * 128 * (NS + 1);
            gemm128_k<0, 1><<<dim3(rem / 128, rem / 128), 256, 0, stream>>>(
                rem, rem, 128, P, NS, 0, P, NS, 0, Ct, NS, 0,
                nullptr, 0, nullptr, 3, 0, 0, 1);
        }
    }
}

// In-place recursive inversion of the lower-triangular factor in A
// (128-diag blocks already hold Dinv). T = scratch >= 1024^2 floats.
static void run_inv(float* A, float* T, hipStream_t stream) {
    zero_upper_k<<<NS, 256, 0, stream>>>(A, NS, NS);
    for (int s = 128; s <= 1024; s <<= 1) {
        int np = NS / (2 * s);
        size_t zz = (size_t)2 * s * (NS + 1);
        size_t zt = (size_t)s * s;
        dim3 g(s / 128, s / 128, np);
        // T = L21 @ X11   (X11 lower-tri -> kstart trim)
        gemm128_k<0, 0><<<g, 256, 0, stream>>>(s, s, s, A + (size_t)s * NS, NS, zz,
                                               A, NS, zz, T, s, zt,
                                               nullptr, 0, nullptr, 0, 0, 0, 4);
        // X21 = -X22 @ T  (X22 lower-tri -> ktrim)
        gemm128_k<0, 0><<<g, 256, 0, stream>>>(s, s, s, A + (size_t)s * (NS + 1), NS, zz,
                                               T, s, zt, A + (size_t)s * NS, NS, zz,
                                               nullptr, 0, nullptr, 4, 0, 0, 2);
    }
}

extern "C" void kernel_launch(void* const* d_in, const int* in_sizes, int n_in,
                              void* d_out, int out_size, void* d_ws, size_t ws_size,
                              hipStream_t stream) {
    const float* source_x = (const float*)d_in[0];
    const float* source_y = (const float*)d_in[1];
    const float* target_x = (const float*)d_in[2];
    const float* target_y = (const float*)d_in[3];
    const float* k_ss = (const float*)d_in[4];
    const float* k_tt = (const float*)d_in[5];
    const float* k_st = (const float*)d_in[6];
    const float* noise_s = (const float*)d_in[7];
    const float* noise_t = (const float*)d_in[8];
    const float* Wf = (const float*)d_in[9];
    const float* bf = (const float*)d_in[10];
    const float* Ws = (const float*)d_in[11];
    const float* bs = (const float*)d_in[12];
    const float* Wt = (const float*)d_in[13];
    const float* bt = (const float*)d_in[14];
    const float* Kb = (const float*)d_in[15];
    const float* base_s = (const float*)d_in[16];
    const float* base_t = (const float*)d_in[17];
    float* out = (float*)d_out;

    float* w = (float*)d_ws;
    const size_t M2 = (size_t)NS * NS;
    float* Ksrc = w;                 // K_src -> chol -> Linv (in place)
    float* Kcos = w + M2;
    float* Ktgt = w + 2 * M2;        // K_tgt -> cov -> Lc -> Lcinv (in place)
    float* stag = w + 3 * M2;        // wsb|wtb|wsK|wtK, later overlaid by Z
    float* wsb = stag;
    float* wtb = stag + (size_t)NS * NB;
    float* wsK = stag + 2 * (size_t)NS * NB;
    float* wtK = stag + 3 * (size_t)NS * NB;
    float* Z = stag;                 // 2048x2048, overlays staging
    float* T = w + 4 * M2;           // recursion temp / resid partials
    float* sm = T + (size_t)1024 * 1024;
    float* wcomb = sm;               // 1024
    float* consts = sm + 1024;       // 4
    float* a_s = sm + 1032;          // 2048
    float* b_s = a_s + NS;           // 512
    float* a_t = b_s + NB;           // 2048
    float* b_t = a_t + NS;           // 512
    float* rvec = b_t + NB;          // 2048
    float* vvec = rvec + NS;         // 2048
    float* z2 = vvec + NS;           // 2048

    // 1) feature maps + kernel weights
    prep_k<<<1, 256, 0, stream>>>(Wf, bf, Ws, Wt, wcomb, consts);
    matvec_k<<<NS / 4, 256, 0, stream>>>(source_x, NS, wcomb + 0 * DIMX, consts, 0, a_s);
    matvec_k<<<NB / 4, 256, 0, stream>>>(base_s, NB, wcomb + 1 * DIMX, consts, 1, b_s);
    matvec_k<<<NS / 4, 256, 0, stream>>>(target_x, NS, wcomb + 2 * DIMX, consts, 2, a_t);
    matvec_k<<<NB / 4, 256, 0, stream>>>(base_t, NB, wcomb + 3 * DIMX, consts, 3, b_t);
    weights_k<<<NS, 256, 0, stream>>>(a_s, b_s, bs, wsb);
    weights_k<<<NS, 256, 0, stream>>>(a_t, b_t, bt, wtb);

    // 2) wsK = ws@Kb, wtK = wt@Kb
    {
        dim3 g(NB / 128, NS / 128);
        gemm128_k<0, 0><<<g, 256, 0, stream>>>(NS, NB, NB, wsb, NB, 0, Kb, NB, 0, wsK, NB, 0,
                                               nullptr, 0, nullptr, 0, 0, 0, 0);
        gemm128_k<0, 0><<<g, 256, 0, stream>>>(NS, NB, NB, wtb, NB, 0, Kb, NB, 0, wtK, NB, 0,
                                               nullptr, 0, nullptr, 0, 0, 0, 0);
    }
    // 3) K_src, K_tgt, K_cos (Hadamard epilogues)
    {
        dim3 g(NS / 128, NS / 128);
        gemm128_k<0, 1><<<g, 256, 0, stream>>>(NS, NS, NB, wsK, NB, 0, wsb, NB, 0, Ksrc, NS, 0,
                                               k_ss, NS, noise_s, 1, 0, 0, 0);
        gemm128_k<0, 1><<<g, 256, 0, stream>>>(NS, NS, NB, wtK, NB, 0, wtb, NB, 0, Ktgt, NS, 0,
                                               k_tt, NS, noise_t, 1, 0, 0, 0);
        gemm128_k<0, 1><<<g, 256, 0, stream>>>(NS, NS, NB, wsK, NB, 0, wtb, NB, 0, Kcos, NS, 0,
                                               k_st, NS, nullptr, 2, 0, 0, 0);
    }

    // 4) Cholesky of K_src + full triangular inversion -> Linv in Ksrc
    run_chol(Ksrc, stream);
    run_inv(Ksrc, T, stream);

    // 5) Z = Linv @ Kcos (K trimmed to the lower band)
    {
        dim3 g(NS / 128, NS / 128);
        gemm128_k<0, 0><<<g, 256, 0, stream>>>(NS, NS, NS, Ksrc, NS, 0, Kcos, NS, 0, Z, NS, 0,
                                               nullptr, 0, nullptr, 0, 0, 0, 2);
    }

    // 6) z2 = Linv @ source_y ; r = target_y - Z^T z2
    gemv_lower_k<<<NS / 4, 256, 0, stream>>>(Ksrc, NS, source_y, z2, NS);
    resid_part_k<<<dim3(NS / 256, 32), 256, 0, stream>>>(Z, z2, T);
    resid_fin_k<<<NS / 256, 256, 0, stream>>>(T, target_y, rvec);

    // 7) cov = K_tgt - Z^T Z (lower tiles only)
    {
        dim3 g(NS / 128, NS / 128);
        gemm128_k<1, 0><<<g, 256, 0, stream>>>(NS, NS, NS, Z, NS, 0, Z, NS, 0, Ktgt, NS, 0,
                                               nullptr, 0, nullptr, 3, 0, 0, 1);
    }

    // 8) Cholesky of cov + full triangular inversion -> Lcinv in Ktgt
    run_chol(Ktgt, stream);
    run_inv(Ktgt, T, stream);

    // 9) v = Lcinv @ r ; loss (log diag(Lc) = -log diag(Lcinv))
    gemv_lower_k<<<NS / 4, 256, 0, stream>>>(Ktgt, NS, rvec, vvec, NS);
    loss_k<<<1, 256, 0, stream>>>(Ktgt, NS, NS, -1.0f, vvec, out);
}

// Round 7
// 10895.347 us; speedup vs baseline: 2.3811x; 1.0585x over previous
//
#include <hip/hip_runtime.h>
#include <hip/hip_bf16.h>
#include <math.h>

#define NS 2048
#define NB 512
#define DIMX 256
#define NFEAT 8
#define DPAD 129
#define BI 16
#define NBK 8

// ---------------- small prep kernels ----------------

__global__ __launch_bounds__(256) void prep_k(const float* __restrict__ Wf,
                                              const float* __restrict__ bf,
                                              const float* __restrict__ Ws,
                                              const float* __restrict__ Wt,
                                              float* __restrict__ wcomb,
                                              float* __restrict__ consts) {
    int d = threadIdx.x;
    float w0 = 0.f, w1 = 0.f, w2 = 0.f, w3 = 0.f;
#pragma unroll
    for (int k = 0; k < NFEAT; ++k) {
        float wf = Wf[k * DIMX + d];
        w0 += Ws[k] * wf;
        w1 += Ws[NFEAT + k] * wf;
        w2 += Wt[k] * wf;
        w3 += Wt[NFEAT + k] * wf;
    }
    wcomb[0 * DIMX + d] = w0;
    wcomb[1 * DIMX + d] = w1;
    wcomb[2 * DIMX + d] = w2;
    wcomb[3 * DIMX + d] = w3;
    if (d == 0) {
        float c0 = 0.f, c1 = 0.f, c2 = 0.f, c3 = 0.f;
#pragma unroll
        for (int k = 0; k < NFEAT; ++k) {
            c0 += Ws[k] * bf[k];
            c1 += Ws[NFEAT + k] * bf[k];
            c2 += Wt[k] * bf[k];
            c3 += Wt[NFEAT + k] * bf[k];
        }
        consts[0] = c0; consts[1] = c1; consts[2] = c2; consts[3] = c3;
    }
}

__global__ __launch_bounds__(256) void matvec_k(const float* __restrict__ X, int nrows,
                                                const float* __restrict__ wc,
                                                const float* __restrict__ consts, int cidx,
                                                float* __restrict__ out) {
    int wave = threadIdx.x >> 6, lane = threadIdx.x & 63;
    int row = blockIdx.x * 4 + wave;
    if (row >= nrows) return;
    const float* xr = X + (size_t)row * DIMX;
    float s = 0.f;
#pragma unroll
    for (int t = 0; t < 4; ++t) s += xr[lane + 64 * t] * wc[lane + 64 * t];
#pragma unroll
    for (int off = 32; off; off >>= 1) s += __shfl_down(s, off);
    if (lane == 0) out[row] = s + consts[cidx];
}

__global__ __launch_bounds__(256) void weights_k(const float* __restrict__ a,
                                                 const float* __restrict__ b,
                                                 const float* __restrict__ bw,
                                                 float* __restrict__ w) {
    __shared__ float red[256];
    int i = blockIdx.x, tid = threadIdx.x;
    float ai = a[i] + bw[0];
    float r1 = ai + b[tid];
    float r2 = ai + b[tid + 256];
    float e1 = r1 > 0.f ? r1 : expm1f(r1);
    float e2 = r2 > 0.f ? r2 : expm1f(r2);
    red[tid] = e1 + e2;
    __syncthreads();
    for (int s = 128; s; s >>= 1) {
        if (tid < s) red[tid] += red[tid + s];
        __syncthreads();
    }
    float scale = 512.f / red[0];
    w[(size_t)i * NB + tid] = e1 * scale;
    w[(size_t)i * NB + tid + 256] = e2 * scale;
}

// ---------------- 128-tile f32 GEMM (M,N mult of 128; K mult of 16) ----------------
// mode 0: C=acc | 1: C=kmat*acc+diag(noise) | 2: C=kmat*acc | 3: C=C-acc | 4: C=-acc
// flags bit0 = lower_only; bit1 = ktrim (K<=rowBase+128); bit2 = kstart (K from colBase)
// XCD-aware bijective block swizzle + register double-buffered staging.
template <int TA, int TB>
__global__ __launch_bounds__(256) void gemm128_k(int M, int N, int K,
                                                 const float* __restrict__ A, int lda, size_t zoffA,
                                                 const float* __restrict__ B, int ldb, size_t zoffB,
                                                 float* __restrict__ C, int ldc, size_t zoffC,
                                                 const float* __restrict__ kmat, int ldk,
                                                 const float* __restrict__ noisep,
                                                 int mode, int row0, int col0, int flags) {
    __shared__ float As[16][132];
    __shared__ float Bs[16][132];
    int bz = blockIdx.z;
    A += zoffA * bz; B += zoffB * bz; C += zoffC * bz;

    // bijective XCD swizzle (m204): contiguous tile chunks per XCD
    int gx = gridDim.x;
    int nwg = gx * gridDim.y;
    int flat = blockIdx.y * gx + blockIdx.x;
    int qq = nwg >> 3, rr = nwg & 7;
    int xcd = flat & 7, pos = flat >> 3;
    int swz = (xcd < rr) ? (xcd * (qq + 1) + pos)
                         : (rr * (qq + 1) + (xcd - rr) * qq + pos);
    int bm = swz / gx, bn = swz % gx;

    int rowBase = bm * 128, colBase = bn * 128;
    if ((flags & 1) && (rowBase + 127) < colBase) return;
    int Kend = (flags & 2) ? ((rowBase + 128 < K) ? rowBase + 128 : K) : K;
    int Kstart = (flags & 4) ? colBase : 0;
    int tid = threadIdx.x;
    int tx = tid & 15, ty = tid >> 4;
    float acc[8][8];
#pragma unroll
    for (int i = 0; i < 8; ++i)
#pragma unroll
        for (int j = 0; j < 8; ++j) acc[i][j] = 0.f;

    float ra[8], rb[8];
    auto loadA = [&](int kk) {
        if (TA == 0) {
            int row = tid >> 1, koff = (tid & 1) * 8;
            const float* src = A + (size_t)(rowBase + row) * lda + kk + koff;
            float4 v0 = *(const float4*)(src);
            float4 v1 = *(const float4*)(src + 4);
            ra[0] = v0.x; ra[1] = v0.y; ra[2] = v0.z; ra[3] = v0.w;
            ra[4] = v1.x; ra[5] = v1.y; ra[6] = v1.z; ra[7] = v1.w;
        } else {
            int k = tid >> 4, ib = (tid & 15) * 4;
            const float* src = A + (size_t)(kk + k) * lda + rowBase + ib;
            float4 v0 = *(const float4*)src;
            float4 v1 = *(const float4*)(src + 64);
            ra[0] = v0.x; ra[1] = v0.y; ra[2] = v0.z; ra[3] = v0.w;
            ra[4] = v1.x; ra[5] = v1.y; ra[6] = v1.z; ra[7] = v1.w;
        }
    };
    auto storeA = [&]() {
        if (TA == 0) {
            int row = tid >> 1, koff = (tid & 1) * 8;
#pragma unroll
            for (int q = 0; q < 8; ++q) As[koff + q][row] = ra[q];
        } else {
            int k = tid >> 4, ib = (tid & 15) * 4;
#pragma unroll
            for (int q = 0; q < 4; ++q) As[k][ib + q] = ra[q];
#pragma unroll
            for (int q = 0; q < 4; ++q) As[k][ib + 64 + q] = ra[4 + q];
        }
    };
    auto loadB = [&](int kk) {
        if (TB == 0) {
            int k = tid >> 4, jb = (tid & 15) * 4;
            const float* src = B + (size_t)(kk + k) * ldb + colBase + jb;
            float4 v0 = *(const float4*)src;
            float4 v1 = *(const float4*)(src + 64);
            rb[0] = v0.x; rb[1] = v0.y; rb[2] = v0.z; rb[3] = v0.w;
            rb[4] = v1.x; rb[5] = v1.y; rb[6] = v1.z; rb[7] = v1.w;
        } else {
            int col = tid >> 1, koff = (tid & 1) * 8;
            const float* src = B + (size_t)(colBase + col) * ldb + kk + koff;
            float4 v0 = *(const float4*)(src);
            float4 v1 = *(const float4*)(src + 4);
            rb[0] = v0.x; rb[1] = v0.y; rb[2] = v0.z; rb[3] = v0.w;
            rb[4] = v1.x; rb[5] = v1.y; rb[6] = v1.z; rb[7] = v1.w;
        }
    };
    auto storeB = [&]() {
        if (TB == 0) {
            int k = tid >> 4, jb = (tid & 15) * 4;
#pragma unroll
            for (int q = 0; q < 4; ++q) Bs[k][jb + q] = rb[q];
#pragma unroll
            for (int q = 0; q < 4; ++q) Bs[k][jb + 64 + q] = rb[4 + q];
        } else {
            int col = tid >> 1, koff = (tid & 1) * 8;
#pragma unroll
            for (int q = 0; q < 8; ++q) Bs[koff + q][col] = rb[q];
        }
    };

    if (Kstart < Kend) {
        loadA(Kstart);
        loadB(Kstart);
    }
    for (int kk = Kstart; kk < Kend; kk += 16) {
        storeA();
        storeB();
        __syncthreads();
        if (kk + 16 < Kend) {   // prefetch next tile while computing this one
            loadA(kk + 16);
            loadB(kk + 16);
        }
#pragma unroll
        for (int k = 0; k < 16; ++k) {
            float a[8], b[8];
            float4 t0 = *(const float4*)&As[k][ty * 4];
            float4 t1 = *(const float4*)&As[k][64 + ty * 4];
            float4 u0 = *(const float4*)&Bs[k][tx * 4];
            float4 u1 = *(const float4*)&Bs[k][64 + tx * 4];
            a[0] = t0.x; a[1] = t0.y; a[2] = t0.z; a[3] = t0.w;
            a[4] = t1.x; a[5] = t1.y; a[6] = t1.z; a[7] = t1.w;
            b[0] = u0.x; b[1] = u0.y; b[2] = u0.z; b[3] = u0.w;
            b[4] = u1.x; b[5] = u1.y; b[6] = u1.z; b[7] = u1.w;
#pragma unroll
            for (int i = 0; i < 8; ++i)
#pragma unroll
                for (int j = 0; j < 8; ++j) acc[i][j] += a[i] * b[j];
        }
        __syncthreads();
    }
#pragma unroll
    for (int i = 0; i < 8; ++i) {
        int gi = rowBase + ((i >> 2) << 6) + ty * 4 + (i & 3);
#pragma unroll
        for (int j = 0; j < 8; ++j) {
            int gj = colBase + ((j >> 2) << 6) + tx * 4 + (j & 3);
            float v = acc[i][j];
            if (mode == 1 || mode == 2) {
                v *= kmat[(size_t)gi * ldk + gj];
                if (mode == 1 && (row0 + gi) == (col0 + gj)) {
                    float ns = noisep[0];
                    ns = fminf(fmaxf(ns, 1e-5f), 1.0f);
                    v += ns;
                }
            } else if (mode == 3) {
                v = C[(size_t)gi * ldc + gj] - v;
            } else if (mode == 4) {
                v = -v;
            }
            C[(size_t)gi * ldc + gj] = v;
        }
    }
}

// ------- fused 128x128 diag Cholesky + blocked triangular inverse (256 thr) -------
// Deferred-scaling Cholesky (raw columns, 1/d^2 rank-1 updates): ONE barrier per k.
// Then scale to true L, then blocked inversion (16x16 blocks, by diagonal offset),
// X stored transposed in strict upper. Writes back Dinv = L^{-1}.
__global__ __launch_bounds__(256) void chol_diag_inv128_k(float* __restrict__ A, int lda) {
    extern __shared__ float s[];              // 128 * DPAD floats
    __shared__ float rsd[128];                // rsqrt of final diag (d_k^2)
    __shared__ float xd[NBK][BI][BI + 1];     // diag-block inverses
    __shared__ float wbuf[NBK - 1][BI][BI + 1];
    int tid = threadIdx.x;

    for (int idx = tid; idx < 128 * 128; idx += 256) {
        int r = idx >> 7, c = idx & 127;
        s[r * DPAD + c] = A[(size_t)r * lda + c];
    }
    __syncthreads();

    // ---- deferred-scaling right-looking Cholesky: s[i][k] stays raw; s[k][k]=d_k^2
    int b = tid >> 5, a = tid & 31;
    for (int k = 0; k < 128; ++k) {
        float isq = 1.0f / s[k * DPAD + k];
        for (int i = k + 1 + b; i < 128; i += 8) {
            float f = s[i * DPAD + k] * isq;
            float* row = s + (size_t)i * DPAD;
            for (int j = k + 1 + a; j <= i; j += 32) {
                row[j] -= f * s[j * DPAD + k];
            }
        }
        __syncthreads();
    }

    // ---- scale to true L: L[i][k] = raw[i][k]/d_k, L[k][k] = d_k
    if (tid < 128) rsd[tid] = rsqrtf(s[tid * DPAD + tid]);
    __syncthreads();
    for (int idx = tid; idx < 128 * 128; idx += 256) {
        int r = idx >> 7, c = idx & 127;
        if (c < r) s[r * DPAD + c] *= rsd[c];
        else if (c == r) s[r * DPAD + r] = 1.0f / rsd[r];
    }
    __syncthreads();

    // ---- phase A: invert the 8 diagonal 16x16 blocks (column-parallel) ----
    {
        int g = tid >> 4, l = tid & 15;
        if (g < NBK) {
            const float* Lb = s + (size_t)(g * BI) * DPAD + g * BI;
            for (int r = 0; r < BI; ++r) {
                float acc = (r == l) ? 1.f : 0.f;
                for (int t = l; t < r; ++t) acc -= Lb[r * DPAD + t] * xd[g][t][l];
                xd[g][r][l] = (r >= l) ? acc / Lb[r * DPAD + r] : 0.f;
            }
        }
    }
    __syncthreads();

    // ---- phase B: off-diagonal blocks by diagonal offset ----
    for (int d = 1; d < NBK; ++d) {
        int npairs = NBK - d;
        for (int e = tid; e < npairs * 256; e += 256) {
            int p = e >> 8, ab = e & 255;
            int a2 = ab >> 4, b2 = ab & 15;
            int J = p, I = p + d;
            int Ibase = I * BI, Jbase = J * BI;
            float acc = 0.f;
            {
                const float* Lr = s + (size_t)(Ibase + a2) * DPAD + Jbase;
                for (int t = 0; t < BI; ++t) acc += Lr[t] * xd[J][t][b2];
            }
            for (int K = J + 1; K < I; ++K) {
                int Kbase = K * BI;
                const float* Lr = s + (size_t)(Ibase + a2) * DPAD + Kbase;
                const float* Xc = s + (size_t)(Jbase + b2) * DPAD + Kbase;
                for (int t = 0; t < BI; ++t) acc += Lr[t] * Xc[t];
            }
            wbuf[p][a2][b2] = acc;
        }
        __syncthreads();
        for (int e = tid; e < npairs * 256; e += 256) {
            int p = e >> 8, ab = e & 255;
            int a2 = ab >> 4, b2 = ab & 15;
            int J = p, I = p + d;
            float acc = 0.f;
            for (int t = 0; t < BI; ++t) acc += xd[I][a2][t] * wbuf[p][t][b2];
            s[(size_t)(J * BI + b2) * DPAD + I * BI + a2] = -acc;
        }
        __syncthreads();
    }

    // ---- write back full 128x128 Dinv (zeros in strict upper) ----
    for (int idx = tid; idx < 128 * 128; idx += 256) {
        int r = idx >> 7, c = idx & 127;
        float v;
        if (c > r) {
            v = 0.f;
        } else {
            int gr = r >> 4, gc = c >> 4;
            v = (gr == gc) ? xd[gr][r & 15][c & 15] : s[(size_t)c * DPAD + r];
        }
        A[(size_t)r * lda + c] = v;
    }
}

__global__ __launch_bounds__(256) void zero_upper_k(float* __restrict__ A, int n, int lda) {
    int i = blockIdx.x;
    for (int j = i + 1 + threadIdx.x; j < n; j += 256) A[(size_t)i * lda + j] = 0.f;
}

// z[row] = sum_{j<=row} L[row][j] * y[j]
__global__ __launch_bounds__(256) void gemv_lower_k(const float* __restrict__ L, int ld,
                                                    const float* __restrict__ y,
                                                    float* __restrict__ z, int n) {
    int wave = threadIdx.x >> 6, lane = threadIdx.x & 63;
    int row = blockIdx.x * 4 + wave;
    if (row >= n) return;
    const float* Lr = L + (size_t)row * ld;
    float s = 0.f;
    for (int j = lane; j <= row; j += 64) s += Lr[j] * y[j];
#pragma unroll
    for (int off = 32; off; off >>= 1) s += __shfl_down(s, off);
    if (lane == 0) z[row] = s;
}

// partials: part[by][j] = sum_{i in block-y range} Z[i][j]*zv[i]
__global__ __launch_bounds__(256) void resid_part_k(const float* __restrict__ Z,
                                                    const float* __restrict__ zv,
                                                    float* __restrict__ part) {
    int j = blockIdx.x * 256 + threadIdx.x;
    int i0 = blockIdx.y * 64;
    float acc = 0.f;
    for (int i = i0; i < i0 + 64; ++i) acc += Z[(size_t)i * NS + j] * zv[i];
    part[(size_t)blockIdx.y * NS + j] = acc;
}

__global__ __launch_bounds__(256) void resid_fin_k(const float* __restrict__ part,
                                                   const float* __restrict__ ty,
                                                   float* __restrict__ r) {
    int j = blockIdx.x * 256 + threadIdx.x;
    float acc = 0.f;
    for (int q = 0; q < 32; ++q) acc += part[(size_t)q * NS + j];
    r[j] = ty[j] - acc;
}

// loss = 0.5*sign*sum(log(diag)) + 0.5*||v||^2 + 0.5*n*log(2*pi)
__global__ __launch_bounds__(256) void loss_k(const float* __restrict__ Lc, int n, int ldl,
                                              float sign,
                                              const float* __restrict__ v,
                                              float* __restrict__ out) {
    __shared__ float red1[256];
    __shared__ float red2[256];
    int tid = threadIdx.x;
    float s1 = 0.f, s2 = 0.f;
    for (int i = tid; i < n; i += 256) {
        s1 += logf(Lc[(size_t)i * ldl + i]);
        float vi = v[i];
        s2 += vi * vi;
    }
    red1[tid] = s1;
    red2[tid] = s2;
    __syncthreads();
    for (int s = 128; s; s >>= 1) {
        if (tid < s) { red1[tid] += red1[tid + s]; red2[tid] += red2[tid + s]; }
        __syncthreads();
    }
    if (tid == 0) {
        out[0] = 0.5f * sign * red1[0] + 0.5f * red2[0] + 0.5f * (float)n * 1.8378770664093453f;
    }
}

// ---------------- host orchestration ----------------

static const size_t CHOL_LDS = (size_t)128 * DPAD * sizeof(float);  // 66 KB dynamic

static void run_chol(float* A, hipStream_t stream) {
    for (int kb = 0; kb < 16; ++kb) {
        float* Ad = A + (size_t)kb * 128 * (NS + 1);
        chol_diag_inv128_k<<<1, 256, CHOL_LDS, stream>>>(Ad, NS);
        int rem = NS - (kb + 1) * 128;
        if (rem > 0) {
            float* P = A + (size_t)(kb + 1) * 128 * NS + kb * 128;
            gemm128_k<0, 1><<<dim3(1, rem / 128), 256, 0, stream>>>(
                rem, 128, 128, P, NS, 0, Ad, NS, 0, P, NS, 0,
                nullptr, 0, nullptr, 0, 0, 0, 0);
            float* Ct = A + (size_t)(kb + 1) * 128 * (NS + 1);
            gemm128_k<0, 1><<<dim3(rem / 128, rem / 128), 256, 0, stream>>>(
                rem, rem, 128, P, NS, 0, P, NS, 0, Ct, NS, 0,
                nullptr, 0, nullptr, 3, 0, 0, 1);
        }
    }
}

static void run_inv(float* A, float* T, hipStream_t stream) {
    zero_upper_k<<<NS, 256, 0, stream>>>(A, NS, NS);
    for (int s = 128; s <= 1024; s <<= 1) {
        int np = NS / (2 * s);
        size_t zz = (size_t)2 * s * (NS + 1);
        size_t zt = (size_t)s * s;
        dim3 g(s / 128, s / 128, np);
        gemm128_k<0, 0><<<g, 256, 0, stream>>>(s, s, s, A + (size_t)s * NS, NS, zz,
                                               A, NS, zz, T, s, zt,
                                               nullptr, 0, nullptr, 0, 0, 0, 4);
        gemm128_k<0, 0><<<g, 256, 0, stream>>>(s, s, s, A + (size_t)s * (NS + 1), NS, zz,
                                               T, s, zt, A + (size_t)s * NS, NS, zz,
                                               nullptr, 0, nullptr, 4, 0, 0, 2);
    }
}

extern "C" void kernel_launch(void* const* d_in, const int* in_sizes, int n_in,
                              void* d_out, int out_size, void* d_ws, size_t ws_size,
                              hipStream_t stream) {
    const float* source_x = (const float*)d_in[0];
    const float* source_y = (const float*)d_in[1];
    const float* target_x = (const float*)d_in[2];
    const float* target_y = (const float*)d_in[3];
    const float* k_ss = (const float*)d_in[4];
    const float* k_tt = (const float*)d_in[5];
    const float* k_st = (const float*)d_in[6];
    const float* noise_s = (const float*)d_in[7];
    const float* noise_t = (const float*)d_in[8];
    const float* Wf = (const float*)d_in[9];
    const float* bf = (const float*)d_in[10];
    const float* Ws = (const float*)d_in[11];
    const float* bs = (const float*)d_in[12];
    const float* Wt = (const float*)d_in[13];
    const float* bt = (const float*)d_in[14];
    const float* Kb = (const float*)d_in[15];
    const float* base_s = (const float*)d_in[16];
    const float* base_t = (const float*)d_in[17];
    float* out = (float*)d_out;

    float* w = (float*)d_ws;
    const size_t M2 = (size_t)NS * NS;
    float* Ksrc = w;                 // K_src -> chol -> Linv (in place)
    float* Kcos = w + M2;
    float* Ktgt = w + 2 * M2;        // K_tgt -> cov -> Lc -> Lcinv (in place)
    float* stag = w + 3 * M2;        // wsb|wtb|wsK|wtK, later overlaid by Z
    float* wsb = stag;
    float* wtb = stag + (size_t)NS * NB;
    float* wsK = stag + 2 * (size_t)NS * NB;
    float* wtK = stag + 3 * (size_t)NS * NB;
    float* Z = stag;                 // 2048x2048, overlays staging
    float* T = w + 4 * M2;           // recursion temp / resid partials
    float* sm = T + (size_t)1024 * 1024;
    float* wcomb = sm;               // 1024
    float* consts = sm + 1024;       // 4
    float* a_s = sm + 1032;          // 2048
    float* b_s = a_s + NS;           // 512
    float* a_t = b_s + NB;           // 2048
    float* b_t = a_t + NS;           // 512
    float* rvec = b_t + NB;          // 2048
    float* vvec = rvec + NS;         // 2048
    float* z2 = vvec + NS;           // 2048

    // 1) feature maps + kernel weights
    prep_k<<<1, 256, 0, stream>>>(Wf, bf, Ws, Wt, wcomb, consts);
    matvec_k<<<NS / 4, 256, 0, stream>>>(source_x, NS, wcomb + 0 * DIMX, consts, 0, a_s);
    matvec_k<<<NB / 4, 256, 0, stream>>>(base_s, NB, wcomb + 1 * DIMX, consts, 1, b_s);
    matvec_k<<<NS / 4, 256, 0, stream>>>(target_x, NS, wcomb + 2 * DIMX, consts, 2, a_t);
    matvec_k<<<NB / 4, 256, 0, stream>>>(base_t, NB, wcomb + 3 * DIMX, consts, 3, b_t);
    weights_k<<<NS, 256, 0, stream>>>(a_s, b_s, bs, wsb);
    weights_k<<<NS, 256, 0, stream>>>(a_t, b_t, bt, wtb);

    // 2) wsK = ws@Kb, wtK = wt@Kb
    {
        dim3 g(NB / 128, NS / 128);
        gemm128_k<0, 0><<<g, 256, 0, stream>>>(NS, NB, NB, wsb, NB, 0, Kb, NB, 0, wsK, NB, 0,
                                               nullptr, 0, nullptr, 0, 0, 0, 0);
        gemm128_k<0, 0><<<g, 256, 0, stream>>>(NS, NB, NB, wtb, NB, 0, Kb, NB, 0, wtK, NB, 0,
                                               nullptr, 0, nullptr, 0, 0, 0, 0);
    }
    // 3) K_src, K_tgt, K_cos (Hadamard epilogues)
    {
        dim3 g(NS / 128, NS / 128);
        gemm128_k<0, 1><<<g, 256, 0, stream>>>(NS, NS, NB, wsK, NB, 0, wsb, NB, 0, Ksrc, NS, 0,
                                               k_ss, NS, noise_s, 1, 0, 0, 0);
        gemm128_k<0, 1><<<g, 256, 0, stream>>>(NS, NS, NB, wtK, NB, 0, wtb, NB, 0, Ktgt, NS, 0,
                                               k_tt, NS, noise_t, 1, 0, 0, 0);
        gemm128_k<0, 1><<<g, 256, 0, stream>>>(NS, NS, NB, wsK, NB, 0, wtb, NB, 0, Kcos, NS, 0,
                                               k_st, NS, nullptr, 2, 0, 0, 0);
    }

    // 4) Cholesky of K_src + full triangular inversion -> Linv in Ksrc
    run_chol(Ksrc, stream);
    run_inv(Ksrc, T, stream);

    // 5) Z = Linv @ Kcos (K trimmed to the lower band)
    {
        dim3 g(NS / 128, NS / 128);
        gemm128_k<0, 0><<<g, 256, 0, stream>>>(NS, NS, NS, Ksrc, NS, 0, Kcos, NS, 0, Z, NS, 0,
                                               nullptr, 0, nullptr, 0, 0, 0, 2);
    }

    // 6) z2 = Linv @ source_y ; r = target_y - Z^T z2
    gemv_lower_k<<<NS / 4, 256, 0, stream>>>(Ksrc, NS, source_y, z2, NS);
    resid_part_k<<<dim3(NS / 256, 32), 256, 0, stream>>>(Z, z2, T);
    resid_fin_k<<<NS / 256, 256, 0, stream>>>(T, target_y, rvec);

    // 7) cov = K_tgt - Z^T Z (lower tiles only)
    {
        dim3 g(NS / 128, NS / 128);
        gemm128_k<1, 0><<<g, 256, 0, stream>>>(NS, NS, NS, Z, NS, 0, Z, NS, 0, Ktgt, NS, 0,
                                               nullptr, 0, nullptr, 3, 0, 0, 1);
    }

    // 8) Cholesky of cov + full triangular inversion -> Lcinv in Ktgt
    run_chol(Ktgt, stream);
    run_inv(Ktgt, T, stream);

    // 9) v = Lcinv @ r ; loss (log diag(Lc) = -log diag(Lcinv))
    gemv_lower_k<<<NS / 4, 256, 0, stream>>>(Ktgt, NS, rvec, vvec, NS);
    loss_k<<<1, 256, 0, stream>>>(Ktgt, NS, NS, -1.0f, vvec, out);
}

// Round 8
// 10790.317 us; speedup vs baseline: 2.4043x; 1.0097x over previous
//
#include <hip/hip_runtime.h>
#include <hip/hip_bf16.h>
#include <math.h>

#define NS 2048
#define NB 512
#define DIMX 256
#define NFEAT 8
#define DPAD 129
#define BI 16
#define NBK 8

// ---------------- small prep kernels ----------------

__global__ __launch_bounds__(256) void prep_k(const float* __restrict__ Wf,
                                              const float* __restrict__ bf,
                                              const float* __restrict__ Ws,
                                              const float* __restrict__ Wt,
                                              float* __restrict__ wcomb,
                                              float* __restrict__ consts) {
    int d = threadIdx.x;
    float w0 = 0.f, w1 = 0.f, w2 = 0.f, w3 = 0.f;
#pragma unroll
    for (int k = 0; k < NFEAT; ++k) {
        float wf = Wf[k * DIMX + d];
        w0 += Ws[k] * wf;
        w1 += Ws[NFEAT + k] * wf;
        w2 += Wt[k] * wf;
        w3 += Wt[NFEAT + k] * wf;
    }
    wcomb[0 * DIMX + d] = w0;
    wcomb[1 * DIMX + d] = w1;
    wcomb[2 * DIMX + d] = w2;
    wcomb[3 * DIMX + d] = w3;
    if (d == 0) {
        float c0 = 0.f, c1 = 0.f, c2 = 0.f, c3 = 0.f;
#pragma unroll
        for (int k = 0; k < NFEAT; ++k) {
            c0 += Ws[k] * bf[k];
            c1 += Ws[NFEAT + k] * bf[k];
            c2 += Wt[k] * bf[k];
            c3 += Wt[NFEAT + k] * bf[k];
        }
        consts[0] = c0; consts[1] = c1; consts[2] = c2; consts[3] = c3;
    }
}

__global__ __launch_bounds__(256) void matvec_k(const float* __restrict__ X, int nrows,
                                                const float* __restrict__ wc,
                                                const float* __restrict__ consts, int cidx,
                                                float* __restrict__ out) {
    int wave = threadIdx.x >> 6, lane = threadIdx.x & 63;
    int row = blockIdx.x * 4 + wave;
    if (row >= nrows) return;
    const float* xr = X + (size_t)row * DIMX;
    float s = 0.f;
#pragma unroll
    for (int t = 0; t < 4; ++t) s += xr[lane + 64 * t] * wc[lane + 64 * t];
#pragma unroll
    for (int off = 32; off; off >>= 1) s += __shfl_down(s, off);
    if (lane == 0) out[row] = s + consts[cidx];
}

__global__ __launch_bounds__(256) void weights_k(const float* __restrict__ a,
                                                 const float* __restrict__ b,
                                                 const float* __restrict__ bw,
                                                 float* __restrict__ w) {
    __shared__ float red[256];
    int i = blockIdx.x, tid = threadIdx.x;
    float ai = a[i] + bw[0];
    float r1 = ai + b[tid];
    float r2 = ai + b[tid + 256];
    float e1 = r1 > 0.f ? r1 : expm1f(r1);
    float e2 = r2 > 0.f ? r2 : expm1f(r2);
    red[tid] = e1 + e2;
    __syncthreads();
    for (int s = 128; s; s >>= 1) {
        if (tid < s) red[tid] += red[tid + s];
        __syncthreads();
    }
    float scale = 512.f / red[0];
    w[(size_t)i * NB + tid] = e1 * scale;
    w[(size_t)i * NB + tid + 256] = e2 * scale;
}

// ---------------- 128-tile f32 GEMM, 512 threads, dbuf LDS ----------------
// mode 0: C=acc | 1: C=kmat*acc+diag(noise) | 2: C=kmat*acc | 3: C=C-acc | 4: C=-acc
// flags bit0 = lower_only; bit1 = ktrim (K<=rowBase+128); bit2 = kstart (K from colBase)
template <int TA, int TB>
__global__ __launch_bounds__(512) void gemm128_k(int M, int N, int K,
                                                 const float* __restrict__ A, int lda, size_t zoffA,
                                                 const float* __restrict__ B, int ldb, size_t zoffB,
                                                 float* __restrict__ C, int ldc, size_t zoffC,
                                                 const float* __restrict__ kmat, int ldk,
                                                 const float* __restrict__ noisep,
                                                 int mode, int row0, int col0, int flags) {
    __shared__ float As[2][16][132];
    __shared__ float Bs[2][16][132];
    int bz = blockIdx.z;
    A += zoffA * bz; B += zoffB * bz; C += zoffC * bz;

    // bijective XCD swizzle (m204): contiguous tile chunks per XCD
    int gx = gridDim.x;
    int nwg = gx * gridDim.y;
    int flat = blockIdx.y * gx + blockIdx.x;
    int qq = nwg >> 3, rr = nwg & 7;
    int xcd = flat & 7, pos = flat >> 3;
    int swz = (xcd < rr) ? (xcd * (qq + 1) + pos)
                         : (rr * (qq + 1) + (xcd - rr) * qq + pos);
    int bm = swz / gx, bn = swz % gx;

    int rowBase = bm * 128, colBase = bn * 128;
    if ((flags & 1) && (rowBase + 127) < colBase) return;
    int Kend = (flags & 2) ? ((rowBase + 128 < K) ? rowBase + 128 : K) : K;
    int Kstart = (flags & 4) ? colBase : 0;
    int tid = threadIdx.x;
    int tx = tid & 31, ty = tid >> 5;      // 32 col-groups x 16 row-groups
    float acc[8][4];
#pragma unroll
    for (int i = 0; i < 8; ++i)
#pragma unroll
        for (int j = 0; j < 4; ++j) acc[i][j] = 0.f;

    float ra[4], rb[4];
    auto loadA = [&](int kk) {
        if (TA == 0) {
            int row = tid >> 2, koff = (tid & 3) * 4;
            const float* src = A + (size_t)(rowBase + row) * lda + kk + koff;
            float4 v = *(const float4*)src;
            ra[0] = v.x; ra[1] = v.y; ra[2] = v.z; ra[3] = v.w;
        } else {
            int k = tid >> 5, ib = (tid & 31) * 4;
            const float* src = A + (size_t)(kk + k) * lda + rowBase + ib;
            float4 v = *(const float4*)src;
            ra[0] = v.x; ra[1] = v.y; ra[2] = v.z; ra[3] = v.w;
        }
    };
    auto storeA = [&](int buf) {
        if (TA == 0) {
            int row = tid >> 2, koff = (tid & 3) * 4;
#pragma unroll
            for (int q = 0; q < 4; ++q) As[buf][koff + q][row] = ra[q];
        } else {
            int k = tid >> 5, ib = (tid & 31) * 4;
#pragma unroll
            for (int q = 0; q < 4; ++q) As[buf][k][ib + q] = ra[q];
        }
    };
    auto loadB = [&](int kk) {
        if (TB == 0) {
            int k = tid >> 5, jb = (tid & 31) * 4;
            const float* src = B + (size_t)(kk + k) * ldb + colBase + jb;
            float4 v = *(const float4*)src;
            rb[0] = v.x; rb[1] = v.y; rb[2] = v.z; rb[3] = v.w;
        } else {
            int col = tid >> 2, koff = (tid & 3) * 4;
            const float* src = B + (size_t)(colBase + col) * ldb + kk + koff;
            float4 v = *(const float4*)src;
            rb[0] = v.x; rb[1] = v.y; rb[2] = v.z; rb[3] = v.w;
        }
    };
    auto storeB = [&](int buf) {
        if (TB == 0) {
            int k = tid >> 5, jb = (tid & 31) * 4;
#pragma unroll
            for (int q = 0; q < 4; ++q) Bs[buf][k][jb + q] = rb[q];
        } else {
            int col = tid >> 2, koff = (tid & 3) * 4;
#pragma unroll
            for (int q = 0; q < 4; ++q) Bs[buf][koff + q][col] = rb[q];
        }
    };

    int nt = (Kend - Kstart) >> 4;
    if (nt > 0) {
        loadA(Kstart);
        loadB(Kstart);
        storeA(0);
        storeB(0);
    }
    for (int t = 0; t < nt; ++t) {
        __syncthreads();
        int cur = t & 1;
        if (t + 1 < nt) {     // async: loads issue, ds_writes land while we compute buf[cur]
            loadA(Kstart + (t + 1) * 16);
            loadB(Kstart + (t + 1) * 16);
            storeA(cur ^ 1);
            storeB(cur ^ 1);
        }
#pragma unroll
        for (int k = 0; k < 16; ++k) {
            float a[8], b[4];
            float4 t0 = *(const float4*)&As[cur][k][ty * 4];
            float4 t1 = *(const float4*)&As[cur][k][64 + ty * 4];
            float4 u0 = *(const float4*)&Bs[cur][k][tx * 4];
            a[0] = t0.x; a[1] = t0.y; a[2] = t0.z; a[3] = t0.w;
            a[4] = t1.x; a[5] = t1.y; a[6] = t1.z; a[7] = t1.w;
            b[0] = u0.x; b[1] = u0.y; b[2] = u0.z; b[3] = u0.w;
#pragma unroll
            for (int i = 0; i < 8; ++i)
#pragma unroll
                for (int j = 0; j < 4; ++j) acc[i][j] += a[i] * b[j];
        }
    }
#pragma unroll
    for (int i = 0; i < 8; ++i) {
        int gi = rowBase + ((i >> 2) << 6) + ty * 4 + (i & 3);
#pragma unroll
        for (int j = 0; j < 4; ++j) {
            int gj = colBase + tx * 4 + j;
            float v = acc[i][j];
            if (mode == 1 || mode == 2) {
                v *= kmat[(size_t)gi * ldk + gj];
                if (mode == 1 && (row0 + gi) == (col0 + gj)) {
                    float ns = noisep[0];
                    ns = fminf(fmaxf(ns, 1e-5f), 1.0f);
                    v += ns;
                }
            } else if (mode == 3) {
                v = C[(size_t)gi * ldc + gj] - v;
            } else if (mode == 4) {
                v = -v;
            }
            C[(size_t)gi * ldc + gj] = v;
        }
    }
}

// ------- fused 128x128 diag Cholesky + blocked triangular inverse (256 thr) -------
__global__ __launch_bounds__(256) void chol_diag_inv128_k(float* __restrict__ A, int lda) {
    extern __shared__ float s[];              // 128 * DPAD floats
    __shared__ float rsd[128];
    __shared__ float xd[NBK][BI][BI + 1];
    __shared__ float wbuf[NBK - 1][BI][BI + 1];
    int tid = threadIdx.x;

    for (int idx = tid; idx < 128 * 128; idx += 256) {
        int r = idx >> 7, c = idx & 127;
        s[r * DPAD + c] = A[(size_t)r * lda + c];
    }
    __syncthreads();

    // deferred-scaling right-looking Cholesky: one barrier per k
    int b = tid >> 5, a = tid & 31;
    for (int k = 0; k < 128; ++k) {
        float isq = 1.0f / s[k * DPAD + k];
        for (int i = k + 1 + b; i < 128; i += 8) {
            float f = s[i * DPAD + k] * isq;
            float* row = s + (size_t)i * DPAD;
            for (int j = k + 1 + a; j <= i; j += 32) {
                row[j] -= f * s[j * DPAD + k];
            }
        }
        __syncthreads();
    }

    if (tid < 128) rsd[tid] = rsqrtf(s[tid * DPAD + tid]);
    __syncthreads();
    for (int idx = tid; idx < 128 * 128; idx += 256) {
        int r = idx >> 7, c = idx & 127;
        if (c < r) s[r * DPAD + c] *= rsd[c];
        else if (c == r) s[r * DPAD + r] = 1.0f / rsd[r];
    }
    __syncthreads();

    // phase A: invert the 8 diagonal 16x16 blocks
    {
        int g = tid >> 4, l = tid & 15;
        if (g < NBK) {
            const float* Lb = s + (size_t)(g * BI) * DPAD + g * BI;
            for (int r = 0; r < BI; ++r) {
                float acc = (r == l) ? 1.f : 0.f;
                for (int t = l; t < r; ++t) acc -= Lb[r * DPAD + t] * xd[g][t][l];
                xd[g][r][l] = (r >= l) ? acc / Lb[r * DPAD + r] : 0.f;
            }
        }
    }
    __syncthreads();

    // phase B: off-diagonal blocks by diagonal offset
    for (int d = 1; d < NBK; ++d) {
        int npairs = NBK - d;
        for (int e = tid; e < npairs * 256; e += 256) {
            int p = e >> 8, ab = e & 255;
            int a2 = ab >> 4, b2 = ab & 15;
            int J = p, I = p + d;
            int Ibase = I * BI, Jbase = J * BI;
            float acc = 0.f;
            {
                const float* Lr = s + (size_t)(Ibase + a2) * DPAD + Jbase;
                for (int t = 0; t < BI; ++t) acc += Lr[t] * xd[J][t][b2];
            }
            for (int K = J + 1; K < I; ++K) {
                int Kbase = K * BI;
                const float* Lr = s + (size_t)(Ibase + a2) * DPAD + Kbase;
                const float* Xc = s + (size_t)(Jbase + b2) * DPAD + Kbase;
                for (int t = 0; t < BI; ++t) acc += Lr[t] * Xc[t];
            }
            wbuf[p][a2][b2] = acc;
        }
        __syncthreads();
        for (int e = tid; e < npairs * 256; e += 256) {
            int p = e >> 8, ab = e & 255;
            int a2 = ab >> 4, b2 = ab & 15;
            int J = p, I = p + d;
            float acc = 0.f;
            for (int t = 0; t < BI; ++t) acc += xd[I][a2][t] * wbuf[p][t][b2];
            s[(size_t)(J * BI + b2) * DPAD + I * BI + a2] = -acc;
        }
        __syncthreads();
    }

    for (int idx = tid; idx < 128 * 128; idx += 256) {
        int r = idx >> 7, c = idx & 127;
        float v;
        if (c > r) {
            v = 0.f;
        } else {
            int gr = r >> 4, gc = c >> 4;
            v = (gr == gc) ? xd[gr][r & 15][c & 15] : s[(size_t)c * DPAD + r];
        }
        A[(size_t)r * lda + c] = v;
    }
}

__global__ __launch_bounds__(256) void zero_upper_k(float* __restrict__ A, int n, int lda) {
    int i = blockIdx.x;
    for (int j = i + 1 + threadIdx.x; j < n; j += 256) A[(size_t)i * lda + j] = 0.f;
}

__global__ __launch_bounds__(256) void gemv_lower_k(const float* __restrict__ L, int ld,
                                                    const float* __restrict__ y,
                                                    float* __restrict__ z, int n) {
    int wave = threadIdx.x >> 6, lane = threadIdx.x & 63;
    int row = blockIdx.x * 4 + wave;
    if (row >= n) return;
    const float* Lr = L + (size_t)row * ld;
    float s = 0.f;
    for (int j = lane; j <= row; j += 64) s += Lr[j] * y[j];
#pragma unroll
    for (int off = 32; off; off >>= 1) s += __shfl_down(s, off);
    if (lane == 0) z[row] = s;
}

__global__ __launch_bounds__(256) void resid_part_k(const float* __restrict__ Z,
                                                    const float* __restrict__ zv,
                                                    float* __restrict__ part) {
    int j = blockIdx.x * 256 + threadIdx.x;
    int i0 = blockIdx.y * 64;
    float acc = 0.f;
    for (int i = i0; i < i0 + 64; ++i) acc += Z[(size_t)i * NS + j] * zv[i];
    part[(size_t)blockIdx.y * NS + j] = acc;
}

__global__ __launch_bounds__(256) void resid_fin_k(const float* __restrict__ part,
                                                   const float* __restrict__ ty,
                                                   float* __restrict__ r) {
    int j = blockIdx.x * 256 + threadIdx.x;
    float acc = 0.f;
    for (int q = 0; q < 32; ++q) acc += part[(size_t)q * NS + j];
    r[j] = ty[j] - acc;
}

__global__ __launch_bounds__(256) void loss_k(const float* __restrict__ Lc, int n, int ldl,
                                              float sign,
                                              const float* __restrict__ v,
                                              float* __restrict__ out) {
    __shared__ float red1[256];
    __shared__ float red2[256];
    int tid = threadIdx.x;
    float s1 = 0.f, s2 = 0.f;
    for (int i = tid; i < n; i += 256) {
        s1 += logf(Lc[(size_t)i * ldl + i]);
        float vi = v[i];
        s2 += vi * vi;
    }
    red1[tid] = s1;
    red2[tid] = s2;
    __syncthreads();
    for (int s = 128; s; s >>= 1) {
        if (tid < s) { red1[tid] += red1[tid + s]; red2[tid] += red2[tid + s]; }
        __syncthreads();
    }
    if (tid == 0) {
        out[0] = 0.5f * sign * red1[0] + 0.5f * red2[0] + 0.5f * (float)n * 1.8378770664093453f;
    }
}

// ---------------- host orchestration ----------------

static const size_t CHOL_LDS = (size_t)128 * DPAD * sizeof(float);  // 66 KB dynamic

static void run_chol(float* A, hipStream_t stream) {
    for (int kb = 0; kb < 16; ++kb) {
        float* Ad = A + (size_t)kb * 128 * (NS + 1);
        chol_diag_inv128_k<<<1, 256, CHOL_LDS, stream>>>(Ad, NS);
        int rem = NS - (kb + 1) * 128;
        if (rem > 0) {
            float* P = A + (size_t)(kb + 1) * 128 * NS + kb * 128;
            gemm128_k<0, 1><<<dim3(1, rem / 128), 512, 0, stream>>>(
                rem, 128, 128, P, NS, 0, Ad, NS, 0, P, NS, 0,
                nullptr, 0, nullptr, 0, 0, 0, 0);
            float* Ct = A + (size_t)(kb + 1) * 128 * (NS + 1);
            gemm128_k<0, 1><<<dim3(rem / 128, rem / 128), 512, 0, stream>>>(
                rem, rem, 128, P, NS, 0, P, NS, 0, Ct, NS, 0,
                nullptr, 0, nullptr, 3, 0, 0, 1);
        }
    }
}

static void run_inv(float* A, float* T, hipStream_t stream) {
    zero_upper_k<<<NS, 256, 0, stream>>>(A, NS, NS);
    for (int s = 128; s <= 1024; s <<= 1) {
        int np = NS / (2 * s);
        size_t zz = (size_t)2 * s * (NS + 1);
        size_t zt = (size_t)s * s;
        dim3 g(s / 128, s / 128, np);
        gemm128_k<0, 0><<<g, 512, 0, stream>>>(s, s, s, A + (size_t)s * NS, NS, zz,
                                               A, NS, zz, T, s, zt,
                                               nullptr, 0, nullptr, 0, 0, 0, 4);
        gemm128_k<0, 0><<<g, 512, 0, stream>>>(s, s, s, A + (size_t)s * (NS + 1), NS, zz,
                                               T, s, zt, A + (size_t)s * NS, NS, zz,
                                               nullptr, 0, nullptr, 4, 0, 0, 2);
    }
}

extern "C" void kernel_launch(void* const* d_in, const int* in_sizes, int n_in,
                              void* d_out, int out_size, void* d_ws, size_t ws_size,
                              hipStream_t stream) {
    const float* source_x = (const float*)d_in[0];
    const float* source_y = (const float*)d_in[1];
    const float* target_x = (const float*)d_in[2];
    const float* target_y = (const float*)d_in[3];
    const float* k_ss = (const float*)d_in[4];
    const float* k_tt = (const float*)d_in[5];
    const float* k_st = (const float*)d_in[6];
    const float* noise_s = (const float*)d_in[7];
    const float* noise_t = (const float*)d_in[8];
    const float* Wf = (const float*)d_in[9];
    const float* bf = (const float*)d_in[10];
    const float* Ws = (const float*)d_in[11];
    const float* bs = (const float*)d_in[12];
    const float* Wt = (const float*)d_in[13];
    const float* bt = (const float*)d_in[14];
    const float* Kb = (const float*)d_in[15];
    const float* base_s = (const float*)d_in[16];
    const float* base_t = (const float*)d_in[17];
    float* out = (float*)d_out;

    float* w = (float*)d_ws;
    const size_t M2 = (size_t)NS * NS;
    float* Ksrc = w;
    float* Kcos = w + M2;
    float* Ktgt = w + 2 * M2;
    float* stag = w + 3 * M2;
    float* wsb = stag;
    float* wtb = stag + (size_t)NS * NB;
    float* wsK = stag + 2 * (size_t)NS * NB;
    float* wtK = stag + 3 * (size_t)NS * NB;
    float* Z = stag;
    float* T = w + 4 * M2;
    float* sm = T + (size_t)1024 * 1024;
    float* wcomb = sm;
    float* consts = sm + 1024;
    float* a_s = sm + 1032;
    float* b_s = a_s + NS;
    float* a_t = b_s + NB;
    float* b_t = a_t + NS;
    float* rvec = b_t + NB;
    float* vvec = rvec + NS;
    float* z2 = vvec + NS;

    // 1) feature maps + kernel weights
    prep_k<<<1, 256, 0, stream>>>(Wf, bf, Ws, Wt, wcomb, consts);
    matvec_k<<<NS / 4, 256, 0, stream>>>(source_x, NS, wcomb + 0 * DIMX, consts, 0, a_s);
    matvec_k<<<NB / 4, 256, 0, stream>>>(base_s, NB, wcomb + 1 * DIMX, consts, 1, b_s);
    matvec_k<<<NS / 4, 256, 0, stream>>>(target_x, NS, wcomb + 2 * DIMX, consts, 2, a_t);
    matvec_k<<<NB / 4, 256, 0, stream>>>(base_t, NB, wcomb + 3 * DIMX, consts, 3, b_t);
    weights_k<<<NS, 256, 0, stream>>>(a_s, b_s, bs, wsb);
    weights_k<<<NS, 256, 0, stream>>>(a_t, b_t, bt, wtb);

    // 2) wsK = ws@Kb, wtK = wt@Kb
    {
        dim3 g(NB / 128, NS / 128);
        gemm128_k<0, 0><<<g, 512, 0, stream>>>(NS, NB, NB, wsb, NB, 0, Kb, NB, 0, wsK, NB, 0,
                                               nullptr, 0, nullptr, 0, 0, 0, 0);
        gemm128_k<0, 0><<<g, 512, 0, stream>>>(NS, NB, NB, wtb, NB, 0, Kb, NB, 0, wtK, NB, 0,
                                               nullptr, 0, nullptr, 0, 0, 0, 0);
    }
    // 3) K_src, K_tgt, K_cos (Hadamard epilogues)
    {
        dim3 g(NS / 128, NS / 128);
        gemm128_k<0, 1><<<g, 512, 0, stream>>>(NS, NS, NB, wsK, NB, 0, wsb, NB, 0, Ksrc, NS, 0,
                                               k_ss, NS, noise_s, 1, 0, 0, 0);
        gemm128_k<0, 1><<<g, 512, 0, stream>>>(NS, NS, NB, wtK, NB, 0, wtb, NB, 0, Ktgt, NS, 0,
                                               k_tt, NS, noise_t, 1, 0, 0, 0);
        gemm128_k<0, 1><<<g, 512, 0, stream>>>(NS, NS, NB, wsK, NB, 0, wtb, NB, 0, Kcos, NS, 0,
                                               k_st, NS, nullptr, 2, 0, 0, 0);
    }

    // 4) Cholesky of K_src + full triangular inversion -> Linv in Ksrc
    run_chol(Ksrc, stream);
    run_inv(Ksrc, T, stream);

    // 5) Z = Linv @ Kcos (K trimmed to the lower band)
    {
        dim3 g(NS / 128, NS / 128);
        gemm128_k<0, 0><<<g, 512, 0, stream>>>(NS, NS, NS, Ksrc, NS, 0, Kcos, NS, 0, Z, NS, 0,
                                               nullptr, 0, nullptr, 0, 0, 0, 2);
    }

    // 6) z2 = Linv @ source_y ; r = target_y - Z^T z2
    gemv_lower_k<<<NS / 4, 256, 0, stream>>>(Ksrc, NS, source_y, z2, NS);
    resid_part_k<<<dim3(NS / 256, 32), 256, 0, stream>>>(Z, z2, T);
    resid_fin_k<<<NS / 256, 256, 0, stream>>>(T, target_y, rvec);

    // 7) cov = K_tgt - Z^T Z (lower tiles only)
    {
        dim3 g(NS / 128, NS / 128);
        gemm128_k<1, 0><<<g, 512, 0, stream>>>(NS, NS, NS, Z, NS, 0, Z, NS, 0, Ktgt, NS, 0,
                                               nullptr, 0, nullptr, 3, 0, 0, 1);
    }

    // 8) Cholesky of cov + full triangular inversion -> Lcinv in Ktgt
    run_chol(Ktgt, stream);
    run_inv(Ktgt, T, stream);

    // 9) v = Lcinv @ r ; loss (log diag(Lc) = -log diag(Lcinv))
    gemv_lower_k<<<NS / 4, 256, 0, stream>>>(Ktgt, NS, rvec, vvec, NS);
    loss_k<<<1, 256, 0, stream>>>(Ktgt, NS, NS, -1.0f, vvec, out);
}

// Round 10
// 7856.255 us; speedup vs baseline: 3.3022x; 1.3735x over previous
//
#include <hip/hip_runtime.h>
#include <hip/hip_bf16.h>
#include <math.h>

#define NS 2048
#define NB 512
#define DIMX 256
#define NFEAT 8
#define DPAD 129
#define BI 16
#define NBK 8

// ---------------- small prep kernels ----------------

__global__ __launch_bounds__(256) void prep_k(const float* __restrict__ Wf,
                                              const float* __restrict__ bf,
                                              const float* __restrict__ Ws,
                                              const float* __restrict__ Wt,
                                              float* __restrict__ wcomb,
                                              float* __restrict__ consts) {
    int d = threadIdx.x;
    float w0 = 0.f, w1 = 0.f, w2 = 0.f, w3 = 0.f;
#pragma unroll
    for (int k = 0; k < NFEAT; ++k) {
        float wf = Wf[k * DIMX + d];
        w0 += Ws[k] * wf;
        w1 += Ws[NFEAT + k] * wf;
        w2 += Wt[k] * wf;
        w3 += Wt[NFEAT + k] * wf;
    }
    wcomb[0 * DIMX + d] = w0;
    wcomb[1 * DIMX + d] = w1;
    wcomb[2 * DIMX + d] = w2;
    wcomb[3 * DIMX + d] = w3;
    if (d == 0) {
        float c0 = 0.f, c1 = 0.f, c2 = 0.f, c3 = 0.f;
#pragma unroll
        for (int k = 0; k < NFEAT; ++k) {
            c0 += Ws[k] * bf[k];
            c1 += Ws[NFEAT + k] * bf[k];
            c2 += Wt[k] * bf[k];
            c3 += Wt[NFEAT + k] * bf[k];
        }
        consts[0] = c0; consts[1] = c1; consts[2] = c2; consts[3] = c3;
    }
}

__global__ __launch_bounds__(256) void matvec_k(const float* __restrict__ X, int nrows,
                                                const float* __restrict__ wc,
                                                const float* __restrict__ consts, int cidx,
                                                float* __restrict__ out) {
    int wave = threadIdx.x >> 6, lane = threadIdx.x & 63;
    int row = blockIdx.x * 4 + wave;
    if (row >= nrows) return;
    const float* xr = X + (size_t)row * DIMX;
    float s = 0.f;
#pragma unroll
    for (int t = 0; t < 4; ++t) s += xr[lane + 64 * t] * wc[lane + 64 * t];
#pragma unroll
    for (int off = 32; off; off >>= 1) s += __shfl_down(s, off);
    if (lane == 0) out[row] = s + consts[cidx];
}

__global__ __launch_bounds__(256) void weights_k(const float* __restrict__ a,
                                                 const float* __restrict__ b,
                                                 const float* __restrict__ bw,
                                                 float* __restrict__ w) {
    __shared__ float red[256];
    int i = blockIdx.x, tid = threadIdx.x;
    float ai = a[i] + bw[0];
    float r1 = ai + b[tid];
    float r2 = ai + b[tid + 256];
    float e1 = r1 > 0.f ? r1 : expm1f(r1);
    float e2 = r2 > 0.f ? r2 : expm1f(r2);
    red[tid] = e1 + e2;
    __syncthreads();
    for (int s = 128; s; s >>= 1) {
        if (tid < s) red[tid] += red[tid + s];
        __syncthreads();
    }
    float scale = 512.f / red[0];
    w[(size_t)i * NB + tid] = e1 * scale;
    w[(size_t)i * NB + tid + 256] = e2 * scale;
}

__global__ __launch_bounds__(64) void init_flags_k(int* __restrict__ f) {
    f[threadIdx.x] = 0;
}

// ---------------- 128-tile f32 GEMM, 512 threads, dbuf LDS, T14 split ----------------
// mode 0: C=acc | 1: C=kmat*acc+diag(noise) | 2: C=kmat*acc | 3: C=C-acc | 4: C=-acc
// flags bit0 = lower_only; bit1 = ktrim (K<=rowBase+128); bit2 = kstart (K from colBase)
// kmat2/noisep2: per-z overrides (bz==1) for batched epilogues.
template <int TA, int TB>
__global__ __launch_bounds__(512) void gemm128_k(int M, int N, int K,
                                                 const float* __restrict__ A, int lda, size_t zoffA,
                                                 const float* __restrict__ B, int ldb, size_t zoffB,
                                                 float* __restrict__ C, int ldc, size_t zoffC,
                                                 const float* __restrict__ kmat, int ldk,
                                                 const float* __restrict__ noisep,
                                                 const float* __restrict__ kmat2,
                                                 const float* __restrict__ noisep2,
                                                 int mode, int row0, int col0, int flags) {
    __shared__ float As[2][16][132];
    __shared__ float Bs[2][16][132];
    int bz = blockIdx.z;
    A += zoffA * bz; B += zoffB * bz; C += zoffC * bz;
    if (bz == 1) {
        if (kmat2) kmat = kmat2;
        if (noisep2) noisep = noisep2;
    }

    // bijective XCD swizzle (m204)
    int gx = gridDim.x;
    int nwg = gx * gridDim.y;
    int flat = blockIdx.y * gx + blockIdx.x;
    int qq = nwg >> 3, rr = nwg & 7;
    int xcd = flat & 7, pos = flat >> 3;
    int swz = (xcd < rr) ? (xcd * (qq + 1) + pos)
                         : (rr * (qq + 1) + (xcd - rr) * qq + pos);
    int bm = swz / gx, bn = swz % gx;

    int rowBase = bm * 128, colBase = bn * 128;
    if ((flags & 1) && (rowBase + 127) < colBase) return;
    int Kend = (flags & 2) ? ((rowBase + 128 < K) ? rowBase + 128 : K) : K;
    int Kstart = (flags & 4) ? colBase : 0;
    int tid = threadIdx.x;
    int tx = tid & 31, ty = tid >> 5;
    float acc[8][4];
#pragma unroll
    for (int i = 0; i < 8; ++i)
#pragma unroll
        for (int j = 0; j < 4; ++j) acc[i][j] = 0.f;

    float ra[4], rb[4];
    auto loadA = [&](int kk) {
        if (TA == 0) {
            int row = tid >> 2, koff = (tid & 3) * 4;
            const float* src = A + (size_t)(rowBase + row) * lda + kk + koff;
            float4 v = *(const float4*)src;
            ra[0] = v.x; ra[1] = v.y; ra[2] = v.z; ra[3] = v.w;
        } else {
            int k = tid >> 5, ib = (tid & 31) * 4;
            const float* src = A + (size_t)(kk + k) * lda + rowBase + ib;
            float4 v = *(const float4*)src;
            ra[0] = v.x; ra[1] = v.y; ra[2] = v.z; ra[3] = v.w;
        }
    };
    auto storeA = [&](int buf) {
        if (TA == 0) {
            int row = tid >> 2, koff = (tid & 3) * 4;
#pragma unroll
            for (int q = 0; q < 4; ++q) As[buf][koff + q][row] = ra[q];
        } else {
            int k = tid >> 5, ib = (tid & 31) * 4;
#pragma unroll
            for (int q = 0; q < 4; ++q) As[buf][k][ib + q] = ra[q];
        }
    };
    auto loadB = [&](int kk) {
        if (TB == 0) {
            int k = tid >> 5, jb = (tid & 31) * 4;
            const float* src = B + (size_t)(kk + k) * ldb + colBase + jb;
            float4 v = *(const float4*)src;
            rb[0] = v.x; rb[1] = v.y; rb[2] = v.z; rb[3] = v.w;
        } else {
            int col = tid >> 2, koff = (tid & 3) * 4;
            const float* src = B + (size_t)(colBase + col) * ldb + kk + koff;
            float4 v = *(const float4*)src;
            rb[0] = v.x; rb[1] = v.y; rb[2] = v.z; rb[3] = v.w;
        }
    };
    auto storeB = [&](int buf) {
        if (TB == 0) {
            int k = tid >> 5, jb = (tid & 31) * 4;
#pragma unroll
            for (int q = 0; q < 4; ++q) Bs[buf][k][jb + q] = rb[q];
        } else {
            int col = tid >> 2, koff = (tid & 3) * 4;
#pragma unroll
            for (int q = 0; q < 4; ++q) Bs[buf][koff + q][col] = rb[q];
        }
    };

    int nt = (Kend - Kstart) >> 4;
    if (nt > 0) {
        loadA(Kstart);
        loadB(Kstart);
        storeA(0);
        storeB(0);
    }
    for (int t = 0; t < nt; ++t) {
        __syncthreads();
        int cur = t & 1;
        bool more = (t + 1 < nt);
        if (more) {                   // ISSUE loads early — in flight during compute
            loadA(Kstart + (t + 1) * 16);
            loadB(Kstart + (t + 1) * 16);
        }
#pragma unroll
        for (int k = 0; k < 16; ++k) {
            float a[8], b[4];
            float4 t0 = *(const float4*)&As[cur][k][ty * 4];
            float4 t1 = *(const float4*)&As[cur][k][64 + ty * 4];
            float4 u0 = *(const float4*)&Bs[cur][k][tx * 4];
            a[0] = t0.x; a[1] = t0.y; a[2] = t0.z; a[3] = t0.w;
            a[4] = t1.x; a[5] = t1.y; a[6] = t1.z; a[7] = t1.w;
            b[0] = u0.x; b[1] = u0.y; b[2] = u0.z; b[3] = u0.w;
#pragma unroll
            for (int i = 0; i < 8; ++i)
#pragma unroll
                for (int j = 0; j < 4; ++j) acc[i][j] += a[i] * b[j];
        }
        if (more) {                   // WRITE late — vmcnt drains after compute
            storeA(cur ^ 1);
            storeB(cur ^ 1);
        }
    }
#pragma unroll
    for (int i = 0; i < 8; ++i) {
        int gi = rowBase + ((i >> 2) << 6) + ty * 4 + (i & 3);
#pragma unroll
        for (int j = 0; j < 4; ++j) {
            int gj = colBase + tx * 4 + j;
            float v = acc[i][j];
            if (mode == 1 || mode == 2) {
                v *= kmat[(size_t)gi * ldk + gj];
                if (mode == 1 && (row0 + gi) == (col0 + gj)) {
                    float ns = noisep[0];
                    ns = fminf(fmaxf(ns, 1e-5f), 1.0f);
                    v += ns;
                }
            } else if (mode == 3) {
                v = C[(size_t)gi * ldc + gj] - v;
            } else if (mode == 4) {
                v = -v;
            }
            C[(size_t)gi * ldc + gj] = v;
        }
    }
}

// ------- fused Cholesky step: block 0 = diag chol+inverse; blocks >=1 = panel -------
__global__ __launch_bounds__(512) void chol_step_k(float* __restrict__ A, int lda, int kb,
                                                   int* __restrict__ flag) {
    extern __shared__ float s[];              // 128 * DPAD floats
    __shared__ float Ps[2][16][132];
    __shared__ float rsd[128];
    __shared__ float xd[NBK][BI][BI + 1];
    __shared__ float wbuf[NBK - 1][BI][BI + 1];
    int tid = threadIdx.x;

    if (blockIdx.x == 0) {
        float* Ad = A + (size_t)kb * 128 * (lda + 1);
        for (int idx = tid; idx < 128 * 128; idx += 512) {
            int r = idx >> 7, c = idx & 127;
            s[r * DPAD + c] = Ad[(size_t)r * lda + c];
        }
        __syncthreads();

        // deferred-scaling right-looking Cholesky: one barrier per k
        int b = tid >> 5, a = tid & 31;    // 16 x 32
        for (int k = 0; k < 128; ++k) {
            float isq = 1.0f / s[k * DPAD + k];
            for (int i = k + 1 + b; i < 128; i += 16) {
                float f = s[i * DPAD + k] * isq;
                float* row = s + (size_t)i * DPAD;
                for (int j = k + 1 + a; j <= i; j += 32) {
                    row[j] -= f * s[j * DPAD + k];
                }
            }
            __syncthreads();
        }

        if (tid < 128) rsd[tid] = rsqrtf(s[tid * DPAD + tid]);
        __syncthreads();
        for (int idx = tid; idx < 128 * 128; idx += 512) {
            int r = idx >> 7, c = idx & 127;
            if (c < r) s[r * DPAD + c] *= rsd[c];
            else if (c == r) s[r * DPAD + r] = 1.0f / rsd[r];
        }
        __syncthreads();

        // phase A: invert the 8 diagonal 16x16 blocks (column-parallel)
        {
            int g = tid >> 4, l = tid & 15;
            if (g < NBK) {
                const float* Lb = s + (size_t)(g * BI) * DPAD + g * BI;
                for (int r = 0; r < BI; ++r) {
                    float acc = (r == l) ? 1.f : 0.f;
                    for (int t = l; t < r; ++t) acc -= Lb[r * DPAD + t] * xd[g][t][l];
                    xd[g][r][l] = (r >= l) ? acc / Lb[r * DPAD + r] : 0.f;
                }
            }
        }
        __syncthreads();

        // phase B: off-diagonal blocks by diagonal offset (X stored transposed upper)
        for (int d = 1; d < NBK; ++d) {
            int npairs = NBK - d;
            for (int e = tid; e < npairs * 256; e += 512) {
                int p = e >> 8, ab = e & 255;
                int a2 = ab >> 4, b2 = ab & 15;
                int J = p, I = p + d;
                int Ibase = I * BI, Jbase = J * BI;
                float acc = 0.f;
                {
                    const float* Lr = s + (size_t)(Ibase + a2) * DPAD + Jbase;
                    for (int t = 0; t < BI; ++t) acc += Lr[t] * xd[J][t][b2];
                }
                for (int K = J + 1; K < I; ++K) {
                    int Kbase = K * BI;
                    const float* Lr = s + (size_t)(Ibase + a2) * DPAD + Kbase;
                    const float* Xc = s + (size_t)(Jbase + b2) * DPAD + Kbase;
                    for (int t = 0; t < BI; ++t) acc += Lr[t] * Xc[t];
                }
                wbuf[p][a2][b2] = acc;
            }
            __syncthreads();
            for (int e = tid; e < npairs * 256; e += 512) {
                int p = e >> 8, ab = e & 255;
                int a2 = ab >> 4, b2 = ab & 15;
                int J = p, I = p + d;
                float acc = 0.f;
                for (int t = 0; t < BI; ++t) acc += xd[I][a2][t] * wbuf[p][t][b2];
                s[(size_t)(J * BI + b2) * DPAD + I * BI + a2] = -acc;
            }
            __syncthreads();
        }

        // write back Dinv (zeros in strict upper)
        for (int idx = tid; idx < 128 * 128; idx += 512) {
            int r = idx >> 7, c = idx & 127;
            float v;
            if (c > r) {
                v = 0.f;
            } else {
                int gr = r >> 4, gc = c >> 4;
                v = (gr == gc) ? xd[gr][r & 15][c & 15] : s[(size_t)c * DPAD + r];
            }
            Ad[(size_t)r * lda + c] = v;
        }
        __threadfence();
        __syncthreads();
        if (tid == 0) {
            __hip_atomic_store(flag, 1, __ATOMIC_RELEASE, __HIP_MEMORY_SCOPE_AGENT);
        }
        return;
    }

    // ---------------- panel block: P = P @ Dinv^T ----------------
    if (tid == 0) {
        while (__hip_atomic_load(flag, __ATOMIC_ACQUIRE, __HIP_MEMORY_SCOPE_AGENT) == 0) {}
    }
    __syncthreads();
    __threadfence();

    float* Pb = A + (size_t)(kb + blockIdx.x) * 128 * lda + (size_t)kb * 128;
    const float* D = A + (size_t)kb * 128 * (lda + 1);

    // stage Dinv TRANSPOSED into s: s[k*DPAD + j] = D[j][k]
    for (int idx = tid; idx < 128 * 128; idx += 512) {
        int j = idx >> 7, k = idx & 127;
        s[(size_t)k * DPAD + j] = D[(size_t)j * lda + k];
    }

    int tx = tid & 31, ty = tid >> 5;
    float acc[8][4];
#pragma unroll
    for (int i = 0; i < 8; ++i)
#pragma unroll
        for (int j = 0; j < 4; ++j) acc[i][j] = 0.f;

    float rp[4];
    auto loadP = [&](int kk) {
        int row = tid >> 2, koff = (tid & 3) * 4;
        const float* src = Pb + (size_t)row * lda + kk + koff;
        float4 v = *(const float4*)src;
        rp[0] = v.x; rp[1] = v.y; rp[2] = v.z; rp[3] = v.w;
    };
    auto storeP = [&](int buf) {
        int row = tid >> 2, koff = (tid & 3) * 4;
#pragma unroll
        for (int q = 0; q < 4; ++q) Ps[buf][koff + q][row] = rp[q];
    };

    loadP(0);
    storeP(0);
    for (int t = 0; t < 8; ++t) {
        __syncthreads();
        int cur = t & 1;
        bool more = (t + 1 < 8);
        if (more) loadP((t + 1) * 16);
#pragma unroll
        for (int k = 0; k < 16; ++k) {
            float a[8], b[4];
            float4 t0 = *(const float4*)&Ps[cur][k][ty * 4];
            float4 t1 = *(const float4*)&Ps[cur][k][64 + ty * 4];
            float4 u0 = *(const float4*)&s[(size_t)(t * 16 + k) * DPAD + tx * 4];
            a[0] = t0.x; a[1] = t0.y; a[2] = t0.z; a[3] = t0.w;
            a[4] = t1.x; a[5] = t1.y; a[6] = t1.z; a[7] = t1.w;
            b[0] = u0.x; b[1] = u0.y; b[2] = u0.z; b[3] = u0.w;
#pragma unroll
            for (int i = 0; i < 8; ++i)
#pragma unroll
                for (int j = 0; j < 4; ++j) acc[i][j] += a[i] * b[j];
        }
        if (more) storeP(cur ^ 1);
    }
#pragma unroll
    for (int i = 0; i < 8; ++i) {
        int gi = ((i >> 2) << 6) + ty * 4 + (i & 3);
#pragma unroll
        for (int j = 0; j < 4; ++j) {
            Pb[(size_t)gi * lda + tx * 4 + j] = acc[i][j];
        }
    }
}

__global__ __launch_bounds__(256) void zero_upper_k(float* __restrict__ A, int n, int lda) {
    int i = blockIdx.x;
    for (int j = i + 1 + threadIdx.x; j < n; j += 256) A[(size_t)i * lda + j] = 0.f;
}

__global__ __launch_bounds__(256) void gemv_lower_k(const float* __restrict__ L, int ld,
                                                    const float* __restrict__ y,
                                                    float* __restrict__ z, int n) {
    int wave = threadIdx.x >> 6, lane = threadIdx.x & 63;
    int row = blockIdx.x * 4 + wave;
    if (row >= n) return;
    const float* Lr = L + (size_t)row * ld;
    float s = 0.f;
    for (int j = lane; j <= row; j += 64) s += Lr[j] * y[j];
#pragma unroll
    for (int off = 32; off; off >>= 1) s += __shfl_down(s, off);
    if (lane == 0) z[row] = s;
}

__global__ __launch_bounds__(256) void resid_part_k(const float* __restrict__ Z,
                                                    const float* __restrict__ zv,
                                                    float* __restrict__ part) {
    int j = blockIdx.x * 256 + threadIdx.x;
    int i0 = blockIdx.y * 64;
    float acc = 0.f;
    for (int i = i0; i < i0 + 64; ++i) acc += Z[(size_t)i * NS + j] * zv[i];
    part[(size_t)blockIdx.y * NS + j] = acc;
}

__global__ __launch_bounds__(256) void resid_fin_k(const float* __restrict__ part,
                                                   const float* __restrict__ ty,
                                                   float* __restrict__ r) {
    int j = blockIdx.x * 256 + threadIdx.x;
    float acc = 0.f;
    for (int q = 0; q < 32; ++q) acc += part[(size_t)q * NS + j];
    r[j] = ty[j] - acc;
}

__global__ __launch_bounds__(256) void loss_k(const float* __restrict__ Lc, int n, int ldl,
                                              float sign,
                                              const float* __restrict__ v,
                                              float* __restrict__ out) {
    __shared__ float red1[256];
    __shared__ float red2[256];
    int tid = threadIdx.x;
    float s1 = 0.f, s2 = 0.f;
    for (int i = tid; i < n; i += 256) {
        s1 += logf(Lc[(size_t)i * ldl + i]);
        float vi = v[i];
        s2 += vi * vi;
    }
    red1[tid] = s1;
    red2[tid] = s2;
    __syncthreads();
    for (int s = 128; s; s >>= 1) {
        if (tid < s) { red1[tid] += red1[tid + s]; red2[tid] += red2[tid + s]; }
        __syncthreads();
    }
    if (tid == 0) {
        out[0] = 0.5f * sign * red1[0] + 0.5f * red2[0] + 0.5f * (float)n * 1.8378770664093453f;
    }
}

// ---------------- host orchestration ----------------

static const size_t CHOL_LDS = (size_t)128 * DPAD * sizeof(float);  // 66 KB dynamic

static void run_chol(float* A, int* flags, hipStream_t stream) {
    for (int kb = 0; kb < 16; ++kb) {
        int nrem = 15 - kb;
        chol_step_k<<<dim3(1 + nrem), 512, CHOL_LDS, stream>>>(A, NS, kb, flags + kb);
        if (nrem > 0) {
            float* P = A + (size_t)(kb + 1) * 128 * NS + kb * 128;
            float* Ct = A + (size_t)(kb + 1) * 128 * (NS + 1);
            gemm128_k<0, 1><<<dim3(nrem, nrem), 512, 0, stream>>>(
                nrem * 128, nrem * 128, 128, P, NS, 0, P, NS, 0, Ct, NS, 0,
                nullptr, 0, nullptr, nullptr, nullptr, 3, 0, 0, 1);
        }
    }
}

static void run_inv(float* A, float* T, hipStream_t stream) {
    zero_upper_k<<<NS, 256, 0, stream>>>(A, NS, NS);
    for (int s = 128; s <= 1024; s <<= 1) {
        int np = NS / (2 * s);
        size_t zz = (size_t)2 * s * (NS + 1);
        size_t zt = (size_t)s * s;
        dim3 g(s / 128, s / 128, np);
        gemm128_k<0, 0><<<g, 512, 0, stream>>>(s, s, s, A + (size_t)s * NS, NS, zz,
                                               A, NS, zz, T, s, zt,
                                               nullptr, 0, nullptr, nullptr, nullptr,
                                               0, 0, 0, 4);
        gemm128_k<0, 0><<<g, 512, 0, stream>>>(s, s, s, A + (size_t)s * (NS + 1), NS, zz,
                                               T, s, zt, A + (size_t)s * NS, NS, zz,
                                               nullptr, 0, nullptr, nullptr, nullptr,
                                               4, 0, 0, 2);
    }
}

extern "C" void kernel_launch(void* const* d_in, const int* in_sizes, int n_in,
                              void* d_out, int out_size, void* d_ws, size_t ws_size,
                              hipStream_t stream) {
    const float* source_x = (const float*)d_in[0];
    const float* source_y = (const float*)d_in[1];
    const float* target_x = (const float*)d_in[2];
    const float* target_y = (const float*)d_in[3];
    const float* k_ss = (const float*)d_in[4];
    const float* k_tt = (const float*)d_in[5];
    const float* k_st = (const float*)d_in[6];
    const float* noise_s = (const float*)d_in[7];
    const float* noise_t = (const float*)d_in[8];
    const float* Wf = (const float*)d_in[9];
    const float* bf = (const float*)d_in[10];
    const float* Ws = (const float*)d_in[11];
    const float* bs = (const float*)d_in[12];
    const float* Wt = (const float*)d_in[13];
    const float* bt = (const float*)d_in[14];
    const float* Kb = (const float*)d_in[15];
    const float* base_s = (const float*)d_in[16];
    const float* base_t = (const float*)d_in[17];
    float* out = (float*)d_out;

    float* w = (float*)d_ws;
    const size_t M2 = (size_t)NS * NS;
    float* Ksrc = w;
    float* Kcos = w + M2;
    float* Ktgt = w + 2 * M2;
    float* stag = w + 3 * M2;
    float* wsb = stag;
    float* wtb = stag + (size_t)NS * NB;
    float* wsK = stag + 2 * (size_t)NS * NB;
    float* wtK = stag + 3 * (size_t)NS * NB;
    float* Z = stag;
    float* T = w + 4 * M2;
    float* sm = T + (size_t)1024 * 1024;
    float* wcomb = sm;
    float* consts = sm + 1024;
    float* a_s = sm + 1032;
    float* b_s = a_s + NS;
    float* a_t = b_s + NB;
    float* b_t = a_t + NS;
    float* rvec = b_t + NB;
    float* vvec = rvec + NS;
    float* z2 = vvec + NS;
    int* flags = (int*)(z2 + NS);   // 64 ints

    // 0) flags for the fused chol steps
    init_flags_k<<<1, 64, 0, stream>>>(flags);

    // 1) feature maps + kernel weights
    prep_k<<<1, 256, 0, stream>>>(Wf, bf, Ws, Wt, wcomb, consts);
    matvec_k<<<NS / 4, 256, 0, stream>>>(source_x, NS, wcomb + 0 * DIMX, consts, 0, a_s);
    matvec_k<<<NB / 4, 256, 0, stream>>>(base_s, NB, wcomb + 1 * DIMX, consts, 1, b_s);
    matvec_k<<<NS / 4, 256, 0, stream>>>(target_x, NS, wcomb + 2 * DIMX, consts, 2, a_t);
    matvec_k<<<NB / 4, 256, 0, stream>>>(base_t, NB, wcomb + 3 * DIMX, consts, 3, b_t);
    weights_k<<<NS, 256, 0, stream>>>(a_s, b_s, bs, wsb);
    weights_k<<<NS, 256, 0, stream>>>(a_t, b_t, bt, wtb);

    // 2) wsK = ws@Kb, wtK = wt@Kb  (batched z=2)
    gemm128_k<0, 0><<<dim3(NB / 128, NS / 128, 2), 512, 0, stream>>>(
        NS, NB, NB, wsb, NB, (size_t)NS * NB, Kb, NB, 0, wsK, NB, (size_t)NS * NB,
        nullptr, 0, nullptr, nullptr, nullptr, 0, 0, 0, 0);

    // 3) K_src & K_tgt (batched z=2, per-z kmat/noise; zoffC = 2*M2 -> Ktgt), then K_cos
    gemm128_k<0, 1><<<dim3(NS / 128, NS / 128, 2), 512, 0, stream>>>(
        NS, NS, NB, wsK, NB, (size_t)NS * NB, wsb, NB, (size_t)NS * NB, Ksrc, NS, 2 * M2,
        k_ss, NS, noise_s, k_tt, noise_t, 1, 0, 0, 0);
    gemm128_k<0, 1><<<dim3(NS / 128, NS / 128), 512, 0, stream>>>(
        NS, NS, NB, wsK, NB, 0, wtb, NB, 0, Kcos, NS, 0,
        k_st, NS, nullptr, nullptr, nullptr, 2, 0, 0, 0);

    // 4) Cholesky of K_src + full triangular inversion -> Linv in Ksrc
    run_chol(Ksrc, flags, stream);
    run_inv(Ksrc, T, stream);

    // 5) Z = Linv @ Kcos (K trimmed to the lower band)
    gemm128_k<0, 0><<<dim3(NS / 128, NS / 128), 512, 0, stream>>>(
        NS, NS, NS, Ksrc, NS, 0, Kcos, NS, 0, Z, NS, 0,
        nullptr, 0, nullptr, nullptr, nullptr, 0, 0, 0, 2);

    // 6) z2 = Linv @ source_y ; r = target_y - Z^T z2
    gemv_lower_k<<<NS / 4, 256, 0, stream>>>(Ksrc, NS, source_y, z2, NS);
    resid_part_k<<<dim3(NS / 256, 32), 256, 0, stream>>>(Z, z2, T);
    resid_fin_k<<<NS / 256, 256, 0, stream>>>(T, target_y, rvec);

    // 7) cov = K_tgt - Z^T Z (lower tiles only)
    gemm128_k<1, 0><<<dim3(NS / 128, NS / 128), 512, 0, stream>>>(
        NS, NS, NS, Z, NS, 0, Z, NS, 0, Ktgt, NS, 0,
        nullptr, 0, nullptr, nullptr, nullptr, 3, 0, 0, 1);

    // 8) Cholesky of cov + full triangular inversion -> Lcinv in Ktgt
    run_chol(Ktgt, flags + 16, stream);
    run_inv(Ktgt, T, stream);

    // 9) v = Lcinv @ r ; loss (log diag(Lc) = -log diag(Lcinv))
    gemv_lower_k<<<NS / 4, 256, 0, stream>>>(Ktgt, NS, rvec, vvec, NS);
    loss_k<<<1, 256, 0, stream>>>(Ktgt, NS, NS, -1.0f, vvec, out);
}

// Round 11
// 6611.585 us; speedup vs baseline: 3.9239x; 1.1883x over previous
//
#include <hip/hip_runtime.h>
#include <hip/hip_bf16.h>
#include <math.h>

#define NS 2048
#define NB 512
#define DIMX 256
#define NFEAT 8
#define DPAD 129
#define BI 16
#define NBK 8
#define BST 40   // ushorts per LDS row (32 + 8 pad): 80 B rows -> 2-way max conflicts

typedef __attribute__((ext_vector_type(8))) short s16x8;
typedef __attribute__((ext_vector_type(4))) float f32x4;

__device__ __forceinline__ void split_bf16(float x, ushort& h, ushort& l) {
    uint u = __float_as_uint(x);
    h = (ushort)(u >> 16);
    float hf = __uint_as_float((uint)h << 16);
    float r = x - hf;
    l = (ushort)(__float_as_uint(r) >> 16);
}

// ---------------- small prep kernels ----------------

__global__ __launch_bounds__(256) void prep_k(const float* __restrict__ Wf,
                                              const float* __restrict__ bf,
                                              const float* __restrict__ Ws,
                                              const float* __restrict__ Wt,
                                              float* __restrict__ wcomb,
                                              float* __restrict__ consts) {
    int d = threadIdx.x;
    float w0 = 0.f, w1 = 0.f, w2 = 0.f, w3 = 0.f;
#pragma unroll
    for (int k = 0; k < NFEAT; ++k) {
        float wf = Wf[k * DIMX + d];
        w0 += Ws[k] * wf;
        w1 += Ws[NFEAT + k] * wf;
        w2 += Wt[k] * wf;
        w3 += Wt[NFEAT + k] * wf;
    }
    wcomb[0 * DIMX + d] = w0;
    wcomb[1 * DIMX + d] = w1;
    wcomb[2 * DIMX + d] = w2;
    wcomb[3 * DIMX + d] = w3;
    if (d == 0) {
        float c0 = 0.f, c1 = 0.f, c2 = 0.f, c3 = 0.f;
#pragma unroll
        for (int k = 0; k < NFEAT; ++k) {
            c0 += Ws[k] * bf[k];
            c1 += Ws[NFEAT + k] * bf[k];
            c2 += Wt[k] * bf[k];
            c3 += Wt[NFEAT + k] * bf[k];
        }
        consts[0] = c0; consts[1] = c1; consts[2] = c2; consts[3] = c3;
    }
}

__global__ __launch_bounds__(256) void matvec_k(const float* __restrict__ X, int nrows,
                                                const float* __restrict__ wc,
                                                const float* __restrict__ consts, int cidx,
                                                float* __restrict__ out) {
    int wave = threadIdx.x >> 6, lane = threadIdx.x & 63;
    int row = blockIdx.x * 4 + wave;
    if (row >= nrows) return;
    const float* xr = X + (size_t)row * DIMX;
    float s = 0.f;
#pragma unroll
    for (int t = 0; t < 4; ++t) s += xr[lane + 64 * t] * wc[lane + 64 * t];
#pragma unroll
    for (int off = 32; off; off >>= 1) s += __shfl_down(s, off);
    if (lane == 0) out[row] = s + consts[cidx];
}

__global__ __launch_bounds__(256) void weights_k(const float* __restrict__ a,
                                                 const float* __restrict__ b,
                                                 const float* __restrict__ bw,
                                                 float* __restrict__ w) {
    __shared__ float red[256];
    int i = blockIdx.x, tid = threadIdx.x;
    float ai = a[i] + bw[0];
    float r1 = ai + b[tid];
    float r2 = ai + b[tid + 256];
    float e1 = r1 > 0.f ? r1 : expm1f(r1);
    float e2 = r2 > 0.f ? r2 : expm1f(r2);
    red[tid] = e1 + e2;
    __syncthreads();
    for (int s = 128; s; s >>= 1) {
        if (tid < s) red[tid] += red[tid + s];
        __syncthreads();
    }
    float scale = 512.f / red[0];
    w[(size_t)i * NB + tid] = e1 * scale;
    w[(size_t)i * NB + tid + 256] = e2 * scale;
}

__global__ __launch_bounds__(64) void init_flags_k(int* __restrict__ f) {
    f[threadIdx.x] = 0;
}

// -------- 128-tile split-bf16 MFMA GEMM, 512 thr (8 waves, 2x4), K-step 32 --------
// C = op(A)@op(B) with a = a_hi + a_lo; D += Ahi*Bhi + Ahi*Blo + Alo*Bhi (~2^-16 rel).
// mode 0: C=acc | 1: C=kmat*acc+diag(noise) | 2: C=kmat*acc | 3: C=C-acc | 4: C=-acc
// flags bit0 = lower_only; bit1 = ktrim (K<=rowBase+128); bit2 = kstart (K from colBase)
// kmat2/noisep2: per-z overrides (bz==1). M,N mult of 128; K mult of 32.
template <int TA, int TB>
__global__ __launch_bounds__(512) void gemm_bf_k(int M, int N, int K,
                                                 const float* __restrict__ A, int lda, size_t zoffA,
                                                 const float* __restrict__ B, int ldb, size_t zoffB,
                                                 float* __restrict__ C, int ldc, size_t zoffC,
                                                 const float* __restrict__ kmat, int ldk,
                                                 const float* __restrict__ noisep,
                                                 const float* __restrict__ kmat2,
                                                 const float* __restrict__ noisep2,
                                                 int mode, int row0, int col0, int flags) {
    __shared__ ushort Ah[128 * BST], Al[128 * BST], Bh[128 * BST], Bl[128 * BST];
    int bz = blockIdx.z;
    A += zoffA * bz; B += zoffB * bz; C += zoffC * bz;
    if (bz == 1) {
        if (kmat2) kmat = kmat2;
        if (noisep2) noisep = noisep2;
    }

    // bijective XCD swizzle (m204)
    int gx = gridDim.x;
    int nwg = gx * gridDim.y;
    int flat = blockIdx.y * gx + blockIdx.x;
    int qq = nwg >> 3, rr = nwg & 7;
    int xcd = flat & 7, pos = flat >> 3;
    int swz = (xcd < rr) ? (xcd * (qq + 1) + pos)
                         : (rr * (qq + 1) + (xcd - rr) * qq + pos);
    int bm = swz / gx, bn = swz % gx;

    int rowBase = bm * 128, colBase = bn * 128;
    if ((flags & 1) && (rowBase + 127) < colBase) return;
    int Kend = (flags & 2) ? ((rowBase + 128 < K) ? rowBase + 128 : K) : K;
    int Kstart = (flags & 4) ? colBase : 0;

    int tid = threadIdx.x;
    int lane = tid & 63, wid = tid >> 6;
    int wr = wid >> 2, wc = wid & 3;            // wave grid 2 (M) x 4 (N)
    int fr = lane & 15, fk = (lane >> 4) * 8;   // fragment row/col & k-chunk

    int sidx = tid >> 2;            // staging M-index / col-index (0..127)
    int sk0 = (tid & 3) * 8;        // staging k offset (0,8,16,24)

    float av[8], bv[8];
    auto loadAB = [&](int kk) {
        if (TA == 0) {
            const float* src = A + (size_t)(rowBase + sidx) * lda + kk + sk0;
            float4 v0 = *(const float4*)src;
            float4 v1 = *(const float4*)(src + 4);
            av[0] = v0.x; av[1] = v0.y; av[2] = v0.z; av[3] = v0.w;
            av[4] = v1.x; av[5] = v1.y; av[6] = v1.z; av[7] = v1.w;
        } else {
#pragma unroll
            for (int q = 0; q < 8; ++q)
                av[q] = A[(size_t)(kk + sk0 + q) * lda + rowBase + sidx];
        }
        if (TB == 0) {
#pragma unroll
            for (int q = 0; q < 8; ++q)
                bv[q] = B[(size_t)(kk + sk0 + q) * ldb + colBase + sidx];
        } else {
            const float* src = B + (size_t)(colBase + sidx) * ldb + kk + sk0;
            float4 v0 = *(const float4*)src;
            float4 v1 = *(const float4*)(src + 4);
            bv[0] = v0.x; bv[1] = v0.y; bv[2] = v0.z; bv[3] = v0.w;
            bv[4] = v1.x; bv[5] = v1.y; bv[6] = v1.z; bv[7] = v1.w;
        }
    };
    auto cvtStore = [&]() {
        uint hw[4], lw[4];
#pragma unroll
        for (int q = 0; q < 4; ++q) {
            ushort h0, l0, h1, l1;
            split_bf16(av[2 * q], h0, l0);
            split_bf16(av[2 * q + 1], h1, l1);
            hw[q] = (uint)h0 | ((uint)h1 << 16);
            lw[q] = (uint)l0 | ((uint)l1 << 16);
        }
        int idx = sidx * BST + sk0;
        *(uint4*)&Ah[idx] = make_uint4(hw[0], hw[1], hw[2], hw[3]);
        *(uint4*)&Al[idx] = make_uint4(lw[0], lw[1], lw[2], lw[3]);
#pragma unroll
        for (int q = 0; q < 4; ++q) {
            ushort h0, l0, h1, l1;
            split_bf16(bv[2 * q], h0, l0);
            split_bf16(bv[2 * q + 1], h1, l1);
            hw[q] = (uint)h0 | ((uint)h1 << 16);
            lw[q] = (uint)l0 | ((uint)l1 << 16);
        }
        *(uint4*)&Bh[idx] = make_uint4(hw[0], hw[1], hw[2], hw[3]);
        *(uint4*)&Bl[idx] = make_uint4(lw[0], lw[1], lw[2], lw[3]);
    };

    f32x4 acc[4][2];
#pragma unroll
    for (int m = 0; m < 4; ++m)
#pragma unroll
        for (int n = 0; n < 2; ++n) acc[m][n] = (f32x4){0.f, 0.f, 0.f, 0.f};

    int nt = (Kend - Kstart) >> 5;
    loadAB(Kstart);
    for (int t = 0; t < nt; ++t) {
        cvtStore();
        __syncthreads();
        if (t + 1 < nt) loadAB(Kstart + (t + 1) * 32);   // in flight during MFMA phase

        s16x8 ah[4], al[4], bh[2], bl[2];
#pragma unroll
        for (int m = 0; m < 4; ++m) {
            int off = (wr * 64 + m * 16 + fr) * BST + fk;
            ah[m] = *(const s16x8*)&Ah[off];
            al[m] = *(const s16x8*)&Al[off];
        }
#pragma unroll
        for (int n = 0; n < 2; ++n) {
            int off = (wc * 32 + n * 16 + fr) * BST + fk;
            bh[n] = *(const s16x8*)&Bh[off];
            bl[n] = *(const s16x8*)&Bl[off];
        }
#pragma unroll
        for (int m = 0; m < 4; ++m) {
#pragma unroll
            for (int n = 0; n < 2; ++n) {
                acc[m][n] = __builtin_amdgcn_mfma_f32_16x16x32_bf16(ah[m], bh[n], acc[m][n], 0, 0, 0);
                acc[m][n] = __builtin_amdgcn_mfma_f32_16x16x32_bf16(ah[m], bl[n], acc[m][n], 0, 0, 0);
                acc[m][n] = __builtin_amdgcn_mfma_f32_16x16x32_bf16(al[m], bh[n], acc[m][n], 0, 0, 0);
            }
        }
        __syncthreads();
    }

    // epilogue: C/D layout (m89-verified): col=lane&15, row=(lane>>4)*4+reg
#pragma unroll
    for (int m = 0; m < 4; ++m) {
#pragma unroll
        for (int n = 0; n < 2; ++n) {
            int gj = colBase + wc * 32 + n * 16 + fr;
#pragma unroll
            for (int reg = 0; reg < 4; ++reg) {
                int gi = rowBase + wr * 64 + m * 16 + (lane >> 4) * 4 + reg;
                float v = acc[m][n][reg];
                if (mode == 1 || mode == 2) {
                    v *= kmat[(size_t)gi * ldk + gj];
                    if (mode == 1 && (row0 + gi) == (col0 + gj)) {
                        float ns = noisep[0];
                        ns = fminf(fmaxf(ns, 1e-5f), 1.0f);
                        v += ns;
                    }
                } else if (mode == 3) {
                    v = C[(size_t)gi * ldc + gj] - v;
                } else if (mode == 4) {
                    v = -v;
                }
                C[(size_t)gi * ldc + gj] = v;
            }
        }
    }
}

// ------- fused Cholesky step: block 0 = diag chol+inverse; blocks >=1 = panel -------
__global__ __launch_bounds__(512) void chol_step_k(float* __restrict__ A, int lda, int kb,
                                                   int* __restrict__ flag) {
    extern __shared__ float s[];              // 128 * DPAD floats
    __shared__ float Ps[2][16][132];
    __shared__ float rsd[128];
    __shared__ float xd[NBK][BI][BI + 1];
    __shared__ float wbuf[NBK - 1][BI][BI + 1];
    int tid = threadIdx.x;

    if (blockIdx.x == 0) {
        float* Ad = A + (size_t)kb * 128 * (lda + 1);
        for (int idx = tid; idx < 128 * 128; idx += 512) {
            int r = idx >> 7, c = idx & 127;
            s[r * DPAD + c] = Ad[(size_t)r * lda + c];
        }
        __syncthreads();

        // deferred-scaling right-looking Cholesky: one barrier per k
        int b = tid >> 5, a = tid & 31;    // 16 x 32
        for (int k = 0; k < 128; ++k) {
            float isq = 1.0f / s[k * DPAD + k];
            for (int i = k + 1 + b; i < 128; i += 16) {
                float f = s[i * DPAD + k] * isq;
                float* row = s + (size_t)i * DPAD;
                for (int j = k + 1 + a; j <= i; j += 32) {
                    row[j] -= f * s[j * DPAD + k];
                }
            }
            __syncthreads();
        }

        if (tid < 128) rsd[tid] = rsqrtf(s[tid * DPAD + tid]);
        __syncthreads();
        for (int idx = tid; idx < 128 * 128; idx += 512) {
            int r = idx >> 7, c = idx & 127;
            if (c < r) s[r * DPAD + c] *= rsd[c];
            else if (c == r) s[r * DPAD + r] = 1.0f / rsd[r];
        }
        __syncthreads();

        // phase A: invert the 8 diagonal 16x16 blocks (column-parallel)
        {
            int g = tid >> 4, l = tid & 15;
            if (g < NBK) {
                const float* Lb = s + (size_t)(g * BI) * DPAD + g * BI;
                for (int r = 0; r < BI; ++r) {
                    float acc = (r == l) ? 1.f : 0.f;
                    for (int t = l; t < r; ++t) acc -= Lb[r * DPAD + t] * xd[g][t][l];
                    xd[g][r][l] = (r >= l) ? acc / Lb[r * DPAD + r] : 0.f;
                }
            }
        }
        __syncthreads();

        // phase B: off-diagonal blocks by diagonal offset (X stored transposed upper)
        for (int d = 1; d < NBK; ++d) {
            int npairs = NBK - d;
            for (int e = tid; e < npairs * 256; e += 512) {
                int p = e >> 8, ab = e & 255;
                int a2 = ab >> 4, b2 = ab & 15;
                int J = p, I = p + d;
                int Ibase = I * BI, Jbase = J * BI;
                float acc = 0.f;
                {
                    const float* Lr = s + (size_t)(Ibase + a2) * DPAD + Jbase;
                    for (int t = 0; t < BI; ++t) acc += Lr[t] * xd[J][t][b2];
                }
                for (int K = J + 1; K < I; ++K) {
                    int Kbase = K * BI;
                    const float* Lr = s + (size_t)(Ibase + a2) * DPAD + Kbase;
                    const float* Xc = s + (size_t)(Jbase + b2) * DPAD + Kbase;
                    for (int t = 0; t < BI; ++t) acc += Lr[t] * Xc[t];
                }
                wbuf[p][a2][b2] = acc;
            }
            __syncthreads();
            for (int e = tid; e < npairs * 256; e += 512) {
                int p = e >> 8, ab = e & 255;
                int a2 = ab >> 4, b2 = ab & 15;
                int J = p, I = p + d;
                float acc = 0.f;
                for (int t = 0; t < BI; ++t) acc += xd[I][a2][t] * wbuf[p][t][b2];
                s[(size_t)(J * BI + b2) * DPAD + I * BI + a2] = -acc;
            }
            __syncthreads();
        }

        // write back Dinv (zeros in strict upper)
        for (int idx = tid; idx < 128 * 128; idx += 512) {
            int r = idx >> 7, c = idx & 127;
            float v;
            if (c > r) {
                v = 0.f;
            } else {
                int gr = r >> 4, gc = c >> 4;
                v = (gr == gc) ? xd[gr][r & 15][c & 15] : s[(size_t)c * DPAD + r];
            }
            Ad[(size_t)r * lda + c] = v;
        }
        __threadfence();
        __syncthreads();
        if (tid == 0) {
            __hip_atomic_store(flag, 1, __ATOMIC_RELEASE, __HIP_MEMORY_SCOPE_AGENT);
        }
        return;
    }

    // ---------------- panel block: P = P @ Dinv^T ----------------
    if (tid == 0) {
        while (__hip_atomic_load(flag, __ATOMIC_ACQUIRE, __HIP_MEMORY_SCOPE_AGENT) == 0) {}
    }
    __syncthreads();
    __threadfence();

    float* Pb = A + (size_t)(kb + blockIdx.x) * 128 * lda + (size_t)kb * 128;
    const float* D = A + (size_t)kb * 128 * (lda + 1);

    // stage Dinv TRANSPOSED into s: s[k*DPAD + j] = D[j][k]
    for (int idx = tid; idx < 128 * 128; idx += 512) {
        int j = idx >> 7, k = idx & 127;
        s[(size_t)k * DPAD + j] = D[(size_t)j * lda + k];
    }

    int tx = tid & 31, ty = tid >> 5;
    float acc[8][4];
#pragma unroll
    for (int i = 0; i < 8; ++i)
#pragma unroll
        for (int j = 0; j < 4; ++j) acc[i][j] = 0.f;

    float rp[4];
    auto loadP = [&](int kk) {
        int row = tid >> 2, koff = (tid & 3) * 4;
        const float* src = Pb + (size_t)row * lda + kk + koff;
        float4 v = *(const float4*)src;
        rp[0] = v.x; rp[1] = v.y; rp[2] = v.z; rp[3] = v.w;
    };
    auto storeP = [&](int buf) {
        int row = tid >> 2, koff = (tid & 3) * 4;
#pragma unroll
        for (int q = 0; q < 4; ++q) Ps[buf][koff + q][row] = rp[q];
    };

    loadP(0);
    storeP(0);
    for (int t = 0; t < 8; ++t) {
        __syncthreads();
        int cur = t & 1;
        bool more = (t + 1 < 8);
        if (more) loadP((t + 1) * 16);
#pragma unroll
        for (int k = 0; k < 16; ++k) {
            float a[8], b[4];
            float4 t0 = *(const float4*)&Ps[cur][k][ty * 4];
            float4 t1 = *(const float4*)&Ps[cur][k][64 + ty * 4];
            float4 u0 = *(const float4*)&s[(size_t)(t * 16 + k) * DPAD + tx * 4];
            a[0] = t0.x; a[1] = t0.y; a[2] = t0.z; a[3] = t0.w;
            a[4] = t1.x; a[5] = t1.y; a[6] = t1.z; a[7] = t1.w;
            b[0] = u0.x; b[1] = u0.y; b[2] = u0.z; b[3] = u0.w;
#pragma unroll
            for (int i = 0; i < 8; ++i)
#pragma unroll
                for (int j = 0; j < 4; ++j) acc[i][j] += a[i] * b[j];
        }
        if (more) storeP(cur ^ 1);
    }
#pragma unroll
    for (int i = 0; i < 8; ++i) {
        int gi = ((i >> 2) << 6) + ty * 4 + (i & 3);
#pragma unroll
        for (int j = 0; j < 4; ++j) {
            Pb[(size_t)gi * lda + tx * 4 + j] = acc[i][j];
        }
    }
}

__global__ __launch_bounds__(256) void gemv_lower_k(const float* __restrict__ L, int ld,
                                                    const float* __restrict__ y,
                                                    float* __restrict__ z, int n) {
    int wave = threadIdx.x >> 6, lane = threadIdx.x & 63;
    int row = blockIdx.x * 4 + wave;
    if (row >= n) return;
    const float* Lr = L + (size_t)row * ld;
    float s = 0.f;
    for (int j = lane; j <= row; j += 64) s += Lr[j] * y[j];
#pragma unroll
    for (int off = 32; off; off >>= 1) s += __shfl_down(s, off);
    if (lane == 0) z[row] = s;
}

__global__ __launch_bounds__(256) void resid_part_k(const float* __restrict__ Z,
                                                    const float* __restrict__ zv,
                                                    float* __restrict__ part) {
    int j = blockIdx.x * 256 + threadIdx.x;
    int i0 = blockIdx.y * 64;
    float acc = 0.f;
    for (int i = i0; i < i0 + 64; ++i) acc += Z[(size_t)i * NS + j] * zv[i];
    part[(size_t)blockIdx.y * NS + j] = acc;
}

__global__ __launch_bounds__(256) void resid_fin_k(const float* __restrict__ part,
                                                   const float* __restrict__ ty,
                                                   float* __restrict__ r) {
    int j = blockIdx.x * 256 + threadIdx.x;
    float acc = 0.f;
    for (int q = 0; q < 32; ++q) acc += part[(size_t)q * NS + j];
    r[j] = ty[j] - acc;
}

__global__ __launch_bounds__(256) void loss_k(const float* __restrict__ Lc, int n, int ldl,
                                              float sign,
                                              const float* __restrict__ v,
                                              float* __restrict__ out) {
    __shared__ float red1[256];
    __shared__ float red2[256];
    int tid = threadIdx.x;
    float s1 = 0.f, s2 = 0.f;
    for (int i = tid; i < n; i += 256) {
        s1 += logf(Lc[(size_t)i * ldl + i]);
        float vi = v[i];
        s2 += vi * vi;
    }
    red1[tid] = s1;
    red2[tid] = s2;
    __syncthreads();
    for (int s = 128; s; s >>= 1) {
        if (tid < s) { red1[tid] += red1[tid + s]; red2[tid] += red2[tid + s]; }
        __syncthreads();
    }
    if (tid == 0) {
        out[0] = 0.5f * sign * red1[0] + 0.5f * red2[0] + 0.5f * (float)n * 1.8378770664093453f;
    }
}

// ---------------- host orchestration ----------------

static const size_t CHOL_LDS = (size_t)128 * DPAD * sizeof(float);  // 66 KB dynamic

static void run_chol(float* A, int* flags, hipStream_t stream) {
    for (int kb = 0; kb < 16; ++kb) {
        int nrem = 15 - kb;
        chol_step_k<<<dim3(1 + nrem), 512, CHOL_LDS, stream>>>(A, NS, kb, flags + kb);
        if (nrem > 0) {
            float* P = A + (size_t)(kb + 1) * 128 * NS + kb * 128;
            float* Ct = A + (size_t)(kb + 1) * 128 * (NS + 1);
            gemm_bf_k<0, 1><<<dim3(nrem, nrem), 512, 0, stream>>>(
                nrem * 128, nrem * 128, 128, P, NS, 0, P, NS, 0, Ct, NS, 0,
                nullptr, 0, nullptr, nullptr, nullptr, 3, 0, 0, 1);
        }
    }
}

// In-place recursive inversion of the lower-triangular factor (diag 128-blocks
// already hold Dinv with explicit zeros above the diagonal, so no zero_upper
// pass is needed: every GEMM reads only the lower band + zeroed diag blocks).
static void run_inv(float* A, float* T, hipStream_t stream) {
    for (int s = 128; s <= 1024; s <<= 1) {
        int np = NS / (2 * s);
        size_t zz = (size_t)2 * s * (NS + 1);
        size_t zt = (size_t)s * s;
        dim3 g(s / 128, s / 128, np);
        gemm_bf_k<0, 0><<<g, 512, 0, stream>>>(s, s, s, A + (size_t)s * NS, NS, zz,
                                               A, NS, zz, T, s, zt,
                                               nullptr, 0, nullptr, nullptr, nullptr,
                                               0, 0, 0, 4);
        gemm_bf_k<0, 0><<<g, 512, 0, stream>>>(s, s, s, A + (size_t)s * (NS + 1), NS, zz,
                                               T, s, zt, A + (size_t)s * NS, NS, zz,
                                               nullptr, 0, nullptr, nullptr, nullptr,
                                               4, 0, 0, 2);
    }
}

extern "C" void kernel_launch(void* const* d_in, const int* in_sizes, int n_in,
                              void* d_out, int out_size, void* d_ws, size_t ws_size,
                              hipStream_t stream) {
    const float* source_x = (const float*)d_in[0];
    const float* source_y = (const float*)d_in[1];
    const float* target_x = (const float*)d_in[2];
    const float* target_y = (const float*)d_in[3];
    const float* k_ss = (const float*)d_in[4];
    const float* k_tt = (const float*)d_in[5];
    const float* k_st = (const float*)d_in[6];
    const float* noise_s = (const float*)d_in[7];
    const float* noise_t = (const float*)d_in[8];
    const float* Wf = (const float*)d_in[9];
    const float* bf = (const float*)d_in[10];
    const float* Ws = (const float*)d_in[11];
    const float* bs = (const float*)d_in[12];
    const float* Wt = (const float*)d_in[13];
    const float* bt = (const float*)d_in[14];
    const float* Kb = (const float*)d_in[15];
    const float* base_s = (const float*)d_in[16];
    const float* base_t = (const float*)d_in[17];
    float* out = (float*)d_out;

    float* w = (float*)d_ws;
    const size_t M2 = (size_t)NS * NS;
    float* Ksrc = w;
    float* Kcos = w + M2;
    float* Ktgt = w + 2 * M2;
    float* stag = w + 3 * M2;
    float* wsb = stag;
    float* wtb = stag + (size_t)NS * NB;
    float* wsK = stag + 2 * (size_t)NS * NB;
    float* wtK = stag + 3 * (size_t)NS * NB;
    float* Z = stag;
    float* T = w + 4 * M2;
    float* sm = T + (size_t)1024 * 1024;
    float* wcomb = sm;
    float* consts = sm + 1024;
    float* a_s = sm + 1032;
    float* b_s = a_s + NS;
    float* a_t = b_s + NB;
    float* b_t = a_t + NS;
    float* rvec = b_t + NB;
    float* vvec = rvec + NS;
    float* z2 = vvec + NS;
    int* flags = (int*)(z2 + NS);   // 64 ints

    // 0) flags for the fused chol steps
    init_flags_k<<<1, 64, 0, stream>>>(flags);

    // 1) feature maps + kernel weights
    prep_k<<<1, 256, 0, stream>>>(Wf, bf, Ws, Wt, wcomb, consts);
    matvec_k<<<NS / 4, 256, 0, stream>>>(source_x, NS, wcomb + 0 * DIMX, consts, 0, a_s);
    matvec_k<<<NB / 4, 256, 0, stream>>>(base_s, NB, wcomb + 1 * DIMX, consts, 1, b_s);
    matvec_k<<<NS / 4, 256, 0, stream>>>(target_x, NS, wcomb + 2 * DIMX, consts, 2, a_t);
    matvec_k<<<NB / 4, 256, 0, stream>>>(base_t, NB, wcomb + 3 * DIMX, consts, 3, b_t);
    weights_k<<<NS, 256, 0, stream>>>(a_s, b_s, bs, wsb);
    weights_k<<<NS, 256, 0, stream>>>(a_t, b_t, bt, wtb);

    // 2) wsK = ws@Kb, wtK = wt@Kb  (batched z=2)
    gemm_bf_k<0, 0><<<dim3(NB / 128, NS / 128, 2), 512, 0, stream>>>(
        NS, NB, NB, wsb, NB, (size_t)NS * NB, Kb, NB, 0, wsK, NB, (size_t)NS * NB,
        nullptr, 0, nullptr, nullptr, nullptr, 0, 0, 0, 0);

    // 3) K_src & K_tgt (batched z=2, per-z kmat/noise; zoffC = 2*M2 -> Ktgt), then K_cos
    gemm_bf_k<0, 1><<<dim3(NS / 128, NS / 128, 2), 512, 0, stream>>>(
        NS, NS, NB, wsK, NB, (size_t)NS * NB, wsb, NB, (size_t)NS * NB, Ksrc, NS, 2 * M2,
        k_ss, NS, noise_s, k_tt, noise_t, 1, 0, 0, 0);
    gemm_bf_k<0, 1><<<dim3(NS / 128, NS / 128), 512, 0, stream>>>(
        NS, NS, NB, wsK, NB, 0, wtb, NB, 0, Kcos, NS, 0,
        k_st, NS, nullptr, nullptr, nullptr, 2, 0, 0, 0);

    // 4) Cholesky of K_src + full triangular inversion -> Linv in Ksrc
    run_chol(Ksrc, flags, stream);
    run_inv(Ksrc, T, stream);

    // 5) Z = Linv @ Kcos (K trimmed to the lower band)
    gemm_bf_k<0, 0><<<dim3(NS / 128, NS / 128), 512, 0, stream>>>(
        NS, NS, NS, Ksrc, NS, 0, Kcos, NS, 0, Z, NS, 0,
        nullptr, 0, nullptr, nullptr, nullptr, 0, 0, 0, 2);

    // 6) z2 = Linv @ source_y ; r = target_y - Z^T z2
    gemv_lower_k<<<NS / 4, 256, 0, stream>>>(Ksrc, NS, source_y, z2, NS);
    resid_part_k<<<dim3(NS / 256, 32), 256, 0, stream>>>(Z, z2, T);
    resid_fin_k<<<NS / 256, 256, 0, stream>>>(T, target_y, rvec);

    // 7) cov = K_tgt - Z^T Z (lower tiles only)
    gemm_bf_k<1, 0><<<dim3(NS / 128, NS / 128), 512, 0, stream>>>(
        NS, NS, NS, Z, NS, 0, Z, NS, 0, Ktgt, NS, 0,
        nullptr, 0, nullptr, nullptr, nullptr, 3, 0, 0, 1);

    // 8) Cholesky of cov + full triangular inversion -> Lcinv in Ktgt
    run_chol(Ktgt, flags + 16, stream);
    run_inv(Ktgt, T, stream);

    // 9) v = Lcinv @ r ; loss (log diag(Lc) = -log diag(Lcinv))
    gemv_lower_k<<<NS / 4, 256, 0, stream>>>(Ktgt, NS, rvec, vvec, NS);
    loss_k<<<1, 256, 0, stream>>>(Ktgt, NS, NS, -1.0f, vvec, out);
}

// Round 12
// 4797.033 us; speedup vs baseline: 5.4082x; 1.3783x over previous
//
#include <hip/hip_runtime.h>
#include <hip/hip_bf16.h>
#include <math.h>

#define NS 2048
#define NB 512
#define DIMX 256
#define NFEAT 8
#define DPAD 129
#define BI 16
#define NBK 8
#define BST 40   // ushorts per LDS row (32 + 8 pad): 80 B rows -> 2-way max conflicts

typedef __attribute__((ext_vector_type(8))) short s16x8;
typedef __attribute__((ext_vector_type(4))) float f32x4;

__device__ __forceinline__ void split_bf16(float x, ushort& h, ushort& l) {
    uint u = __float_as_uint(x);
    h = (ushort)(u >> 16);
    float hf = __uint_as_float((uint)h << 16);
    float r = x - hf;
    l = (ushort)(__float_as_uint(r) >> 16);
}

// ---------------- small prep kernels ----------------

__global__ __launch_bounds__(256) void prep_k(const float* __restrict__ Wf,
                                              const float* __restrict__ bf,
                                              const float* __restrict__ Ws,
                                              const float* __restrict__ Wt,
                                              float* __restrict__ wcomb,
                                              float* __restrict__ consts) {
    int d = threadIdx.x;
    float w0 = 0.f, w1 = 0.f, w2 = 0.f, w3 = 0.f;
#pragma unroll
    for (int k = 0; k < NFEAT; ++k) {
        float wf = Wf[k * DIMX + d];
        w0 += Ws[k] * wf;
        w1 += Ws[NFEAT + k] * wf;
        w2 += Wt[k] * wf;
        w3 += Wt[NFEAT + k] * wf;
    }
    wcomb[0 * DIMX + d] = w0;
    wcomb[1 * DIMX + d] = w1;
    wcomb[2 * DIMX + d] = w2;
    wcomb[3 * DIMX + d] = w3;
    if (d == 0) {
        float c0 = 0.f, c1 = 0.f, c2 = 0.f, c3 = 0.f;
#pragma unroll
        for (int k = 0; k < NFEAT; ++k) {
            c0 += Ws[k] * bf[k];
            c1 += Ws[NFEAT + k] * bf[k];
            c2 += Wt[k] * bf[k];
            c3 += Wt[NFEAT + k] * bf[k];
        }
        consts[0] = c0; consts[1] = c1; consts[2] = c2; consts[3] = c3;
    }
}

__global__ __launch_bounds__(256) void matvec_k(const float* __restrict__ X, int nrows,
                                                const float* __restrict__ wc,
                                                const float* __restrict__ consts, int cidx,
                                                float* __restrict__ out) {
    int wave = threadIdx.x >> 6, lane = threadIdx.x & 63;
    int row = blockIdx.x * 4 + wave;
    if (row >= nrows) return;
    const float* xr = X + (size_t)row * DIMX;
    float s = 0.f;
#pragma unroll
    for (int t = 0; t < 4; ++t) s += xr[lane + 64 * t] * wc[lane + 64 * t];
#pragma unroll
    for (int off = 32; off; off >>= 1) s += __shfl_down(s, off);
    if (lane == 0) out[row] = s + consts[cidx];
}

__global__ __launch_bounds__(256) void weights_k(const float* __restrict__ a,
                                                 const float* __restrict__ b,
                                                 const float* __restrict__ bw,
                                                 float* __restrict__ w) {
    __shared__ float red[256];
    int i = blockIdx.x, tid = threadIdx.x;
    float ai = a[i] + bw[0];
    float r1 = ai + b[tid];
    float r2 = ai + b[tid + 256];
    float e1 = r1 > 0.f ? r1 : expm1f(r1);
    float e2 = r2 > 0.f ? r2 : expm1f(r2);
    red[tid] = e1 + e2;
    __syncthreads();
    for (int s = 128; s; s >>= 1) {
        if (tid < s) red[tid] += red[tid + s];
        __syncthreads();
    }
    float scale = 512.f / red[0];
    w[(size_t)i * NB + tid] = e1 * scale;
    w[(size_t)i * NB + tid + 256] = e2 * scale;
}

__global__ __launch_bounds__(64) void init_flags_k(int* __restrict__ f) {
    f[threadIdx.x] = 0;
}

// -------- 128-tile split-bf16 MFMA GEMM, 512 thr (8 waves, 2x4), K-step 32 --------
// C = op(A)@op(B) with a = a_hi + a_lo; D += Ahi*Bhi + Ahi*Blo + Alo*Bhi (~2^-16 rel).
// mode 0: C=acc | 1: C=kmat*acc+diag(noise) | 2: C=kmat*acc | 3: C=C-acc | 4: C=-acc
// flags bit0 = lower_only; bit1 = ktrim (K<=rowBase+128); bit2 = kstart (K from colBase)
// kmat2/noisep2: per-z overrides (bz==1). M,N mult of 128; K mult of 32.
template <int TA, int TB>
__global__ __launch_bounds__(512) void gemm_bf_k(int M, int N, int K,
                                                 const float* __restrict__ A, int lda, size_t zoffA,
                                                 const float* __restrict__ B, int ldb, size_t zoffB,
                                                 float* __restrict__ C, int ldc, size_t zoffC,
                                                 const float* __restrict__ kmat, int ldk,
                                                 const float* __restrict__ noisep,
                                                 const float* __restrict__ kmat2,
                                                 const float* __restrict__ noisep2,
                                                 int mode, int row0, int col0, int flags) {
    __shared__ ushort Ah[128 * BST], Al[128 * BST], Bh[128 * BST], Bl[128 * BST];
    int bz = blockIdx.z;
    A += zoffA * bz; B += zoffB * bz; C += zoffC * bz;
    if (bz == 1) {
        if (kmat2) kmat = kmat2;
        if (noisep2) noisep = noisep2;
    }

    // bijective XCD swizzle (m204)
    int gx = gridDim.x;
    int nwg = gx * gridDim.y;
    int flat = blockIdx.y * gx + blockIdx.x;
    int qq = nwg >> 3, rr = nwg & 7;
    int xcd = flat & 7, pos = flat >> 3;
    int swz = (xcd < rr) ? (xcd * (qq + 1) + pos)
                         : (rr * (qq + 1) + (xcd - rr) * qq + pos);
    int bm = swz / gx, bn = swz % gx;

    int rowBase = bm * 128, colBase = bn * 128;
    if ((flags & 1) && (rowBase + 127) < colBase) return;
    int Kend = (flags & 2) ? ((rowBase + 128 < K) ? rowBase + 128 : K) : K;
    int Kstart = (flags & 4) ? colBase : 0;

    int tid = threadIdx.x;
    int lane = tid & 63, wid = tid >> 6;
    int wr = wid >> 2, wc = wid & 3;            // wave grid 2 (M) x 4 (N)
    int fr = lane & 15, fk = (lane >> 4) * 8;   // fragment row/col & k-chunk

    int sidx = tid >> 2;            // staging M-index / col-index (0..127)
    int sk0 = (tid & 3) * 8;        // staging k offset (0,8,16,24)

    float av[8], bv[8];
    auto loadAB = [&](int kk) {
        if (TA == 0) {
            const float* src = A + (size_t)(rowBase + sidx) * lda + kk + sk0;
            float4 v0 = *(const float4*)src;
            float4 v1 = *(const float4*)(src + 4);
            av[0] = v0.x; av[1] = v0.y; av[2] = v0.z; av[3] = v0.w;
            av[4] = v1.x; av[5] = v1.y; av[6] = v1.z; av[7] = v1.w;
        } else {
#pragma unroll
            for (int q = 0; q < 8; ++q)
                av[q] = A[(size_t)(kk + sk0 + q) * lda + rowBase + sidx];
        }
        if (TB == 0) {
#pragma unroll
            for (int q = 0; q < 8; ++q)
                bv[q] = B[(size_t)(kk + sk0 + q) * ldb + colBase + sidx];
        } else {
            const float* src = B + (size_t)(colBase + sidx) * ldb + kk + sk0;
            float4 v0 = *(const float4*)src;
            float4 v1 = *(const float4*)(src + 4);
            bv[0] = v0.x; bv[1] = v0.y; bv[2] = v0.z; bv[3] = v0.w;
            bv[4] = v1.x; bv[5] = v1.y; bv[6] = v1.z; bv[7] = v1.w;
        }
    };
    auto cvtStore = [&]() {
        uint hw[4], lw[4];
#pragma unroll
        for (int q = 0; q < 4; ++q) {
            ushort h0, l0, h1, l1;
            split_bf16(av[2 * q], h0, l0);
            split_bf16(av[2 * q + 1], h1, l1);
            hw[q] = (uint)h0 | ((uint)h1 << 16);
            lw[q] = (uint)l0 | ((uint)l1 << 16);
        }
        int idx = sidx * BST + sk0;
        *(uint4*)&Ah[idx] = make_uint4(hw[0], hw[1], hw[2], hw[3]);
        *(uint4*)&Al[idx] = make_uint4(lw[0], lw[1], lw[2], lw[3]);
#pragma unroll
        for (int q = 0; q < 4; ++q) {
            ushort h0, l0, h1, l1;
            split_bf16(bv[2 * q], h0, l0);
            split_bf16(bv[2 * q + 1], h1, l1);
            hw[q] = (uint)h0 | ((uint)h1 << 16);
            lw[q] = (uint)l0 | ((uint)l1 << 16);
        }
        *(uint4*)&Bh[idx] = make_uint4(hw[0], hw[1], hw[2], hw[3]);
        *(uint4*)&Bl[idx] = make_uint4(lw[0], lw[1], lw[2], lw[3]);
    };

    f32x4 acc[4][2];
#pragma unroll
    for (int m = 0; m < 4; ++m)
#pragma unroll
        for (int n = 0; n < 2; ++n) acc[m][n] = (f32x4){0.f, 0.f, 0.f, 0.f};

    int nt = (Kend - Kstart) >> 5;
    loadAB(Kstart);
    for (int t = 0; t < nt; ++t) {
        cvtStore();
        __syncthreads();
        if (t + 1 < nt) loadAB(Kstart + (t + 1) * 32);   // in flight during MFMA phase

        s16x8 ah[4], al[4], bh[2], bl[2];
#pragma unroll
        for (int m = 0; m < 4; ++m) {
            int off = (wr * 64 + m * 16 + fr) * BST + fk;
            ah[m] = *(const s16x8*)&Ah[off];
            al[m] = *(const s16x8*)&Al[off];
        }
#pragma unroll
        for (int n = 0; n < 2; ++n) {
            int off = (wc * 32 + n * 16 + fr) * BST + fk;
            bh[n] = *(const s16x8*)&Bh[off];
            bl[n] = *(const s16x8*)&Bl[off];
        }
#pragma unroll
        for (int m = 0; m < 4; ++m) {
#pragma unroll
            for (int n = 0; n < 2; ++n) {
                acc[m][n] = __builtin_amdgcn_mfma_f32_16x16x32_bf16(ah[m], bh[n], acc[m][n], 0, 0, 0);
                acc[m][n] = __builtin_amdgcn_mfma_f32_16x16x32_bf16(ah[m], bl[n], acc[m][n], 0, 0, 0);
                acc[m][n] = __builtin_amdgcn_mfma_f32_16x16x32_bf16(al[m], bh[n], acc[m][n], 0, 0, 0);
            }
        }
        __syncthreads();
    }

    // epilogue: C/D layout (m89-verified): col=lane&15, row=(lane>>4)*4+reg
#pragma unroll
    for (int m = 0; m < 4; ++m) {
#pragma unroll
        for (int n = 0; n < 2; ++n) {
            int gj = colBase + wc * 32 + n * 16 + fr;
#pragma unroll
            for (int reg = 0; reg < 4; ++reg) {
                int gi = rowBase + wr * 64 + m * 16 + (lane >> 4) * 4 + reg;
                float v = acc[m][n][reg];
                if (mode == 1 || mode == 2) {
                    v *= kmat[(size_t)gi * ldk + gj];
                    if (mode == 1 && (row0 + gi) == (col0 + gj)) {
                        float ns = noisep[0];
                        ns = fminf(fmaxf(ns, 1e-5f), 1.0f);
                        v += ns;
                    }
                } else if (mode == 3) {
                    v = C[(size_t)gi * ldc + gj] - v;
                } else if (mode == 4) {
                    v = -v;
                }
                C[(size_t)gi * ldc + gj] = v;
            }
        }
    }
}

// ------- fused Cholesky step: block 0 = diag chol+inverse; blocks >=1 = panel -------
// Diag path: panel-blocked (16-wide) right-looking Cholesky:
//   phase1: wave-0 register/shfl factor of the 16x16 diag sub-block (no barriers)
//   phase2: row-parallel TRSM of the sub-panel (1 thread/row, serial-16 in regs)
//   phase3: rank-16 SYRK trailing update (4-wide j blocking, pnl stride-17 copy)
// then blocked 16x16 triangular inversion (unchanged), Dinv written back, flag release.
__global__ __launch_bounds__(512) void chol_step_k(float* __restrict__ A, int lda, int kb,
                                                   int* __restrict__ flag) {
    extern __shared__ float s[];              // 128 * DPAD floats
    __shared__ float Ps[2][16][132];
    __shared__ float pnl[128 * 17];
    __shared__ float xd[NBK][BI][BI + 1];
    __shared__ float wbuf[NBK - 1][BI][BI + 1];
    int tid = threadIdx.x;
    int lane = tid & 63, wid = tid >> 6;

    if (blockIdx.x == 0) {
        float* Ad = A + (size_t)kb * 128 * (lda + 1);
        for (int idx = tid; idx < 128 * 32; idx += 512) {
            int r = idx >> 5, c4 = (idx & 31) * 4;
            float4 v = *(const float4*)(Ad + (size_t)r * lda + c4);
            float* dst = s + (size_t)r * DPAD + c4;
            dst[0] = v.x; dst[1] = v.y; dst[2] = v.z; dst[3] = v.w;
        }
        __syncthreads();

        // ---- panel-blocked Cholesky, 16-wide panels ----
        for (int pb = 0; pb < 8; ++pb) {
            int pc0 = pb * 16, pe = pc0 + 16, nr = 128 - pe;

            // phase 1: wave 0 factors the 16x16 diag sub-block in registers
            if (wid == 0) {
                int r = lane & 15;
                float a[16];
#pragma unroll
                for (int j = 0; j < 16; ++j) a[j] = s[(size_t)(pc0 + r) * DPAD + pc0 + j];
#pragma unroll
                for (int k = 0; k < 16; ++k) {
                    float dk = sqrtf(__shfl(a[k], k));
                    float inv = 1.0f / dk;
                    if (r == k) a[k] = dk;
                    else if (r > k) a[k] *= inv;
#pragma unroll
                    for (int j = k + 1; j < 16; ++j) {
                        float ljk = __shfl(a[k], j);
                        if (r >= j) a[j] -= a[k] * ljk;
                    }
                }
                if (lane < 16) {
#pragma unroll
                    for (int j = 0; j < 16; ++j)
                        s[(size_t)(pc0 + r) * DPAD + pc0 + j] = (j <= r) ? a[j] : 0.f;
                }
            }
            __syncthreads();

            if (nr > 0) {
                // phase 2: TRSM rows below the panel (one thread per row)
                if (tid < nr) {
                    int i = pe + tid;
                    float* Lr = s + (size_t)i * DPAD + pc0;
                    float x[16];
#pragma unroll
                    for (int c = 0; c < 16; ++c) x[c] = Lr[c];
#pragma unroll
                    for (int c = 0; c < 16; ++c) {
                        float xc = x[c] / s[(size_t)(pc0 + c) * DPAD + pc0 + c];
                        x[c] = xc;
#pragma unroll
                        for (int t = c + 1; t < 16; ++t)
                            x[t] -= xc * s[(size_t)(pc0 + t) * DPAD + pc0 + c];
                    }
#pragma unroll
                    for (int c = 0; c < 16; ++c) {
                        Lr[c] = x[c];
                        pnl[i * 17 + c] = x[c];
                    }
                }
                __syncthreads();

                // phase 3: rank-16 SYRK on the trailing lower triangle
                int njb = nr >> 2;               // nr is a multiple of 16
                int ntask = nr * njb;
                for (int task = tid; task < ntask; task += 512) {
                    int ti = task % nr;          // i fastest -> bank spread
                    int jb = task / nr;
                    int i = pe + ti;
                    int j0 = pe + jb * 4;
                    if (j0 <= i) {
                        float xi[16];
#pragma unroll
                        for (int t = 0; t < 16; ++t) xi[t] = pnl[i * 17 + t];
#pragma unroll
                        for (int jj = 0; jj < 4; ++jj) {
                            int j = j0 + jj;
                            if (j <= i) {
                                float acc = 0.f;
#pragma unroll
                                for (int t = 0; t < 16; ++t) acc += xi[t] * pnl[j * 17 + t];
                                s[(size_t)i * DPAD + j] -= acc;
                            }
                        }
                    }
                }
                __syncthreads();
            }
        }

        // ---- phase A: invert the 8 diagonal 16x16 blocks (column-parallel) ----
        {
            int g = tid >> 4, l = tid & 15;
            if (g < NBK) {
                const float* Lb = s + (size_t)(g * BI) * DPAD + g * BI;
                for (int r = 0; r < BI; ++r) {
                    float acc = (r == l) ? 1.f : 0.f;
                    for (int t = l; t < r; ++t) acc -= Lb[r * DPAD + t] * xd[g][t][l];
                    xd[g][r][l] = (r >= l) ? acc / Lb[r * DPAD + r] : 0.f;
                }
            }
        }
        __syncthreads();

        // ---- phase B: off-diagonal blocks by diagonal offset (X transposed upper) ----
        for (int d = 1; d < NBK; ++d) {
            int npairs = NBK - d;
            for (int e = tid; e < npairs * 256; e += 512) {
                int p = e >> 8, ab = e & 255;
                int a2 = ab >> 4, b2 = ab & 15;
                int J = p, I = p + d;
                int Ibase = I * BI, Jbase = J * BI;
                float acc = 0.f;
                {
                    const float* Lr = s + (size_t)(Ibase + a2) * DPAD + Jbase;
                    for (int t = 0; t < BI; ++t) acc += Lr[t] * xd[J][t][b2];
                }
                for (int K = J + 1; K < I; ++K) {
                    int Kbase = K * BI;
                    const float* Lr = s + (size_t)(Ibase + a2) * DPAD + Kbase;
                    const float* Xc = s + (size_t)(Jbase + b2) * DPAD + Kbase;
                    for (int t = 0; t < BI; ++t) acc += Lr[t] * Xc[t];
                }
                wbuf[p][a2][b2] = acc;
            }
            __syncthreads();
            for (int e = tid; e < npairs * 256; e += 512) {
                int p = e >> 8, ab = e & 255;
                int a2 = ab >> 4, b2 = ab & 15;
                int J = p, I = p + d;
                float acc = 0.f;
                for (int t = 0; t < BI; ++t) acc += xd[I][a2][t] * wbuf[p][t][b2];
                s[(size_t)(J * BI + b2) * DPAD + I * BI + a2] = -acc;
            }
            __syncthreads();
        }

        // ---- write back Dinv (zeros in strict upper) ----
        for (int idx = tid; idx < 128 * 128; idx += 512) {
            int r = idx >> 7, c = idx & 127;
            float v;
            if (c > r) {
                v = 0.f;
            } else {
                int gr = r >> 4, gc = c >> 4;
                v = (gr == gc) ? xd[gr][r & 15][c & 15] : s[(size_t)c * DPAD + r];
            }
            Ad[(size_t)r * lda + c] = v;
        }
        __threadfence();
        __syncthreads();
        if (tid == 0) {
            __hip_atomic_store(flag, 1, __ATOMIC_RELEASE, __HIP_MEMORY_SCOPE_AGENT);
        }
        return;
    }

    // ---------------- panel block: P = P @ Dinv^T ----------------
    if (tid == 0) {
        while (__hip_atomic_load(flag, __ATOMIC_ACQUIRE, __HIP_MEMORY_SCOPE_AGENT) == 0) {}
    }
    __syncthreads();
    __threadfence();

    float* Pb = A + (size_t)(kb + blockIdx.x) * 128 * lda + (size_t)kb * 128;
    const float* D = A + (size_t)kb * 128 * (lda + 1);

    // stage Dinv TRANSPOSED into s: s[k*DPAD + j] = D[j][k]
    for (int idx = tid; idx < 128 * 128; idx += 512) {
        int j = idx >> 7, k = idx & 127;
        s[(size_t)k * DPAD + j] = D[(size_t)j * lda + k];
    }

    int tx = tid & 31, ty = tid >> 5;
    float acc[8][4];
#pragma unroll
    for (int i = 0; i < 8; ++i)
#pragma unroll
        for (int j = 0; j < 4; ++j) acc[i][j] = 0.f;

    float rp[4];
    auto loadP = [&](int kk) {
        int row = tid >> 2, koff = (tid & 3) * 4;
        const float* src = Pb + (size_t)row * lda + kk + koff;
        float4 v = *(const float4*)src;
        rp[0] = v.x; rp[1] = v.y; rp[2] = v.z; rp[3] = v.w;
    };
    auto storeP = [&](int buf) {
        int row = tid >> 2, koff = (tid & 3) * 4;
#pragma unroll
        for (int q = 0; q < 4; ++q) Ps[buf][koff + q][row] = rp[q];
    };

    loadP(0);
    storeP(0);
    for (int t = 0; t < 8; ++t) {
        __syncthreads();
        int cur = t & 1;
        bool more = (t + 1 < 8);
        if (more) loadP((t + 1) * 16);
#pragma unroll
        for (int k = 0; k < 16; ++k) {
            float a[8], b[4];
            float4 t0 = *(const float4*)&Ps[cur][k][ty * 4];
            float4 t1 = *(const float4*)&Ps[cur][k][64 + ty * 4];
            float4 u0 = *(const float4*)&s[(size_t)(t * 16 + k) * DPAD + tx * 4];
            a[0] = t0.x; a[1] = t0.y; a[2] = t0.z; a[3] = t0.w;
            a[4] = t1.x; a[5] = t1.y; a[6] = t1.z; a[7] = t1.w;
            b[0] = u0.x; b[1] = u0.y; b[2] = u0.z; b[3] = u0.w;
#pragma unroll
            for (int i = 0; i < 8; ++i)
#pragma unroll
                for (int j = 0; j < 4; ++j) acc[i][j] += a[i] * b[j];
        }
        if (more) storeP(cur ^ 1);
    }
#pragma unroll
    for (int i = 0; i < 8; ++i) {
        int gi = ((i >> 2) << 6) + ty * 4 + (i & 3);
#pragma unroll
        for (int j = 0; j < 4; ++j) {
            Pb[(size_t)gi * lda + tx * 4 + j] = acc[i][j];
        }
    }
}

__global__ __launch_bounds__(256) void gemv_lower_k(const float* __restrict__ L, int ld,
                                                    const float* __restrict__ y,
                                                    float* __restrict__ z, int n) {
    int wave = threadIdx.x >> 6, lane = threadIdx.x & 63;
    int row = blockIdx.x * 4 + wave;
    if (row >= n) return;
    const float* Lr = L + (size_t)row * ld;
    float s = 0.f;
    for (int j = lane; j <= row; j += 64) s += Lr[j] * y[j];
#pragma unroll
    for (int off = 32; off; off >>= 1) s += __shfl_down(s, off);
    if (lane == 0) z[row] = s;
}

__global__ __launch_bounds__(256) void resid_part_k(const float* __restrict__ Z,
                                                    const float* __restrict__ zv,
                                                    float* __restrict__ part) {
    int j = blockIdx.x * 256 + threadIdx.x;
    int i0 = blockIdx.y * 64;
    float acc = 0.f;
    for (int i = i0; i < i0 + 64; ++i) acc += Z[(size_t)i * NS + j] * zv[i];
    part[(size_t)blockIdx.y * NS + j] = acc;
}

__global__ __launch_bounds__(256) void resid_fin_k(const float* __restrict__ part,
                                                   const float* __restrict__ ty,
                                                   float* __restrict__ r) {
    int j = blockIdx.x * 256 + threadIdx.x;
    float acc = 0.f;
    for (int q = 0; q < 32; ++q) acc += part[(size_t)q * NS + j];
    r[j] = ty[j] - acc;
}

__global__ __launch_bounds__(256) void loss_k(const float* __restrict__ Lc, int n, int ldl,
                                              float sign,
                                              const float* __restrict__ v,
                                              float* __restrict__ out) {
    __shared__ float red1[256];
    __shared__ float red2[256];
    int tid = threadIdx.x;
    float s1 = 0.f, s2 = 0.f;
    for (int i = tid; i < n; i += 256) {
        s1 += logf(Lc[(size_t)i * ldl + i]);
        float vi = v[i];
        s2 += vi * vi;
    }
    red1[tid] = s1;
    red2[tid] = s2;
    __syncthreads();
    for (int s = 128; s; s >>= 1) {
        if (tid < s) { red1[tid] += red1[tid + s]; red2[tid] += red2[tid + s]; }
        __syncthreads();
    }
    if (tid == 0) {
        out[0] = 0.5f * sign * red1[0] + 0.5f * red2[0] + 0.5f * (float)n * 1.8378770664093453f;
    }
}

// ---------------- host orchestration ----------------

static const size_t CHOL_LDS = (size_t)128 * DPAD * sizeof(float);  // 66 KB dynamic

static void run_chol(float* A, int* flags, hipStream_t stream) {
    for (int kb = 0; kb < 16; ++kb) {
        int nrem = 15 - kb;
        chol_step_k<<<dim3(1 + nrem), 512, CHOL_LDS, stream>>>(A, NS, kb, flags + kb);
        if (nrem > 0) {
            float* P = A + (size_t)(kb + 1) * 128 * NS + kb * 128;
            float* Ct = A + (size_t)(kb + 1) * 128 * (NS + 1);
            gemm_bf_k<0, 1><<<dim3(nrem, nrem), 512, 0, stream>>>(
                nrem * 128, nrem * 128, 128, P, NS, 0, P, NS, 0, Ct, NS, 0,
                nullptr, 0, nullptr, nullptr, nullptr, 3, 0, 0, 1);
        }
    }
}

// In-place recursive inversion of the lower-triangular factor (diag 128-blocks
// already hold Dinv with explicit zeros above the diagonal).
static void run_inv(float* A, float* T, hipStream_t stream) {
    for (int s = 128; s <= 1024; s <<= 1) {
        int np = NS / (2 * s);
        size_t zz = (size_t)2 * s * (NS + 1);
        size_t zt = (size_t)s * s;
        dim3 g(s / 128, s / 128, np);
        gemm_bf_k<0, 0><<<g, 512, 0, stream>>>(s, s, s, A + (size_t)s * NS, NS, zz,
                                               A, NS, zz, T, s, zt,
                                               nullptr, 0, nullptr, nullptr, nullptr,
                                               0, 0, 0, 4);
        gemm_bf_k<0, 0><<<g, 512, 0, stream>>>(s, s, s, A + (size_t)s * (NS + 1), NS, zz,
                                               T, s, zt, A + (size_t)s * NS, NS, zz,
                                               nullptr, 0, nullptr, nullptr, nullptr,
                                               4, 0, 0, 2);
    }
}

extern "C" void kernel_launch(void* const* d_in, const int* in_sizes, int n_in,
                              void* d_out, int out_size, void* d_ws, size_t ws_size,
                              hipStream_t stream) {
    const float* source_x = (const float*)d_in[0];
    const float* source_y = (const float*)d_in[1];
    const float* target_x = (const float*)d_in[2];
    const float* target_y = (const float*)d_in[3];
    const float* k_ss = (const float*)d_in[4];
    const float* k_tt = (const float*)d_in[5];
    const float* k_st = (const float*)d_in[6];
    const float* noise_s = (const float*)d_in[7];
    const float* noise_t = (const float*)d_in[8];
    const float* Wf = (const float*)d_in[9];
    const float* bf = (const float*)d_in[10];
    const float* Ws = (const float*)d_in[11];
    const float* bs = (const float*)d_in[12];
    const float* Wt = (const float*)d_in[13];
    const float* bt = (const float*)d_in[14];
    const float* Kb = (const float*)d_in[15];
    const float* base_s = (const float*)d_in[16];
    const float* base_t = (const float*)d_in[17];
    float* out = (float*)d_out;

    float* w = (float*)d_ws;
    const size_t M2 = (size_t)NS * NS;
    float* Ksrc = w;
    float* Kcos = w + M2;
    float* Ktgt = w + 2 * M2;
    float* stag = w + 3 * M2;
    float* wsb = stag;
    float* wtb = stag + (size_t)NS * NB;
    float* wsK = stag + 2 * (size_t)NS * NB;
    float* wtK = stag + 3 * (size_t)NS * NB;
    float* Z = stag;
    float* T = w + 4 * M2;
    float* sm = T + (size_t)1024 * 1024;
    float* wcomb = sm;
    float* consts = sm + 1024;
    float* a_s = sm + 1032;
    float* b_s = a_s + NS;
    float* a_t = b_s + NB;
    float* b_t = a_t + NS;
    float* rvec = b_t + NB;
    float* vvec = rvec + NS;
    float* z2 = vvec + NS;
    int* flags = (int*)(z2 + NS);   // 64 ints

    // 0) flags for the fused chol steps
    init_flags_k<<<1, 64, 0, stream>>>(flags);

    // 1) feature maps + kernel weights
    prep_k<<<1, 256, 0, stream>>>(Wf, bf, Ws, Wt, wcomb, consts);
    matvec_k<<<NS / 4, 256, 0, stream>>>(source_x, NS, wcomb + 0 * DIMX, consts, 0, a_s);
    matvec_k<<<NB / 4, 256, 0, stream>>>(base_s, NB, wcomb + 1 * DIMX, consts, 1, b_s);
    matvec_k<<<NS / 4, 256, 0, stream>>>(target_x, NS, wcomb + 2 * DIMX, consts, 2, a_t);
    matvec_k<<<NB / 4, 256, 0, stream>>>(base_t, NB, wcomb + 3 * DIMX, consts, 3, b_t);
    weights_k<<<NS, 256, 0, stream>>>(a_s, b_s, bs, wsb);
    weights_k<<<NS, 256, 0, stream>>>(a_t, b_t, bt, wtb);

    // 2) wsK = ws@Kb, wtK = wt@Kb  (batched z=2)
    gemm_bf_k<0, 0><<<dim3(NB / 128, NS / 128, 2), 512, 0, stream>>>(
        NS, NB, NB, wsb, NB, (size_t)NS * NB, Kb, NB, 0, wsK, NB, (size_t)NS * NB,
        nullptr, 0, nullptr, nullptr, nullptr, 0, 0, 0, 0);

    // 3) K_src & K_tgt (batched z=2, per-z kmat/noise; zoffC = 2*M2 -> Ktgt), then K_cos
    gemm_bf_k<0, 1><<<dim3(NS / 128, NS / 128, 2), 512, 0, stream>>>(
        NS, NS, NB, wsK, NB, (size_t)NS * NB, wsb, NB, (size_t)NS * NB, Ksrc, NS, 2 * M2,
        k_ss, NS, noise_s, k_tt, noise_t, 1, 0, 0, 0);
    gemm_bf_k<0, 1><<<dim3(NS / 128, NS / 128), 512, 0, stream>>>(
        NS, NS, NB, wsK, NB, 0, wtb, NB, 0, Kcos, NS, 0,
        k_st, NS, nullptr, nullptr, nullptr, 2, 0, 0, 0);

    // 4) Cholesky of K_src + full triangular inversion -> Linv in Ksrc
    run_chol(Ksrc, flags, stream);
    run_inv(Ksrc, T, stream);

    // 5) Z = Linv @ Kcos (K trimmed to the lower band)
    gemm_bf_k<0, 0><<<dim3(NS / 128, NS / 128), 512, 0, stream>>>(
        NS, NS, NS, Ksrc, NS, 0, Kcos, NS, 0, Z, NS, 0,
        nullptr, 0, nullptr, nullptr, nullptr, 0, 0, 0, 2);

    // 6) z2 = Linv @ source_y ; r = target_y - Z^T z2
    gemv_lower_k<<<NS / 4, 256, 0, stream>>>(Ksrc, NS, source_y, z2, NS);
    resid_part_k<<<dim3(NS / 256, 32), 256, 0, stream>>>(Z, z2, T);
    resid_fin_k<<<NS / 256, 256, 0, stream>>>(T, target_y, rvec);

    // 7) cov = K_tgt - Z^T Z (lower tiles only)
    gemm_bf_k<1, 0><<<dim3(NS / 128, NS / 128), 512, 0, stream>>>(
        NS, NS, NS, Z, NS, 0, Z, NS, 0, Ktgt, NS, 0,
        nullptr, 0, nullptr, nullptr, nullptr, 3, 0, 0, 1);

    // 8) Cholesky of cov + full triangular inversion -> Lcinv in Ktgt
    run_chol(Ktgt, flags + 16, stream);
    run_inv(Ktgt, T, stream);

    // 9) v = Lcinv @ r ; loss (log diag(Lc) = -log diag(Lcinv))
    gemv_lower_k<<<NS / 4, 256, 0, stream>>>(Ktgt, NS, rvec, vvec, NS);
    loss_k<<<1, 256, 0, stream>>>(Ktgt, NS, NS, -1.0f, vvec, out);
}